// Round 11
// baseline (2467.772 us; speedup 1.0000x reference)
//
#include <hip/hip_runtime.h>

typedef unsigned short u16;
typedef __attribute__((ext_vector_type(8))) short bf16x8s;
typedef __attribute__((ext_vector_type(4))) float f32x4;

#define DEV static __device__ __forceinline__

DEV float b2f(u16 v) { return __uint_as_float(((unsigned)v) << 16); }
// HW RNE f32->bf16 (1 VALU op)
DEV u16 f2b(float f) {
  unsigned r;
  asm("v_cvt_pk_bf16_f32 %0, %1, %1" : "=v"(r) : "v"(f));
  return (u16)r;
}
DEV unsigned f2b2(float a, float b) {
  unsigned r;
  asm("v_cvt_pk_bf16_f32 %0, %1, %2" : "=v"(r) : "v"(a), "v"(b));
  return r;
}

// async global->LDS, 16B per lane; lds base must be wave-uniform (HW adds lane*16)
#define GLL(gp, lp)                                                            \
  __builtin_amdgcn_global_load_lds(                                            \
      (const __attribute__((address_space(1))) unsigned int*)(gp),             \
      (__attribute__((address_space(3))) unsigned int*)(lp), 16, 0, 0)

#define MFMA __builtin_amdgcn_mfma_f32_16x16x32_bf16

// ---------------- fused converts: x and z fp32 -> bf16 ----------------------
__global__ __launch_bounds__(256) void k_f2bxz(const float* __restrict__ x,
                                               const float* __restrict__ z,
                                               u16* __restrict__ xb,
                                               u16* __restrict__ zb) {
  long i = (long)blockIdx.x * 256 + threadIdx.x;  // < 6291456
  const float* src;
  u16* dst;
  long j;
  if (i < 4194304) { src = x; dst = xb; j = i; }
  else { src = z; dst = zb; j = i - 4194304; }
  float4 v = *(const float4*)(src + j * 4);
  unsigned* d = (unsigned*)(dst + j * 4);
  d[0] = f2b2(v.x, v.y);
  d[1] = f2b2(v.z, v.w);
}

// ---------------- fused weight transposes: Wq, Wkv, Wo ----------------------
__global__ __launch_bounds__(256) void k_wt3(const float* __restrict__ Wq,
                                             const float* __restrict__ Wkv,
                                             const float* __restrict__ Wo,
                                             u16* __restrict__ wqt,
                                             u16* __restrict__ wkvt,
                                             u16* __restrict__ wot) {
  int e = blockIdx.x * 256 + threadIdx.x;  // < 1048576
  const float* W;
  u16* Wt;
  int N, le;
  if (e < 262144) { W = Wq; Wt = wqt; N = 512; le = e; }
  else if (e < 786432) { W = Wkv; Wt = wkvt; N = 1024; le = e - 262144; }
  else { W = Wo; Wt = wot; N = 512; le = e - 786432; }
  int nn = le >> 9, kk = le & 511;
  Wt[le] = f2b(W[(long)kk * N + nn]);
}

// ---------------- 128x128 bf16 NT GEMM (BK=64, global_load_lds, swizzled) ----
template <int MODE>
__global__ __launch_bounds__(256, 2) void k_gemm128(
    const u16* __restrict__ A, const u16* __restrict__ Bm, void* __restrict__ C0,
    void* __restrict__ C1, const float* __restrict__ xres,
    const float* __restrict__ bias, int K) {
  const int nwg = gridDim.x * gridDim.y;
  const int orig = blockIdx.y * gridDim.x + blockIdx.x;
  const int qq = nwg >> 3, rr = nwg & 7;
  const int xcd = orig & 7, loc = orig >> 3;
  const int swz = (xcd < rr ? xcd * (qq + 1) : rr * (qq + 1) + (xcd - rr) * qq) + loc;
  const int m0 = (swz / gridDim.x) << 7, n0 = (swz % gridDim.x) << 7;
  const int t = threadIdx.x, lane = t & 63, w = t >> 6;
  const int wm = (w >> 1) << 6, wn = (w & 1) << 6;
  const int fr = lane & 15, g = lane >> 4;
  __shared__ u16 As[8192];
  __shared__ u16 Bs[8192];
  f32x4 acc[4][4] = {};
  const int srow = t >> 3, scs = t & 7;
  for (int k0 = 0; k0 < K; k0 += 64) {
    __syncthreads();
#pragma unroll
    for (int i = 0; i < 4; ++i) {
      int row = srow + (i << 5), cs = scs;
      GLL(A + (long)(m0 + row) * K + k0 + ((cs ^ (row & 7)) << 3),
          &As[(i << 11) + (w << 9)]);
      GLL(Bm + (long)(n0 + row) * K + k0 + ((cs ^ (row & 7)) << 3),
          &Bs[(i << 11) + (w << 9)]);
    }
    __syncthreads();
#pragma unroll
    for (int ks = 0; ks < 2; ++ks) {
      bf16x8s af[4], bf[4];
#pragma unroll
      for (int fi = 0; fi < 4; ++fi) {
        int row = wm + fi * 16 + fr;
        af[fi] = *(const bf16x8s*)((const char*)As + row * 128 +
                                   (((ks * 4 + g) ^ (row & 7)) << 4));
      }
#pragma unroll
      for (int fj = 0; fj < 4; ++fj) {
        int row = wn + fj * 16 + fr;
        bf[fj] = *(const bf16x8s*)((const char*)Bs + row * 128 +
                                   (((ks * 4 + g) ^ (row & 7)) << 4));
      }
#pragma unroll
      for (int fi = 0; fi < 4; ++fi)
#pragma unroll
        for (int fj = 0; fj < 4; ++fj)
          acc[fi][fj] = MFMA(af[fi], bf[fj], acc[fi][fj], 0, 0, 0);
    }
  }
  const int crow = g << 2;
#pragma unroll
  for (int fi = 0; fi < 4; ++fi)
#pragma unroll
    for (int fj = 0; fj < 4; ++fj)
#pragma unroll
      for (int r = 0; r < 4; ++r) {
        int row = m0 + wm + fi * 16 + crow + r;
        int col = n0 + wn + fj * 16 + fr;
        float v = acc[fi][fj][r];
        if (MODE == 0) {
          int b = row >> 13, n = row & 8191, h = col >> 6, dh = col & 63;
          ((u16*)C0)[((((long)(b * 8 + h)) << 13) + n) * 64 + dh] = f2b(v * 0.125f);
        } else if (MODE == 1) {
          int b = row >> 12, nz = row & 4095;
          if (col < 512) {
            int h = col >> 6, dh = col & 63;
            ((u16*)C0)[((((long)(b * 8 + h)) << 12) + nz) * 64 + dh] = f2b(v);
          } else {
            int c2 = col - 512, h = c2 >> 6, dh = c2 & 63;
            ((u16*)C1)[((((long)(b * 8 + h) * 64 + dh)) << 12) + nz] = f2b(v);
          }
        } else if (MODE == 2) {
          long idx = ((long)row << 9) + col;
          ((float*)C0)[idx] = v + xres[idx] + bias[col];
        }
      }
}

// ---------------- fused landmarks (q then k): mean -> split hi/lo bf16 ------
__global__ __launch_bounds__(256) void k_land2(const u16* __restrict__ qb,
                                               const u16* __restrict__ kb,
                                               u16* __restrict__ qlh,
                                               u16* __restrict__ qll,
                                               u16* __restrict__ klh,
                                               u16* __restrict__ kll) {
  int pidx = blockIdx.x * 4 + (threadIdx.x >> 6);  // < 16384
  const u16* src;
  u16 *hi, *lo;
  int ntok, l;
  float inv;
  if (pidx < 8192) { src = qb; hi = qlh; lo = qll; ntok = 8192; l = 32; inv = 1.f / 32.f; }
  else { src = kb; hi = klh; lo = kll; ntok = 4096; l = 16; inv = 1.f / 16.f; pidx -= 8192; }
  int d = threadIdx.x & 63;
  int bh = pidx >> 8, m = pidx & 255;
  const u16* s = src + ((long)bh * ntok + (long)m * l) * 64 + d;
  float sum = 0.f;
  for (int j = 0; j < l; ++j) sum += b2f(s[j * 64]);
  sum *= inv;
  long o = ((long)bh * 256 + m) * 64 + d;
  u16 h = f2b(sum);
  hi[o] = h;
  lo[o] = f2b(sum - b2f(h));
}

// ---------------- sim2 + softmax via split-bf16 MFMA ------------------------
__global__ __launch_bounds__(256, 2) void k_sim2(
    const u16* __restrict__ qlh, const u16* __restrict__ qll,
    const u16* __restrict__ klh, const u16* __restrict__ kll,
    float* __restrict__ attn2, u16* __restrict__ aNhi, u16* __restrict__ aNlo) {
  const int rb = blockIdx.x, bh = blockIdx.y;
  const int t = threadIdx.x, lane = t & 63, w = t >> 6;
  const int fr = lane & 15, g = lane >> 4;
  __shared__ char lds[65536];
  {
    const u16* kh = klh + (long)bh * 16384;
    const u16* kl = kll + (long)bh * 16384;
    int srow8 = lane >> 3, cs7 = lane & 7;
#pragma unroll
    for (int i = 0; i < 8; ++i) {
      int slab = w * 8 + i;
      int krow = slab * 8 + srow8;
      GLL(kh + krow * 64 + ((cs7 ^ (krow & 7)) << 3), lds + slab * 1024);
      GLL(kl + krow * 64 + ((cs7 ^ (krow & 7)) << 3), lds + 32768 + slab * 1024);
    }
  }
  long qoff = ((long)bh * 256 + rb * 64 + w * 16 + fr) * 64;
  bf16x8s qh0 = *(const bf16x8s*)(qlh + qoff + g * 8);
  bf16x8s qh1 = *(const bf16x8s*)(qlh + qoff + 32 + g * 8);
  bf16x8s ql0 = *(const bf16x8s*)(qll + qoff + g * 8);
  bf16x8s ql1 = *(const bf16x8s*)(qll + qoff + 32 + g * 8);
  __syncthreads();
  f32x4 s[16];
#pragma unroll
  for (int c = 0; c < 16; ++c) {
    int j = (c << 4) + fr;
    int o0 = j * 128 + ((g ^ (j & 7)) << 4);
    int o1 = j * 128 + (((4 + g) ^ (j & 7)) << 4);
    bf16x8s kh0 = *(const bf16x8s*)(lds + o0);
    bf16x8s kh1 = *(const bf16x8s*)(lds + o1);
    bf16x8s kl0 = *(const bf16x8s*)(lds + 32768 + o0);
    bf16x8s kl1 = *(const bf16x8s*)(lds + 32768 + o1);
    f32x4 zz = {};
    zz = MFMA(qh0, kh0, zz, 0, 0, 0);
    zz = MFMA(qh1, kh1, zz, 0, 0, 0);
    zz = MFMA(qh0, kl0, zz, 0, 0, 0);
    zz = MFMA(qh1, kl1, zz, 0, 0, 0);
    zz = MFMA(ql0, kh0, zz, 0, 0, 0);
    zz = MFMA(ql1, kh1, zz, 0, 0, 0);
    s[c] = zz;
  }
  float li[4];
#pragma unroll
  for (int r = 0; r < 4; ++r) {
    float m = s[0][r];
#pragma unroll
    for (int c = 1; c < 16; ++c) m = fmaxf(m, s[c][r]);
    m = fmaxf(m, __shfl_xor(m, 1, 64));
    m = fmaxf(m, __shfl_xor(m, 2, 64));
    m = fmaxf(m, __shfl_xor(m, 4, 64));
    m = fmaxf(m, __shfl_xor(m, 8, 64));
    float l = 0.f;
#pragma unroll
    for (int c = 0; c < 16; ++c) {
      float e = __expf(s[c][r] - m);
      s[c][r] = e;
      l += e;
    }
    l += __shfl_xor(l, 1, 64);
    l += __shfl_xor(l, 2, 64);
    l += __shfl_xor(l, 4, 64);
    l += __shfl_xor(l, 8, 64);
    li[r] = 1.f / l;
  }
#pragma unroll
  for (int c = 0; c < 16; ++c)
#pragma unroll
    for (int r = 0; r < 4; ++r) {
      int row = rb * 64 + w * 16 + (g << 2) + r;
      int col = (c << 4) + fr;
      long idx = ((long)bh << 16) + ((long)row << 8) + col;
      float p = s[c][r] * li[r];
      attn2[idx] = p;
      u16 h = f2b(p);
      aNhi[idx] = h;
      aNlo[idx] = f2b(p - b2f(h));
    }
}

__global__ __launch_bounds__(256) void k_colmax(const float* __restrict__ attn2,
                                                unsigned* __restrict__ cmax) {
  int bh = blockIdx.x, j = threadIdx.x, lane = j & 63, w = j >> 6;
  const float* p = attn2 + ((long)bh << 16) + j;
  float s = 0.f;
  for (int m = 0; m < 256; ++m) s += p[m * 256];
  float mx = s;
  for (int o = 1; o < 64; o <<= 1) mx = fmaxf(mx, __shfl_xor(mx, o, 64));
  __shared__ float r1[4];
  if (lane == 0) r1[w] = mx;
  __syncthreads();
  if (j == 0) {
    mx = fmaxf(fmaxf(r1[0], r1[1]), fmaxf(r1[2], r1[3]));
    atomicMax(cmax, __float_as_uint(mx));
  }
}

// ---------------- T1 split-KV partial: (bh, rb, kc of 1024 keys) ------------
__global__ __launch_bounds__(256, 2) void k_t1part(
    const u16* __restrict__ qlb, const u16* __restrict__ kb,
    const u16* __restrict__ vtb, float* __restrict__ opart,
    float* __restrict__ pm_, float* __restrict__ pl_) {
  int orig = blockIdx.x;  // 512 = 32 bh * 4 kc * 4 rb
  int xcd = orig & 7, idx = orig >> 3;
  int p = xcd * 16 + (idx >> 2);
  int rb = idx & 3;
  int bh = p >> 2, kc = p & 3;
  const int t = threadIdx.x, lane = t & 63, w = t >> 6;
  const int fr = lane & 15, g = lane >> 4;
  __shared__ char lds[65536];
  const u16* qrow = qlb + ((long)bh * 256 + rb * 64 + w * 16 + fr) * 64;
  bf16x8s qa0 = *(const bf16x8s*)(qrow + g * 8);
  bf16x8s qa1 = *(const bf16x8s*)(qrow + 32 + g * 8);
  f32x4 o[4] = {};
  float m[4] = {-3e38f, -3e38f, -3e38f, -3e38f};
  float l[4] = {};
  const long kbase = (long)bh * 262144;
  for (int cc = 0; cc < 4; ++cc) {
    int c0 = kc * 1024 + cc * 256;
    __syncthreads();
#pragma unroll
    for (int i = 0; i < 8; ++i) {
      int seg = (i << 8) + t, row = seg >> 3, cs = seg & 7;
      GLL(kb + kbase + (long)(c0 + row) * 64 + ((cs ^ (row & 7)) << 3),
          lds + (i << 12) + (w << 10));
    }
#pragma unroll
    for (int i = 0; i < 8; ++i) {
      int seg = (i << 8) + t, row = seg >> 5, cs = seg & 31;
      GLL(vtb + kbase + (long)row * 4096 + c0 + ((cs ^ (row & 7)) << 3),
          lds + 32768 + (i << 12) + (w << 10));
    }
    __syncthreads();
    f32x4 s[16];
#pragma unroll
    for (int c = 0; c < 16; ++c) {
      int j = c * 16 + fr;
      bf16x8s b0 = *(const bf16x8s*)(lds + j * 128 + ((g ^ (j & 7)) << 4));
      bf16x8s b1 = *(const bf16x8s*)(lds + j * 128 + (((4 + g) ^ (j & 7)) << 4));
      f32x4 zz = {};
      zz = MFMA(qa0, b0, zz, 0, 0, 0);
      zz = MFMA(qa1, b1, zz, 0, 0, 0);
      s[c] = zz;
    }
    float sc[4];
#pragma unroll
    for (int r = 0; r < 4; ++r) {
      float pm = s[0][r];
#pragma unroll
      for (int c = 1; c < 16; ++c) pm = fmaxf(pm, s[c][r]);
      pm = fmaxf(pm, __shfl_xor(pm, 1, 64));
      pm = fmaxf(pm, __shfl_xor(pm, 2, 64));
      pm = fmaxf(pm, __shfl_xor(pm, 4, 64));
      pm = fmaxf(pm, __shfl_xor(pm, 8, 64));
      float mn = fmaxf(m[r], pm);
      sc[r] = __expf(m[r] - mn);
      m[r] = mn;
    }
#pragma unroll
    for (int r = 0; r < 4; ++r) {
      float su = 0.f;
#pragma unroll
      for (int c = 0; c < 16; ++c) {
        float e = __expf(s[c][r] - m[r]);
        s[c][r] = e;
        su += e;
      }
      su += __shfl_xor(su, 1, 64);
      su += __shfl_xor(su, 2, 64);
      su += __shfl_xor(su, 4, 64);
      su += __shfl_xor(su, 8, 64);
      l[r] = l[r] * sc[r] + su;
    }
#pragma unroll
    for (int d = 0; d < 4; ++d)
#pragma unroll
      for (int r = 0; r < 4; ++r) o[d][r] *= sc[r];
    __syncthreads();
#pragma unroll
    for (int c = 0; c < 16; ++c)
#pragma unroll
      for (int r = 0; r < 4; ++r) {
        int row = (w << 4) + (g << 2) + r;
        int byin = (c << 5) + (fr << 1);
        *(u16*)(lds + row * 512 + (byin ^ ((row & 7) << 4))) = f2b(s[c][r]);
      }
    asm volatile("s_waitcnt lgkmcnt(0)" ::: "memory");
    __builtin_amdgcn_sched_barrier(0);
#pragma unroll
    for (int ss = 0; ss < 8; ++ss) {
      int prow = (w << 4) + fr;
      bf16x8s ap = *(const bf16x8s*)(lds + prow * 512 +
                                     (((ss * 64) + (g << 4)) ^ ((prow & 7) << 4)));
#pragma unroll
      for (int d = 0; d < 4; ++d) {
        int dh = (d << 4) + fr;
        bf16x8s bv = *(const bf16x8s*)(lds + 32768 + dh * 512 +
                                       (((ss * 4 + g) ^ (dh & 7)) << 4));
        o[d] = MFMA(ap, bv, o[d], 0, 0, 0);
      }
    }
  }
  __syncthreads();
  float* lf = (float*)lds;
#pragma unroll
  for (int d = 0; d < 4; ++d)
#pragma unroll
    for (int r = 0; r < 4; ++r)
      lf[((w << 4) + (g << 2) + r) * 76 + (d << 4) + fr] = o[d][r];
  __syncthreads();
  const long pb = (long)(bh * 4 + kc) * 256 + rb * 64;
#pragma unroll
  for (int i = 0; i < 4; ++i) {
    int row = i * 16 + (t >> 4);
    int c4 = (t & 15) << 2;
    float4 v = *(const float4*)&lf[row * 76 + c4];
    *(float4*)&opart[(pb + row) * 64 + c4] = v;
  }
  if (fr == 0) {
#pragma unroll
    for (int r = 0; r < 4; ++r) {
      int lr = (w << 4) + (g << 2) + r;
      pm_[pb + lr] = m[r];
      pl_[pb + lr] = l[r];
    }
  }
}

// ---------------- merge 4 partials -> T1^T split bf16 -----------------------
__global__ __launch_bounds__(256) void k_t1merge(
    const float* __restrict__ opart, const float* __restrict__ pm_,
    const float* __restrict__ pl_, u16* __restrict__ T1thi,
    u16* __restrict__ T1tlo) {
  const int rb = blockIdx.x, bh = blockIdx.y;
  const int t = threadIdx.x;
#pragma unroll
  for (int rp = 0; rp < 4; ++rp) {
    int row = rb * 64 + rp * 16 + (t >> 4);
    int dh4 = (t & 15) << 2;
    float pmv[4], M = -3e38f;
#pragma unroll
    for (int i = 0; i < 4; ++i) {
      pmv[i] = pm_[(long)(bh * 4 + i) * 256 + row];
      M = fmaxf(M, pmv[i]);
    }
    float L = 0.f, wt[4];
#pragma unroll
    for (int i = 0; i < 4; ++i) {
      wt[i] = __expf(pmv[i] - M);
      L += pl_[(long)(bh * 4 + i) * 256 + row] * wt[i];
    }
    float4 acc = {0.f, 0.f, 0.f, 0.f};
#pragma unroll
    for (int i = 0; i < 4; ++i) {
      float4 v = *(const float4*)&opart[((long)(bh * 4 + i) * 256 + row) * 64 + dh4];
      acc.x += v.x * wt[i]; acc.y += v.y * wt[i];
      acc.z += v.z * wt[i]; acc.w += v.w * wt[i];
    }
    float invL = 1.f / L;
    float vv[4] = {acc.x * invL, acc.y * invL, acc.z * invL, acc.w * invL};
#pragma unroll
    for (int e = 0; e < 4; ++e) {
      int dh = dh4 + e;
      long idx = (long)bh * 16384 + (long)dh * 256 + row;
      u16 h = f2b(vv[e]);
      T1thi[idx] = h;
      T1tlo[idx] = f2b(vv[e] - b2f(h));
    }
  }
}

// ---------------- pinv operand prep (z0 only; aN written by k_sim2) ---------
__global__ __launch_bounds__(256) void k_prep_pinv(
    const float* __restrict__ attn2, const unsigned* __restrict__ cmax,
    u16* __restrict__ zNhi, u16* __restrict__ zNlo,
    u16* __restrict__ zThi, u16* __restrict__ zTlo) {
  const int bz = blockIdx.z, i0 = blockIdx.y << 6, j0 = blockIdx.x << 6;
  const float s = 1.f / __uint_as_float(*cmax);
  const float* base = attn2 + ((long)bz << 16);
  __shared__ float mt[64][65];
  const int r = threadIdx.x >> 2, cb = (threadIdx.x & 3) << 4;
#pragma unroll
  for (int c4 = 0; c4 < 16; c4 += 4) {
    float4 v = *(const float4*)&base[(long)(j0 + r) * 256 + i0 + cb + c4];
    mt[r][cb + c4] = v.x; mt[r][cb + c4 + 1] = v.y;
    mt[r][cb + c4 + 2] = v.z; mt[r][cb + c4 + 3] = v.w;
  }
  __syncthreads();
  const int i = i0 + r;
#pragma unroll
  for (int c4 = 0; c4 < 16; c4 += 4) {
    float4 v = *(const float4*)&base[(long)i * 256 + j0 + cb + c4];
    float vv[4] = {v.x, v.y, v.z, v.w};
#pragma unroll
    for (int e = 0; e < 4; ++e) {
      int j = j0 + cb + c4 + e;
      long idx = ((long)bz << 16) + ((long)i << 8) + j;
      float zt = vv[e] * s;
      u16 zh = f2b(zt);
      zThi[idx] = zh; zTlo[idx] = f2b(zt - b2f(zh));
      float zn = mt[cb + c4 + e][r] * s;
      u16 nh = f2b(zn);
      zNhi[idx] = nh; zNlo[idx] = f2b(zn - b2f(nh));
    }
  }
}

// ---------------- block-local GEMM for the pinv chain -----------------------
// One 512-thread block computes the full [256][NC] product for one bh.
// C = sab*(A@B) + sa*A + cdiag*I ; A [256][256] (hi,lo) row-major; B stored
// transposed (Bthi,Btlo) = [NC][256]. Same math/layout as old k_nn_mfma.
template <int NP, int NC>
DEV void chain_gemm(const u16* __restrict__ Ahi, const u16* __restrict__ Alo,
                    const u16* __restrict__ Bthi, const u16* __restrict__ Btlo,
                    u16* CNhi, u16* CNlo, u16* CThi, u16* CTlo,
                    float sab, float sa, float cdiag, int bz, char* lds, int t) {
  const int lane = t & 63, w = t >> 6;   // 8 waves
  const int fr = lane & 15, g = lane >> 4;
  const long offA = (long)bz << 16;
  const long offB = (long)bz * ((long)NC << 8);
  const int wr = w << 5;                 // wave's 32-row strip
  char* LA = lds;                        // A hi  [256][64] 32KB
  char* LB = lds + 32768;                // B hi  [NC][64]
  char* LAl = lds + 65536;               // A lo (NP3)
  char* LBl = lds + 98304;               // B lo (NP3)
  f32x4 acc[2][NC / 16] = {};
  for (int k0 = 0; k0 < 256; k0 += 64) {
    __syncthreads();  // prior phase's LDS reads + global stores drained
#pragma unroll
    for (int i = 0; i < 4; ++i) {        // A: 2048 segs of 16B
      int seg = (i << 9) + t, row = seg >> 3, cs = seg & 7;
      long a = offA + (long)row * 256 + k0 + ((cs ^ (row & 7)) << 3);
      GLL(Ahi + a, LA + (i << 13) + (w << 10));
      if (NP == 3) GLL(Alo + a, LAl + (i << 13) + (w << 10));
    }
#pragma unroll
    for (int i = 0; i < NC / 64; ++i) {  // B: NC*8 segs
      int seg = (i << 9) + t, row = seg >> 3, cs = seg & 7;
      long b = offB + (long)row * 256 + k0 + ((cs ^ (row & 7)) << 3);
      GLL(Bthi + b, LB + (i << 13) + (w << 10));
      if (NP == 3) GLL(Btlo + b, LBl + (i << 13) + (w << 10));
    }
    __syncthreads();
#pragma unroll
    for (int ks = 0; ks < 2; ++ks) {
#define RD(base, row) \
  (*(const bf16x8s*)((base) + (row) * 128 + (((ks * 4 + g) ^ ((row) & 7)) << 4)))
      bf16x8s a0 = RD(LA, wr + fr), a1 = RD(LA, wr + 16 + fr);
      bf16x8s l0, l1;
      if (NP == 3) { l0 = RD(LAl, wr + fr); l1 = RD(LAl, wr + 16 + fr); }
#pragma unroll
      for (int c = 0; c < NC / 16; ++c) {
        bf16x8s b0 = RD(LB, c * 16 + fr);
        acc[0][c] = MFMA(a0, b0, acc[0][c], 0, 0, 0);
        acc[1][c] = MFMA(a1, b0, acc[1][c], 0, 0, 0);
        if (NP == 3) {
          bf16x8s bl = RD(LBl, c * 16 + fr);
          acc[0][c] = MFMA(a0, bl, acc[0][c], 0, 0, 0);
          acc[0][c] = MFMA(l0, b0, acc[0][c], 0, 0, 0);
          acc[1][c] = MFMA(a1, bl, acc[1][c], 0, 0, 0);
          acc[1][c] = MFMA(l1, b0, acc[1][c], 0, 0, 0);
        }
      }
#undef RD
    }
  }
  const int crow = g << 2;
  const long offC = (long)bz * ((long)NC << 8);
#pragma unroll
  for (int i = 0; i < 2; ++i)
#pragma unroll
    for (int c = 0; c < NC / 16; ++c)
#pragma unroll
      for (int r = 0; r < 4; ++r) {
        int row = wr + i * 16 + crow + r;
        int col = c * 16 + fr;
        float v = sab * acc[i][c][r];
        if (sa != 0.f) {
          long ai = offA + ((long)row << 8) + col;
          v += sa * (b2f(Ahi[ai]) + b2f(Alo[ai]));
        }
        if (row == col) v += cdiag;
        if (CNhi) {
          long ci = offC + (long)row * NC + col;
          u16 h = f2b(v);
          CNhi[ci] = h;
          if (CNlo) CNlo[ci] = f2b(v - b2f(h));
        }
        if (CThi) {
          long ti = offC + ((long)col << 8) + row;
          u16 h = f2b(v);
          CThi[ti] = h;
          if (CTlo) CTlo[ti] = f2b(v - b2f(h));
        }
      }
}

// one block per bh: 6 NS iterations (4 GEMMs each) + final T2^T GEMM.
// All state for a bh touched by exactly ONE block (same CU) -> block-scope
// global RAW via __syncthreads (vmcnt drain + own-L1 write-invalidate).
__global__ __launch_bounds__(512) void k_pinv_chain(
    const u16* __restrict__ aNhi, const u16* __restrict__ aNlo,
    u16* __restrict__ PS, const u16* __restrict__ T1thi,
    const u16* __restrict__ T1tlo, u16* __restrict__ T2t) {
  __shared__ char lds[131072];
  const int bz = blockIdx.x, t = threadIdx.x;
  const long MC = 2097152;
  u16 *zA_N0 = PS,          *zA_N1 = PS + MC,     *zA_T0 = PS + 2 * MC, *zA_T1 = PS + 3 * MC;
  u16 *zB_N0 = PS + 4 * MC, *zB_N1 = PS + 5 * MC, *zB_T0 = PS + 6 * MC, *zB_T1 = PS + 7 * MC;
  u16 *azN0 = PS + 8 * MC,  *azN1 = PS + 9 * MC,  *azT0 = PS + 10 * MC, *azT1 = PS + 11 * MC;
  u16 *taT0 = PS + 12 * MC, *taT1 = PS + 13 * MC;
  u16 *tcT0 = PS + 14 * MC, *tcT1 = PS + 15 * MC;
  for (int it = 0; it < 6; ++it) {
    u16 *cN0, *cN1, *cT0, *cT1, *nN0, *nN1, *nT0, *nT1;
    if ((it & 1) == 0) {
      cN0 = zA_N0; cN1 = zA_N1; cT0 = zA_T0; cT1 = zA_T1;
      nN0 = zB_N0; nN1 = zB_N1; nT0 = zB_T0; nT1 = zB_T1;
    } else {
      cN0 = zB_N0; cN1 = zB_N1; cT0 = zB_T0; cT1 = zB_T1;
      nN0 = zA_N0; nN1 = zA_N1; nT0 = zA_T0; nT1 = zA_T1;
    }
    if (it < 5) {
      bool l4 = (it == 4);  // z5 feeds the NP3 iteration -> write lo planes
      chain_gemm<1, 256>(aNhi, aNlo, cT0, cT1, azN0, azN1, azT0, nullptr,
                         1.f, 0.f, 0.f, bz, lds, t);
      chain_gemm<1, 256>(azN0, azN1, azT0, nullptr, nullptr, nullptr, taT0, nullptr,
                         1.f, -7.f, 15.f, bz, lds, t);
      chain_gemm<1, 256>(azN0, azN1, taT0, nullptr, nullptr, nullptr, tcT0, nullptr,
                         -1.f, 0.f, 13.f, bz, lds, t);
      chain_gemm<1, 256>(cN0, cN1, tcT0, nullptr, nN0, l4 ? nN1 : nullptr,
                         nT0, l4 ? nT1 : nullptr, 0.25f, 0.f, 0.f, bz, lds, t);
    } else {
      chain_gemm<3, 256>(aNhi, aNlo, cT0, cT1, azN0, azN1, azT0, azT1,
                         1.f, 0.f, 0.f, bz, lds, t);
      chain_gemm<3, 256>(azN0, azN1, azT0, azT1, nullptr, nullptr, taT0, taT1,
                         1.f, -7.f, 15.f, bz, lds, t);
      chain_gemm<3, 256>(azN0, azN1, taT0, taT1, nullptr, nullptr, tcT0, tcT1,
                         -1.f, 0.f, 13.f, bz, lds, t);
      chain_gemm<3, 256>(cN0, cN1, tcT0, tcT1, nN0, nN1, nullptr, nullptr,
                         0.25f, 0.f, 0.f, bz, lds, t);
    }
  }
  // T2^T = (pinv @ T1)^T ; final z in zA set after 6 swaps
  chain_gemm<3, 64>(zA_N0, zA_N1, T1thi, T1tlo, nullptr, nullptr, T2t, nullptr,
                    1.f, 0.f, 0.f, bz, lds, t);
}

// ---------------- fused sim1: O = softmax(q @ k_land^T) @ T2 ----------------
__global__ __launch_bounds__(256) void k_fused_attn1(const u16* __restrict__ q,
                                                     const u16* __restrict__ klb,
                                                     const u16* __restrict__ t2t,
                                                     u16* __restrict__ O) {
  const int bh = blockIdx.y, n0 = blockIdx.x << 6;
  const int bb = bh >> 3, hh = bh & 7;
  const int t = threadIdx.x, lane = t & 63, w = t >> 6;
  const int fr = lane & 15, g = lane >> 4;
  __shared__ char lds[65536];
  {
    const u16* ks = klb + (long)bh * 16384;
    const u16* ts = t2t + (long)bh * 16384;
    int srow8 = lane >> 3, cs7 = lane & 7;
    int srow2 = lane >> 5, seg32 = lane & 31;
#pragma unroll
    for (int i = 0; i < 8; ++i) {
      int slab = w * 8 + i;
      int krow = slab * 8 + srow8;
      GLL(ks + krow * 64 + ((cs7 ^ (krow & 7)) << 3), lds + slab * 1024);
      int trow = slab * 2 + srow2;
      GLL(ts + trow * 256 + ((seg32 ^ (trow & 7)) << 3), lds + 32768 + slab * 1024);
    }
  }
  __syncthreads();
  const u16* qrow = q + ((long)bh * 8192 + n0 + (w << 4) + fr) * 64;
  bf16x8s qa0 = *(const bf16x8s*)(qrow + g * 8);
  bf16x8s qa1 = *(const bf16x8s*)(qrow + 32 + g * 8);
  f32x4 s[16];
#pragma unroll
  for (int c = 0; c < 16; ++c) {
    int j = (c << 4) + fr;
    bf16x8s b0 = *(const bf16x8s*)(lds + j * 128 + ((g ^ (j & 7)) << 4));
    bf16x8s b1 = *(const bf16x8s*)(lds + j * 128 + (((4 + g) ^ (j & 7)) << 4));
    f32x4 zz = {};
    zz = MFMA(qa0, b0, zz, 0, 0, 0);
    zz = MFMA(qa1, b1, zz, 0, 0, 0);
    s[c] = zz;
  }
  float li[4];
#pragma unroll
  for (int r = 0; r < 4; ++r) {
    float m = s[0][r];
#pragma unroll
    for (int c = 1; c < 16; ++c) m = fmaxf(m, s[c][r]);
    m = fmaxf(m, __shfl_xor(m, 1, 64));
    m = fmaxf(m, __shfl_xor(m, 2, 64));
    m = fmaxf(m, __shfl_xor(m, 4, 64));
    m = fmaxf(m, __shfl_xor(m, 8, 64));
    float l = 0.f;
#pragma unroll
    for (int c = 0; c < 16; ++c) {
      float e = __expf(s[c][r] - m);
      s[c][r] = e;
      l += e;
    }
    l += __shfl_xor(l, 1, 64);
    l += __shfl_xor(l, 2, 64);
    l += __shfl_xor(l, 4, 64);
    l += __shfl_xor(l, 8, 64);
    li[r] = 1.f / l;
  }
  __syncthreads();
#pragma unroll
  for (int c = 0; c < 16; ++c)
#pragma unroll
    for (int r = 0; r < 4; ++r) {
      int row = (w << 4) + (g << 2) + r;
      int byin = (c << 5) + (fr << 1);
      *(u16*)(lds + row * 512 + (byin ^ ((row & 7) << 4))) = f2b(s[c][r]);
    }
  asm volatile("s_waitcnt lgkmcnt(0)" ::: "memory");
  __builtin_amdgcn_sched_barrier(0);
  f32x4 o4[4] = {};
#pragma unroll
  for (int ss = 0; ss < 8; ++ss) {
    int prow = (w << 4) + fr;
    bf16x8s ap = *(const bf16x8s*)(lds + prow * 512 +
                                   (((ss * 64) + (g << 4)) ^ ((prow & 7) << 4)));
#pragma unroll
    for (int d = 0; d < 4; ++d) {
      int dh = (d << 4) + fr;
      bf16x8s bv = *(const bf16x8s*)(lds + 32768 + dh * 512 +
                                     (((ss * 4 + g) ^ (dh & 7)) << 4));
      o4[d] = MFMA(ap, bv, o4[d], 0, 0, 0);
    }
  }
  u16* ob = O + (((long)bb * 8192 + n0 + (w << 4)) << 9) + (hh << 6);
#pragma unroll
  for (int d = 0; d < 4; ++d)
#pragma unroll
    for (int r = 0; r < 4; ++r) {
      int row = (g << 2) + r;
      int col = (d << 4) + fr;
      ob[((long)row << 9) + col] = f2b(o4[d][r] * li[r]);
    }
}

// ---------------- host ----------------
extern "C" void kernel_launch(void* const* d_in, const int* in_sizes, int n_in,
                              void* d_out, int out_size, void* d_ws, size_t ws_size,
                              hipStream_t stream) {
  const float* x = (const float*)d_in[0];
  const float* z = (const float*)d_in[1];
  const float* Wq = (const float*)d_in[2];
  const float* Wkv = (const float*)d_in[3];
  const float* Wo = (const float*)d_in[4];
  const float* bo = (const float*)d_in[5];
  float* out = (float*)d_out;

  char* base = (char*)d_ws;
  size_t off = 0;
  auto alloc = [&](size_t bytes) -> void* {
    void* r = base + off;
    off = (off + bytes + 255) & ~(size_t)255;
    return r;
  };
  u16* qb = (u16*)alloc(33554432);
  u16* kb = (u16*)alloc(16777216);
  u16* vtb = (u16*)alloc(16777216);
  u16* PS = (u16*)alloc(67108864);    // T1 partials, then pinv state (16 x 4MB)
  float* attn2 = (float*)alloc(8388608);
  u16* xb = (u16*)alloc(33554432);    // dead after qproj -> Ob
  u16* zb = (u16*)alloc(16777216);    // dead after kvproj -> attn2 split aN
  u16* wqt = (u16*)alloc(524288);
  u16* wkvt = (u16*)alloc(1048576);
  u16* wot = (u16*)alloc(524288);
  u16* qlh = (u16*)alloc(1048576);
  u16* qll = (u16*)alloc(1048576);
  u16* klh = (u16*)alloc(1048576);
  u16* kll = (u16*)alloc(1048576);
  u16* T1t = (u16*)alloc(2097152);
  u16* T2t = (u16*)alloc(1048576);    // T2^T [bh][64 dh][256 m]
  unsigned* cmax = (unsigned*)alloc(256);
  const long MC = 2097152;
  u16 *ztA_Nhi = PS, *ztA_Nlo = PS + MC, *ztA_Thi = PS + 2 * MC, *ztA_Tlo = PS + 3 * MC;
  u16 *aNhi = zb, *aNlo = zb + MC;
  float* opart = (float*)PS;          // 8.4MB partials (consumed before prep/chain)
  float* pm_ = opart + 2097152;
  float* pl_ = pm_ + 32768;
  u16* T1thi = T1t;
  u16* T1tlo = T1t + 524288;
  u16* Ob = xb;

  hipMemsetAsync(cmax, 0, 4, stream);
  k_f2bxz<<<24576, 256, 0, stream>>>(x, z, xb, zb);
  k_wt3<<<4096, 256, 0, stream>>>(Wq, Wkv, Wo, wqt, wkvt, wot);

  k_gemm128<0><<<dim3(4, 256), 256, 0, stream>>>(xb, wqt, qb, nullptr, nullptr,
                                                 nullptr, 512);
  k_gemm128<1><<<dim3(8, 128), 256, 0, stream>>>(zb, wkvt, kb, vtb, nullptr,
                                                 nullptr, 512);
  k_land2<<<4096, 256, 0, stream>>>(qb, kb, qlh, qll, klh, kll);

  k_sim2<<<dim3(4, 32), 256, 0, stream>>>(qlh, qll, klh, kll, attn2, aNhi, aNlo);
  k_colmax<<<32, 256, 0, stream>>>(attn2, cmax);

  k_t1part<<<512, 256, 0, stream>>>(qlh, kb, vtb, opart, pm_, pl_);
  k_t1merge<<<dim3(4, 32), 256, 0, stream>>>(opart, pm_, pl_, T1thi, T1tlo);

  // z0 prep into PS (partials consumed by merge above), then the whole
  // Newton-Schulz chain + T2^T in ONE launch (block-local per bh).
  k_prep_pinv<<<dim3(4, 4, 32), 256, 0, stream>>>(attn2, cmax, ztA_Nhi, ztA_Nlo,
                                                  ztA_Thi, ztA_Tlo);
  k_pinv_chain<<<32, 512, 0, stream>>>(aNhi, aNlo, PS, T1thi, T1tlo, T2t);

  k_fused_attn1<<<dim3(128, 32), 256, 0, stream>>>(qb, klh, T2t, Ob);
  k_gemm128<2><<<dim3(4, 256), 256, 0, stream>>>(Ob, wot, out, nullptr, x, bo, 512);
}

// Round 12
// 613.385 us; speedup vs baseline: 4.0232x; 4.0232x over previous
//
#include <hip/hip_runtime.h>

typedef unsigned short u16;
typedef __attribute__((ext_vector_type(8))) short bf16x8s;
typedef __attribute__((ext_vector_type(4))) float f32x4;

#define DEV static __device__ __forceinline__

DEV float b2f(u16 v) { return __uint_as_float(((unsigned)v) << 16); }
// HW RNE f32->bf16 (1 VALU op)
DEV u16 f2b(float f) {
  unsigned r;
  asm("v_cvt_pk_bf16_f32 %0, %1, %1" : "=v"(r) : "v"(f));
  return (u16)r;
}
DEV unsigned f2b2(float a, float b) {
  unsigned r;
  asm("v_cvt_pk_bf16_f32 %0, %1, %2" : "=v"(r) : "v"(a), "v"(b));
  return r;
}

// async global->LDS, 16B per lane; lds base must be wave-uniform (HW adds lane*16)
#define GLL(gp, lp)                                                            \
  __builtin_amdgcn_global_load_lds(                                            \
      (const __attribute__((address_space(1))) unsigned int*)(gp),             \
      (__attribute__((address_space(3))) unsigned int*)(lp), 16, 0, 0)

#define MFMA __builtin_amdgcn_mfma_f32_16x16x32_bf16

// ---------------- fused converts: x and z fp32 -> bf16 ----------------------
__global__ __launch_bounds__(256) void k_f2bxz(const float* __restrict__ x,
                                               const float* __restrict__ z,
                                               u16* __restrict__ xb,
                                               u16* __restrict__ zb) {
  long i = (long)blockIdx.x * 256 + threadIdx.x;  // < 6291456
  const float* src;
  u16* dst;
  long j;
  if (i < 4194304) { src = x; dst = xb; j = i; }
  else { src = z; dst = zb; j = i - 4194304; }
  float4 v = *(const float4*)(src + j * 4);
  unsigned* d = (unsigned*)(dst + j * 4);
  d[0] = f2b2(v.x, v.y);
  d[1] = f2b2(v.z, v.w);
}

// ---------------- fused weight transposes: Wq, Wkv, Wo ----------------------
__global__ __launch_bounds__(256) void k_wt3(const float* __restrict__ Wq,
                                             const float* __restrict__ Wkv,
                                             const float* __restrict__ Wo,
                                             u16* __restrict__ wqt,
                                             u16* __restrict__ wkvt,
                                             u16* __restrict__ wot) {
  int e = blockIdx.x * 256 + threadIdx.x;  // < 1048576
  const float* W;
  u16* Wt;
  int N, le;
  if (e < 262144) { W = Wq; Wt = wqt; N = 512; le = e; }
  else if (e < 786432) { W = Wkv; Wt = wkvt; N = 1024; le = e - 262144; }
  else { W = Wo; Wt = wot; N = 512; le = e - 786432; }
  int nn = le >> 9, kk = le & 511;
  Wt[le] = f2b(W[(long)kk * N + nn]);
}

// ---------------- 128x128 bf16 NT GEMM (BK=64, global_load_lds, swizzled) ----
template <int MODE>
__global__ __launch_bounds__(256, 2) void k_gemm128(
    const u16* __restrict__ A, const u16* __restrict__ Bm, void* __restrict__ C0,
    void* __restrict__ C1, const float* __restrict__ xres,
    const float* __restrict__ bias, int K) {
  const int nwg = gridDim.x * gridDim.y;
  const int orig = blockIdx.y * gridDim.x + blockIdx.x;
  const int qq = nwg >> 3, rr = nwg & 7;
  const int xcd = orig & 7, loc = orig >> 3;
  const int swz = (xcd < rr ? xcd * (qq + 1) : rr * (qq + 1) + (xcd - rr) * qq) + loc;
  const int m0 = (swz / gridDim.x) << 7, n0 = (swz % gridDim.x) << 7;
  const int t = threadIdx.x, lane = t & 63, w = t >> 6;
  const int wm = (w >> 1) << 6, wn = (w & 1) << 6;
  const int fr = lane & 15, g = lane >> 4;
  __shared__ u16 As[8192];
  __shared__ u16 Bs[8192];
  f32x4 acc[4][4] = {};
  const int srow = t >> 3, scs = t & 7;
  for (int k0 = 0; k0 < K; k0 += 64) {
    __syncthreads();
#pragma unroll
    for (int i = 0; i < 4; ++i) {
      int row = srow + (i << 5), cs = scs;
      GLL(A + (long)(m0 + row) * K + k0 + ((cs ^ (row & 7)) << 3),
          &As[(i << 11) + (w << 9)]);
      GLL(Bm + (long)(n0 + row) * K + k0 + ((cs ^ (row & 7)) << 3),
          &Bs[(i << 11) + (w << 9)]);
    }
    __syncthreads();
#pragma unroll
    for (int ks = 0; ks < 2; ++ks) {
      bf16x8s af[4], bf[4];
#pragma unroll
      for (int fi = 0; fi < 4; ++fi) {
        int row = wm + fi * 16 + fr;
        af[fi] = *(const bf16x8s*)((const char*)As + row * 128 +
                                   (((ks * 4 + g) ^ (row & 7)) << 4));
      }
#pragma unroll
      for (int fj = 0; fj < 4; ++fj) {
        int row = wn + fj * 16 + fr;
        bf[fj] = *(const bf16x8s*)((const char*)Bs + row * 128 +
                                   (((ks * 4 + g) ^ (row & 7)) << 4));
      }
#pragma unroll
      for (int fi = 0; fi < 4; ++fi)
#pragma unroll
        for (int fj = 0; fj < 4; ++fj)
          acc[fi][fj] = MFMA(af[fi], bf[fj], acc[fi][fj], 0, 0, 0);
    }
  }
  const int crow = g << 2;
#pragma unroll
  for (int fi = 0; fi < 4; ++fi)
#pragma unroll
    for (int fj = 0; fj < 4; ++fj)
#pragma unroll
      for (int r = 0; r < 4; ++r) {
        int row = m0 + wm + fi * 16 + crow + r;
        int col = n0 + wn + fj * 16 + fr;
        float v = acc[fi][fj][r];
        if (MODE == 0) {
          int b = row >> 13, n = row & 8191, h = col >> 6, dh = col & 63;
          ((u16*)C0)[((((long)(b * 8 + h)) << 13) + n) * 64 + dh] = f2b(v * 0.125f);
        } else if (MODE == 1) {
          int b = row >> 12, nz = row & 4095;
          if (col < 512) {
            int h = col >> 6, dh = col & 63;
            ((u16*)C0)[((((long)(b * 8 + h)) << 12) + nz) * 64 + dh] = f2b(v);
          } else {
            int c2 = col - 512, h = c2 >> 6, dh = c2 & 63;
            ((u16*)C1)[((((long)(b * 8 + h) * 64 + dh)) << 12) + nz] = f2b(v);
          }
        } else if (MODE == 2) {
          long idx = ((long)row << 9) + col;
          ((float*)C0)[idx] = v + xres[idx] + bias[col];
        }
      }
}

// ---------------- fused landmarks (q then k): mean -> split hi/lo bf16 ------
__global__ __launch_bounds__(256) void k_land2(const u16* __restrict__ qb,
                                               const u16* __restrict__ kb,
                                               u16* __restrict__ qlh,
                                               u16* __restrict__ qll,
                                               u16* __restrict__ klh,
                                               u16* __restrict__ kll) {
  int pidx = blockIdx.x * 4 + (threadIdx.x >> 6);  // < 16384
  const u16* src;
  u16 *hi, *lo;
  int ntok, l;
  float inv;
  if (pidx < 8192) { src = qb; hi = qlh; lo = qll; ntok = 8192; l = 32; inv = 1.f / 32.f; }
  else { src = kb; hi = klh; lo = kll; ntok = 4096; l = 16; inv = 1.f / 16.f; pidx -= 8192; }
  int d = threadIdx.x & 63;
  int bh = pidx >> 8, m = pidx & 255;
  const u16* s = src + ((long)bh * ntok + (long)m * l) * 64 + d;
  float sum = 0.f;
  for (int j = 0; j < l; ++j) sum += b2f(s[j * 64]);
  sum *= inv;
  long o = ((long)bh * 256 + m) * 64 + d;
  u16 h = f2b(sum);
  hi[o] = h;
  lo[o] = f2b(sum - b2f(h));
}

// ---------------- sim2 + softmax via split-bf16 MFMA ------------------------
__global__ __launch_bounds__(256, 2) void k_sim2(
    const u16* __restrict__ qlh, const u16* __restrict__ qll,
    const u16* __restrict__ klh, const u16* __restrict__ kll,
    float* __restrict__ attn2, u16* __restrict__ aNhi, u16* __restrict__ aNlo) {
  const int rb = blockIdx.x, bh = blockIdx.y;
  const int t = threadIdx.x, lane = t & 63, w = t >> 6;
  const int fr = lane & 15, g = lane >> 4;
  __shared__ char lds[65536];
  {
    const u16* kh = klh + (long)bh * 16384;
    const u16* kl = kll + (long)bh * 16384;
    int srow8 = lane >> 3, cs7 = lane & 7;
#pragma unroll
    for (int i = 0; i < 8; ++i) {
      int slab = w * 8 + i;
      int krow = slab * 8 + srow8;
      GLL(kh + krow * 64 + ((cs7 ^ (krow & 7)) << 3), lds + slab * 1024);
      GLL(kl + krow * 64 + ((cs7 ^ (krow & 7)) << 3), lds + 32768 + slab * 1024);
    }
  }
  long qoff = ((long)bh * 256 + rb * 64 + w * 16 + fr) * 64;
  bf16x8s qh0 = *(const bf16x8s*)(qlh + qoff + g * 8);
  bf16x8s qh1 = *(const bf16x8s*)(qlh + qoff + 32 + g * 8);
  bf16x8s ql0 = *(const bf16x8s*)(qll + qoff + g * 8);
  bf16x8s ql1 = *(const bf16x8s*)(qll + qoff + 32 + g * 8);
  __syncthreads();
  f32x4 s[16];
#pragma unroll
  for (int c = 0; c < 16; ++c) {
    int j = (c << 4) + fr;
    int o0 = j * 128 + ((g ^ (j & 7)) << 4);
    int o1 = j * 128 + (((4 + g) ^ (j & 7)) << 4);
    bf16x8s kh0 = *(const bf16x8s*)(lds + o0);
    bf16x8s kh1 = *(const bf16x8s*)(lds + o1);
    bf16x8s kl0 = *(const bf16x8s*)(lds + 32768 + o0);
    bf16x8s kl1 = *(const bf16x8s*)(lds + 32768 + o1);
    f32x4 zz = {};
    zz = MFMA(qh0, kh0, zz, 0, 0, 0);
    zz = MFMA(qh1, kh1, zz, 0, 0, 0);
    zz = MFMA(qh0, kl0, zz, 0, 0, 0);
    zz = MFMA(qh1, kl1, zz, 0, 0, 0);
    zz = MFMA(ql0, kh0, zz, 0, 0, 0);
    zz = MFMA(ql1, kh1, zz, 0, 0, 0);
    s[c] = zz;
  }
  float li[4];
#pragma unroll
  for (int r = 0; r < 4; ++r) {
    float m = s[0][r];
#pragma unroll
    for (int c = 1; c < 16; ++c) m = fmaxf(m, s[c][r]);
    m = fmaxf(m, __shfl_xor(m, 1, 64));
    m = fmaxf(m, __shfl_xor(m, 2, 64));
    m = fmaxf(m, __shfl_xor(m, 4, 64));
    m = fmaxf(m, __shfl_xor(m, 8, 64));
    float l = 0.f;
#pragma unroll
    for (int c = 0; c < 16; ++c) {
      float e = __expf(s[c][r] - m);
      s[c][r] = e;
      l += e;
    }
    l += __shfl_xor(l, 1, 64);
    l += __shfl_xor(l, 2, 64);
    l += __shfl_xor(l, 4, 64);
    l += __shfl_xor(l, 8, 64);
    li[r] = 1.f / l;
  }
#pragma unroll
  for (int c = 0; c < 16; ++c)
#pragma unroll
    for (int r = 0; r < 4; ++r) {
      int row = rb * 64 + w * 16 + (g << 2) + r;
      int col = (c << 4) + fr;
      long idx = ((long)bh << 16) + ((long)row << 8) + col;
      float p = s[c][r] * li[r];
      attn2[idx] = p;
      u16 h = f2b(p);
      aNhi[idx] = h;
      aNlo[idx] = f2b(p - b2f(h));
    }
}

__global__ __launch_bounds__(256) void k_colmax(const float* __restrict__ attn2,
                                                unsigned* __restrict__ cmax) {
  int bh = blockIdx.x, j = threadIdx.x, lane = j & 63, w = j >> 6;
  const float* p = attn2 + ((long)bh << 16) + j;
  float s = 0.f;
  for (int m = 0; m < 256; ++m) s += p[m * 256];
  float mx = s;
  for (int o = 1; o < 64; o <<= 1) mx = fmaxf(mx, __shfl_xor(mx, o, 64));
  __shared__ float r1[4];
  if (lane == 0) r1[w] = mx;
  __syncthreads();
  if (j == 0) {
    mx = fmaxf(fmaxf(r1[0], r1[1]), fmaxf(r1[2], r1[3]));
    atomicMax(cmax, __float_as_uint(mx));
  }
}

// ---------------- T1 split-KV partial: (bh, rb, kc of 1024 keys) ------------
__global__ __launch_bounds__(256, 2) void k_t1part(
    const u16* __restrict__ qlb, const u16* __restrict__ kb,
    const u16* __restrict__ vtb, float* __restrict__ opart,
    float* __restrict__ pm_, float* __restrict__ pl_) {
  int orig = blockIdx.x;  // 512 = 32 bh * 4 kc * 4 rb
  int xcd = orig & 7, idx = orig >> 3;
  int p = xcd * 16 + (idx >> 2);
  int rb = idx & 3;
  int bh = p >> 2, kc = p & 3;
  const int t = threadIdx.x, lane = t & 63, w = t >> 6;
  const int fr = lane & 15, g = lane >> 4;
  __shared__ char lds[65536];
  const u16* qrow = qlb + ((long)bh * 256 + rb * 64 + w * 16 + fr) * 64;
  bf16x8s qa0 = *(const bf16x8s*)(qrow + g * 8);
  bf16x8s qa1 = *(const bf16x8s*)(qrow + 32 + g * 8);
  f32x4 o[4] = {};
  float m[4] = {-3e38f, -3e38f, -3e38f, -3e38f};
  float l[4] = {};
  const long kbase = (long)bh * 262144;
  for (int cc = 0; cc < 4; ++cc) {
    int c0 = kc * 1024 + cc * 256;
    __syncthreads();
#pragma unroll
    for (int i = 0; i < 8; ++i) {
      int seg = (i << 8) + t, row = seg >> 3, cs = seg & 7;
      GLL(kb + kbase + (long)(c0 + row) * 64 + ((cs ^ (row & 7)) << 3),
          lds + (i << 12) + (w << 10));
    }
#pragma unroll
    for (int i = 0; i < 8; ++i) {
      int seg = (i << 8) + t, row = seg >> 5, cs = seg & 31;
      GLL(vtb + kbase + (long)row * 4096 + c0 + ((cs ^ (row & 7)) << 3),
          lds + 32768 + (i << 12) + (w << 10));
    }
    __syncthreads();
    f32x4 s[16];
#pragma unroll
    for (int c = 0; c < 16; ++c) {
      int j = c * 16 + fr;
      bf16x8s b0 = *(const bf16x8s*)(lds + j * 128 + ((g ^ (j & 7)) << 4));
      bf16x8s b1 = *(const bf16x8s*)(lds + j * 128 + (((4 + g) ^ (j & 7)) << 4));
      f32x4 zz = {};
      zz = MFMA(qa0, b0, zz, 0, 0, 0);
      zz = MFMA(qa1, b1, zz, 0, 0, 0);
      s[c] = zz;
    }
    float sc[4];
#pragma unroll
    for (int r = 0; r < 4; ++r) {
      float pm = s[0][r];
#pragma unroll
      for (int c = 1; c < 16; ++c) pm = fmaxf(pm, s[c][r]);
      pm = fmaxf(pm, __shfl_xor(pm, 1, 64));
      pm = fmaxf(pm, __shfl_xor(pm, 2, 64));
      pm = fmaxf(pm, __shfl_xor(pm, 4, 64));
      pm = fmaxf(pm, __shfl_xor(pm, 8, 64));
      float mn = fmaxf(m[r], pm);
      sc[r] = __expf(m[r] - mn);
      m[r] = mn;
    }
#pragma unroll
    for (int r = 0; r < 4; ++r) {
      float su = 0.f;
#pragma unroll
      for (int c = 0; c < 16; ++c) {
        float e = __expf(s[c][r] - m[r]);
        s[c][r] = e;
        su += e;
      }
      su += __shfl_xor(su, 1, 64);
      su += __shfl_xor(su, 2, 64);
      su += __shfl_xor(su, 4, 64);
      su += __shfl_xor(su, 8, 64);
      l[r] = l[r] * sc[r] + su;
    }
#pragma unroll
    for (int d = 0; d < 4; ++d)
#pragma unroll
      for (int r = 0; r < 4; ++r) o[d][r] *= sc[r];
    __syncthreads();
#pragma unroll
    for (int c = 0; c < 16; ++c)
#pragma unroll
      for (int r = 0; r < 4; ++r) {
        int row = (w << 4) + (g << 2) + r;
        int byin = (c << 5) + (fr << 1);
        *(u16*)(lds + row * 512 + (byin ^ ((row & 7) << 4))) = f2b(s[c][r]);
      }
    asm volatile("s_waitcnt lgkmcnt(0)" ::: "memory");
    __builtin_amdgcn_sched_barrier(0);
#pragma unroll
    for (int ss = 0; ss < 8; ++ss) {
      int prow = (w << 4) + fr;
      bf16x8s ap = *(const bf16x8s*)(lds + prow * 512 +
                                     (((ss * 64) + (g << 4)) ^ ((prow & 7) << 4)));
#pragma unroll
      for (int d = 0; d < 4; ++d) {
        int dh = (d << 4) + fr;
        bf16x8s bv = *(const bf16x8s*)(lds + 32768 + dh * 512 +
                                       (((ss * 4 + g) ^ (dh & 7)) << 4));
        o[d] = MFMA(ap, bv, o[d], 0, 0, 0);
      }
    }
  }
  __syncthreads();
  float* lf = (float*)lds;
#pragma unroll
  for (int d = 0; d < 4; ++d)
#pragma unroll
    for (int r = 0; r < 4; ++r)
      lf[((w << 4) + (g << 2) + r) * 76 + (d << 4) + fr] = o[d][r];
  __syncthreads();
  const long pb = (long)(bh * 4 + kc) * 256 + rb * 64;
#pragma unroll
  for (int i = 0; i < 4; ++i) {
    int row = i * 16 + (t >> 4);
    int c4 = (t & 15) << 2;
    float4 v = *(const float4*)&lf[row * 76 + c4];
    *(float4*)&opart[(pb + row) * 64 + c4] = v;
  }
  if (fr == 0) {
#pragma unroll
    for (int r = 0; r < 4; ++r) {
      int lr = (w << 4) + (g << 2) + r;
      pm_[pb + lr] = m[r];
      pl_[pb + lr] = l[r];
    }
  }
}

// ---------------- merge 4 partials -> T1^T split bf16 -----------------------
__global__ __launch_bounds__(256) void k_t1merge(
    const float* __restrict__ opart, const float* __restrict__ pm_,
    const float* __restrict__ pl_, u16* __restrict__ T1thi,
    u16* __restrict__ T1tlo) {
  const int rb = blockIdx.x, bh = blockIdx.y;
  const int t = threadIdx.x;
#pragma unroll
  for (int rp = 0; rp < 4; ++rp) {
    int row = rb * 64 + rp * 16 + (t >> 4);
    int dh4 = (t & 15) << 2;
    float pmv[4], M = -3e38f;
#pragma unroll
    for (int i = 0; i < 4; ++i) {
      pmv[i] = pm_[(long)(bh * 4 + i) * 256 + row];
      M = fmaxf(M, pmv[i]);
    }
    float L = 0.f, wt[4];
#pragma unroll
    for (int i = 0; i < 4; ++i) {
      wt[i] = __expf(pmv[i] - M);
      L += pl_[(long)(bh * 4 + i) * 256 + row] * wt[i];
    }
    float4 acc = {0.f, 0.f, 0.f, 0.f};
#pragma unroll
    for (int i = 0; i < 4; ++i) {
      float4 v = *(const float4*)&opart[((long)(bh * 4 + i) * 256 + row) * 64 + dh4];
      acc.x += v.x * wt[i]; acc.y += v.y * wt[i];
      acc.z += v.z * wt[i]; acc.w += v.w * wt[i];
    }
    float invL = 1.f / L;
    float vv[4] = {acc.x * invL, acc.y * invL, acc.z * invL, acc.w * invL};
#pragma unroll
    for (int e = 0; e < 4; ++e) {
      int dh = dh4 + e;
      long idx = (long)bh * 16384 + (long)dh * 256 + row;
      u16 h = f2b(vv[e]);
      T1thi[idx] = h;
      T1tlo[idx] = f2b(vv[e] - b2f(h));
    }
  }
}

// ---------------- MFMA NN GEMM (pinv chain); NP=1 plain bf16, NP=3 split ----
template <int NP>
__global__ __launch_bounds__(256) void k_nn_mfma(
    const u16* __restrict__ Ahi, const u16* __restrict__ Alo,
    const u16* __restrict__ Bthi, const u16* __restrict__ Btlo,
    u16* __restrict__ CNhi, u16* __restrict__ CNlo,
    u16* __restrict__ CThi, u16* __restrict__ CTlo,
    int Nc, float sab, float sa, float cdiag) {
  const int bz = blockIdx.z;
  const long offA = (long)bz << 16;
  const long offB = (long)bz * ((long)Nc << 8);
  const int m0 = blockIdx.y << 6, n0 = blockIdx.x << 6;
  const int t = threadIdx.x, lane = t & 63, w = t >> 6;
  const int wm = (w >> 1) << 5, wn = (w & 1) << 5;
  const int fr = lane & 15, g = lane >> 4;
  __shared__ u16 lds[16384];
  u16* LAh = lds;
  u16* LAl = lds + 4096;
  u16* LBh = lds + 8192;
  u16* LBl = lds + 12288;
  f32x4 acc[2][2] = {};
  const int srow8 = lane >> 3, cs = lane & 7;
  for (int k0 = 0; k0 < 256; k0 += 64) {
    __syncthreads();
#pragma unroll
    for (int j = 0; j < 2; ++j) {
      int slab = w * 2 + j;
      int row = slab * 8 + srow8;
      long asrc = offA + (long)(m0 + row) * 256 + k0 + ((cs ^ (row & 7)) << 3);
      long bsrc = offB + (long)(n0 + row) * 256 + k0 + ((cs ^ (row & 7)) << 3);
      GLL(Ahi + asrc, LAh + slab * 512);
      GLL(Bthi + bsrc, LBh + slab * 512);
      if (NP == 3) {
        GLL(Alo + asrc, LAl + slab * 512);
        GLL(Btlo + bsrc, LBl + slab * 512);
      }
    }
    __syncthreads();
#pragma unroll
    for (int ks = 0; ks < 2; ++ks) {
      const int ra0 = wm + fr, ra1 = wm + 16 + fr;
      const int rb0 = wn + fr, rb1 = wn + 16 + fr;
#define RD(base, row) \
  (*(const bf16x8s*)((const char*)(base) + (row) * 128 + (((ks * 4 + g) ^ ((row) & 7)) << 4)))
      bf16x8s ah0 = RD(LAh, ra0), ah1 = RD(LAh, ra1);
      bf16x8s bh0 = RD(LBh, rb0), bh1 = RD(LBh, rb1);
      acc[0][0] = MFMA(ah0, bh0, acc[0][0], 0, 0, 0);
      acc[0][1] = MFMA(ah0, bh1, acc[0][1], 0, 0, 0);
      acc[1][0] = MFMA(ah1, bh0, acc[1][0], 0, 0, 0);
      acc[1][1] = MFMA(ah1, bh1, acc[1][1], 0, 0, 0);
      if (NP == 3) {
        bf16x8s al0 = RD(LAl, ra0), al1 = RD(LAl, ra1);
        bf16x8s bl0 = RD(LBl, rb0), bl1 = RD(LBl, rb1);
        acc[0][0] = MFMA(ah0, bl0, acc[0][0], 0, 0, 0);
        acc[0][0] = MFMA(al0, bh0, acc[0][0], 0, 0, 0);
        acc[0][1] = MFMA(ah0, bl1, acc[0][1], 0, 0, 0);
        acc[0][1] = MFMA(al0, bh1, acc[0][1], 0, 0, 0);
        acc[1][0] = MFMA(ah1, bl0, acc[1][0], 0, 0, 0);
        acc[1][0] = MFMA(al1, bh0, acc[1][0], 0, 0, 0);
        acc[1][1] = MFMA(ah1, bl1, acc[1][1], 0, 0, 0);
        acc[1][1] = MFMA(al1, bh1, acc[1][1], 0, 0, 0);
      }
#undef RD
    }
  }
  const int crow = g << 2;
  const long offC = (long)bz * ((long)Nc << 8);
#pragma unroll
  for (int i = 0; i < 2; ++i)
#pragma unroll
    for (int j = 0; j < 2; ++j)
#pragma unroll
      for (int r = 0; r < 4; ++r) {
        int row = m0 + wm + i * 16 + crow + r;
        int col = n0 + wn + j * 16 + fr;
        float v = sab * acc[i][j][r];
        if (sa != 0.f) {
          long ai = offA + ((long)row << 8) + col;
          v += sa * (b2f(Ahi[ai]) + b2f(Alo[ai]));
        }
        if (row == col) v += cdiag;
        if (CNhi) {
          long ci = offC + (long)row * Nc + col;
          u16 h = f2b(v);
          if (CNlo) { CNhi[ci] = h; CNlo[ci] = f2b(v - b2f(h)); }
          else CNhi[ci] = h;
        }
        if (CThi) {
          long ti = offC + ((long)col << 8) + row;
          u16 h = f2b(v);
          CThi[ti] = h;
          if (CTlo) CTlo[ti] = f2b(v - b2f(h));
        }
      }
}

// ---------------- pinv operand prep (z0 only; aN written by k_sim2) ---------
__global__ __launch_bounds__(256) void k_prep_pinv(
    const float* __restrict__ attn2, const unsigned* __restrict__ cmax,
    u16* __restrict__ zNhi, u16* __restrict__ zNlo,
    u16* __restrict__ zThi, u16* __restrict__ zTlo) {
  const int bz = blockIdx.z, i0 = blockIdx.y << 6, j0 = blockIdx.x << 6;
  const float s = 1.f / __uint_as_float(*cmax);
  const float* base = attn2 + ((long)bz << 16);
  __shared__ float mt[64][65];
  const int r = threadIdx.x >> 2, cb = (threadIdx.x & 3) << 4;
#pragma unroll
  for (int c4 = 0; c4 < 16; c4 += 4) {
    float4 v = *(const float4*)&base[(long)(j0 + r) * 256 + i0 + cb + c4];
    mt[r][cb + c4] = v.x; mt[r][cb + c4 + 1] = v.y;
    mt[r][cb + c4 + 2] = v.z; mt[r][cb + c4 + 3] = v.w;
  }
  __syncthreads();
  const int i = i0 + r;
#pragma unroll
  for (int c4 = 0; c4 < 16; c4 += 4) {
    float4 v = *(const float4*)&base[(long)i * 256 + j0 + cb + c4];
    float vv[4] = {v.x, v.y, v.z, v.w};
#pragma unroll
    for (int e = 0; e < 4; ++e) {
      int j = j0 + cb + c4 + e;
      long idx = ((long)bz << 16) + ((long)i << 8) + j;
      float zt = vv[e] * s;
      u16 zh = f2b(zt);
      zThi[idx] = zh; zTlo[idx] = f2b(zt - b2f(zh));
      float zn = mt[cb + c4 + e][r] * s;
      u16 nh = f2b(zn);
      zNhi[idx] = nh; zNlo[idx] = f2b(zn - b2f(nh));
    }
  }
}

// ---------------- fused sim1: O = softmax(q @ k_land^T) @ T2 ----------------
// 512 threads / 128 q-rows per block; P staged in two k-halves over the dead
// K region (wave-local rows) -> 64KB LDS, 2 blocks/CU, 16 waves/CU.
__global__ __launch_bounds__(512, 4) void k_fused_attn1(const u16* __restrict__ q,
                                                        const u16* __restrict__ klb,
                                                        const u16* __restrict__ t2t,
                                                        u16* __restrict__ O) {
  const int bh = blockIdx.y, n0 = blockIdx.x << 7;
  const int bb = bh >> 3, hh = bh & 7;
  const int t = threadIdx.x, lane = t & 63, w = t >> 6;  // 8 waves
  const int fr = lane & 15, g = lane >> 4;
  __shared__ char lds[65536];  // [0,32K) k_land (aliased by half-P); [32K,64K) T2^T
  {
    const u16* ks = klb + (long)bh * 16384;
    const u16* ts = t2t + (long)bh * 16384;
#pragma unroll
    for (int i = 0; i < 4; ++i) {
      // K: 2048 segs of 16B over 512 threads x 4 iters
      int seg = (i << 9) + t, row = seg >> 3, cs = seg & 7;
      GLL(ks + row * 64 + ((cs ^ (row & 7)) << 3), lds + (i << 13) + (w << 10));
      // T2: 32 slabs of 1KB (2 rows of 512B each)
      int slab = w * 4 + i;
      int trow = slab * 2 + (lane >> 5), cs32 = lane & 31;
      GLL(ts + trow * 256 + ((cs32 ^ (trow & 7)) << 3),
          lds + 32768 + slab * 1024);
    }
  }
  __syncthreads();
  const u16* qrow = q + ((long)bh * 8192 + n0 + (w << 4) + fr) * 64;
  bf16x8s qa0 = *(const bf16x8s*)(qrow + g * 8);
  bf16x8s qa1 = *(const bf16x8s*)(qrow + 32 + g * 8);
  f32x4 s[16];
#pragma unroll
  for (int c = 0; c < 16; ++c) {
    int j = (c << 4) + fr;
    bf16x8s b0 = *(const bf16x8s*)(lds + j * 128 + ((g ^ (j & 7)) << 4));
    bf16x8s b1 = *(const bf16x8s*)(lds + j * 128 + (((4 + g) ^ (j & 7)) << 4));
    f32x4 zz = {};
    zz = MFMA(qa0, b0, zz, 0, 0, 0);
    zz = MFMA(qa1, b1, zz, 0, 0, 0);
    s[c] = zz;
  }
  float li[4];
#pragma unroll
  for (int r = 0; r < 4; ++r) {
    float m = s[0][r];
#pragma unroll
    for (int c = 1; c < 16; ++c) m = fmaxf(m, s[c][r]);
    m = fmaxf(m, __shfl_xor(m, 1, 64));
    m = fmaxf(m, __shfl_xor(m, 2, 64));
    m = fmaxf(m, __shfl_xor(m, 4, 64));
    m = fmaxf(m, __shfl_xor(m, 8, 64));
    float l = 0.f;
#pragma unroll
    for (int c = 0; c < 16; ++c) {
      float e = __expf(s[c][r] - m);
      s[c][r] = e;
      l += e;
    }
    l += __shfl_xor(l, 1, 64);
    l += __shfl_xor(l, 2, 64);
    l += __shfl_xor(l, 4, 64);
    l += __shfl_xor(l, 8, 64);
    li[r] = 1.f / l;
  }
  __syncthreads();  // ALL waves done reading K; region becomes half-P [128][256B]
  f32x4 o4[4] = {};
#pragma unroll
  for (int p = 0; p < 2; ++p) {
    // write this wave's 16 P rows for k-half p (wave-local region rows)
#pragma unroll
    for (int c8 = 0; c8 < 8; ++c8) {
      int c = p * 8 + c8;
#pragma unroll
      for (int r = 0; r < 4; ++r) {
        int row = (w << 4) + (g << 2) + r;
        int byin = (c8 << 5) + (fr << 1);
        *(u16*)(lds + row * 256 + (byin ^ ((row & 7) << 4))) = f2b(s[c][r]);
      }
    }
    asm volatile("s_waitcnt lgkmcnt(0)" ::: "memory");
    __builtin_amdgcn_sched_barrier(0);
#pragma unroll
    for (int ss8 = 0; ss8 < 4; ++ss8) {
      int ss = p * 4 + ss8;
      int prow = (w << 4) + fr;
      bf16x8s ap = *(const bf16x8s*)(lds + prow * 256 +
                                     (((ss8 * 64) + (g << 4)) ^ ((prow & 7) << 4)));
#pragma unroll
      for (int d = 0; d < 4; ++d) {
        int dh = (d << 4) + fr;
        bf16x8s bv = *(const bf16x8s*)(lds + 32768 + dh * 512 +
                                       (((ss * 4 + g) ^ (dh & 7)) << 4));
        o4[d] = MFMA(ap, bv, o4[d], 0, 0, 0);
      }
    }
    asm volatile("s_waitcnt lgkmcnt(0)" ::: "memory");  // reads done before overwrite
    __builtin_amdgcn_sched_barrier(0);
  }
  u16* ob = O + (((long)bb * 8192 + n0 + (w << 4)) << 9) + (hh << 6);
#pragma unroll
  for (int d = 0; d < 4; ++d)
#pragma unroll
    for (int r = 0; r < 4; ++r) {
      int row = (g << 2) + r;
      int col = (d << 4) + fr;
      ob[((long)row << 9) + col] = f2b(o4[d][r] * li[r]);
    }
}

// ---------------- host ----------------
extern "C" void kernel_launch(void* const* d_in, const int* in_sizes, int n_in,
                              void* d_out, int out_size, void* d_ws, size_t ws_size,
                              hipStream_t stream) {
  const float* x = (const float*)d_in[0];
  const float* z = (const float*)d_in[1];
  const float* Wq = (const float*)d_in[2];
  const float* Wkv = (const float*)d_in[3];
  const float* Wo = (const float*)d_in[4];
  const float* bo = (const float*)d_in[5];
  float* out = (float*)d_out;

  char* base = (char*)d_ws;
  size_t off = 0;
  auto alloc = [&](size_t bytes) -> void* {
    void* r = base + off;
    off = (off + bytes + 255) & ~(size_t)255;
    return r;
  };
  u16* qb = (u16*)alloc(33554432);
  u16* kb = (u16*)alloc(16777216);
  u16* vtb = (u16*)alloc(16777216);
  u16* PS = (u16*)alloc(67108864);
  float* attn2 = (float*)alloc(8388608);
  u16* xb = (u16*)alloc(33554432);
  u16* zb = (u16*)alloc(16777216);
  u16* wqt = (u16*)alloc(524288);
  u16* wkvt = (u16*)alloc(1048576);
  u16* wot = (u16*)alloc(524288);
  u16* qlh = (u16*)alloc(1048576);
  u16* qll = (u16*)alloc(1048576);
  u16* klh = (u16*)alloc(1048576);
  u16* kll = (u16*)alloc(1048576);
  u16* T1t = (u16*)alloc(2097152);
  u16* T2t = (u16*)alloc(1048576);
  unsigned* cmax = (unsigned*)alloc(256);
  const long MC = 2097152;
  u16* P = PS;
  u16 *ztA_Nhi = P,          *ztA_Nlo = P + MC,      *ztA_Thi = P + 2 * MC,  *ztA_Tlo = P + 3 * MC;
  u16 *ztB_Nhi = P + 4 * MC,  *ztB_Nlo = P + 5 * MC,  *ztB_Thi = P + 6 * MC,  *ztB_Tlo = P + 7 * MC;
  u16 *az_Nhi = P + 8 * MC,   *az_Nlo = P + 9 * MC,   *az_Thi = P + 10 * MC,  *az_Tlo = P + 11 * MC;
  u16 *taThi = P + 12 * MC,   *taTlo = P + 13 * MC;
  u16 *tcThi = P + 14 * MC,   *tcTlo = P + 15 * MC;
  u16 *aNhi = zb, *aNlo = zb + MC;
  float* opart = (float*)PS;
  float* pm_ = opart + 2097152;
  float* pl_ = pm_ + 32768;
  u16* T1thi = T1t;
  u16* T1tlo = T1t + 524288;
  u16* Ob = xb;

  hipMemsetAsync(cmax, 0, 4, stream);
  k_f2bxz<<<24576, 256, 0, stream>>>(x, z, xb, zb);
  k_wt3<<<4096, 256, 0, stream>>>(Wq, Wkv, Wo, wqt, wkvt, wot);

  k_gemm128<0><<<dim3(4, 256), 256, 0, stream>>>(xb, wqt, qb, nullptr, nullptr,
                                                 nullptr, 512);
  k_gemm128<1><<<dim3(8, 128), 256, 0, stream>>>(zb, wkvt, kb, vtb, nullptr,
                                                 nullptr, 512);
  k_land2<<<4096, 256, 0, stream>>>(qb, kb, qlh, qll, klh, kll);

  k_sim2<<<dim3(4, 32), 256, 0, stream>>>(qlh, qll, klh, kll, attn2, aNhi, aNlo);
  k_colmax<<<32, 256, 0, stream>>>(attn2, cmax);

  k_t1part<<<512, 256, 0, stream>>>(qlh, kb, vtb, opart, pm_, pl_);
  k_t1merge<<<dim3(4, 32), 256, 0, stream>>>(opart, pm_, pl_, T1thi, T1tlo);

  k_prep_pinv<<<dim3(4, 4, 32), 256, 0, stream>>>(attn2, cmax, ztA_Nhi, ztA_Nlo,
                                                  ztA_Thi, ztA_Tlo);

  dim3 g256(4, 4, 32);
  u16 *cN0 = ztA_Nhi, *cN1 = ztA_Nlo, *cT0 = ztA_Thi, *cT1 = ztA_Tlo;
  u16 *nN0 = ztB_Nhi, *nN1 = ztB_Nlo, *nT0 = ztB_Thi, *nT1 = ztB_Tlo;
  for (int it = 0; it < 6; ++it) {
    bool last = (it == 5);
    if (it < 5) {
      k_nn_mfma<1><<<g256, 256, 0, stream>>>(aNhi, aNlo, cT0, cT1, az_Nhi, az_Nlo,
                                             az_Thi, az_Tlo, 256, 1.f, 0.f, 0.f);
      k_nn_mfma<1><<<g256, 256, 0, stream>>>(az_Nhi, az_Nlo, az_Thi, az_Tlo, nullptr,
                                             nullptr, taThi, taTlo, 256, 1.f, -7.f, 15.f);
      k_nn_mfma<1><<<g256, 256, 0, stream>>>(az_Nhi, az_Nlo, taThi, taTlo, nullptr,
                                             nullptr, tcThi, tcTlo, 256, -1.f, 0.f, 13.f);
      k_nn_mfma<1><<<g256, 256, 0, stream>>>(cN0, cN1, tcThi, tcTlo, nN0, nN1,
                                             nT0, nT1, 256, 0.25f, 0.f, 0.f);
    } else {
      k_nn_mfma<3><<<g256, 256, 0, stream>>>(aNhi, aNlo, cT0, cT1, az_Nhi, az_Nlo,
                                             az_Thi, az_Tlo, 256, 1.f, 0.f, 0.f);
      k_nn_mfma<3><<<g256, 256, 0, stream>>>(az_Nhi, az_Nlo, az_Thi, az_Tlo, nullptr,
                                             nullptr, taThi, taTlo, 256, 1.f, -7.f, 15.f);
      k_nn_mfma<3><<<g256, 256, 0, stream>>>(az_Nhi, az_Nlo, taThi, taTlo, nullptr,
                                             nullptr, tcThi, tcTlo, 256, -1.f, 0.f, 13.f);
      k_nn_mfma<3><<<g256, 256, 0, stream>>>(cN0, cN1, tcThi, tcTlo, nN0, nN1,
                                             last ? nullptr : nT0, last ? nullptr : nT1,
                                             256, 0.25f, 0.f, 0.f);
    }
    u16* t0;
    t0 = cN0; cN0 = nN0; nN0 = t0;  t0 = cN1; cN1 = nN1; nN1 = t0;
    t0 = cT0; cT0 = nT0; nT0 = t0;  t0 = cT1; cT1 = nT1; nT1 = t0;
  }
  k_nn_mfma<3><<<dim3(1, 4, 32), 256, 0, stream>>>(cN0, cN1, T1thi, T1tlo, nullptr,
                                                   nullptr, T2t, nullptr, 64,
                                                   1.f, 0.f, 0.f);

  k_fused_attn1<<<dim3(64, 32), 512, 0, stream>>>(qb, klh, T2t, Ob);
  k_gemm128<2><<<dim3(4, 256), 256, 0, stream>>>(Ob, wot, out, nullptr, x, bo, 512);
}

// Round 13
// 595.031 us; speedup vs baseline: 4.1473x; 1.0308x over previous
//
#include <hip/hip_runtime.h>

typedef unsigned short u16;
typedef __attribute__((ext_vector_type(8))) short bf16x8s;
typedef __attribute__((ext_vector_type(4))) float f32x4;

#define DEV static __device__ __forceinline__

DEV float b2f(u16 v) { return __uint_as_float(((unsigned)v) << 16); }
// HW RNE f32->bf16 (1 VALU op)
DEV u16 f2b(float f) {
  unsigned r;
  asm("v_cvt_pk_bf16_f32 %0, %1, %1" : "=v"(r) : "v"(f));
  return (u16)r;
}
DEV unsigned f2b2(float a, float b) {
  unsigned r;
  asm("v_cvt_pk_bf16_f32 %0, %1, %2" : "=v"(r) : "v"(a), "v"(b));
  return r;
}

// async global->LDS, 16B per lane; lds base must be wave-uniform (HW adds lane*16)
#define GLL(gp, lp)                                                            \
  __builtin_amdgcn_global_load_lds(                                            \
      (const __attribute__((address_space(1))) unsigned int*)(gp),             \
      (__attribute__((address_space(3))) unsigned int*)(lp), 16, 0, 0)

#define MFMA __builtin_amdgcn_mfma_f32_16x16x32_bf16

// ---------------- fused converts: x and z fp32 -> bf16 ----------------------
__global__ __launch_bounds__(256) void k_f2bxz(const float* __restrict__ x,
                                               const float* __restrict__ z,
                                               u16* __restrict__ xb,
                                               u16* __restrict__ zb) {
  long i = (long)blockIdx.x * 256 + threadIdx.x;  // < 6291456
  const float* src;
  u16* dst;
  long j;
  if (i < 4194304) { src = x; dst = xb; j = i; }
  else { src = z; dst = zb; j = i - 4194304; }
  float4 v = *(const float4*)(src + j * 4);
  unsigned* d = (unsigned*)(dst + j * 4);
  d[0] = f2b2(v.x, v.y);
  d[1] = f2b2(v.z, v.w);
}

// ---------------- fused weight transposes: Wq, Wkv, Wo ----------------------
__global__ __launch_bounds__(256) void k_wt3(const float* __restrict__ Wq,
                                             const float* __restrict__ Wkv,
                                             const float* __restrict__ Wo,
                                             u16* __restrict__ wqt,
                                             u16* __restrict__ wkvt,
                                             u16* __restrict__ wot) {
  int e = blockIdx.x * 256 + threadIdx.x;  // < 1048576
  const float* W;
  u16* Wt;
  int N, le;
  if (e < 262144) { W = Wq; Wt = wqt; N = 512; le = e; }
  else if (e < 786432) { W = Wkv; Wt = wkvt; N = 1024; le = e - 262144; }
  else { W = Wo; Wt = wot; N = 512; le = e - 786432; }
  int nn = le >> 9, kk = le & 511;
  Wt[le] = f2b(W[(long)kk * N + nn]);
}

// ---------------- 128x128 bf16 NT GEMM (BK=64, global_load_lds, swizzled) ----
// MODE 0/1: LDS-staged coalesced bf16x8 C-writeback (values bit-identical).
template <int MODE>
__global__ __launch_bounds__(256, 2) void k_gemm128(
    const u16* __restrict__ A, const u16* __restrict__ Bm, void* __restrict__ C0,
    void* __restrict__ C1, const float* __restrict__ xres,
    const float* __restrict__ bias, int K) {
  const int nwg = gridDim.x * gridDim.y;
  const int orig = blockIdx.y * gridDim.x + blockIdx.x;
  const int qq = nwg >> 3, rr = nwg & 7;
  const int xcd = orig & 7, loc = orig >> 3;
  const int swz = (xcd < rr ? xcd * (qq + 1) : rr * (qq + 1) + (xcd - rr) * qq) + loc;
  const int m0 = (swz / gridDim.x) << 7, n0 = (swz % gridDim.x) << 7;
  const int t = threadIdx.x, lane = t & 63, w = t >> 6;
  const int wm = (w >> 1) << 6, wn = (w & 1) << 6;
  const int fr = lane & 15, g = lane >> 4;
  __shared__ u16 sh[16384];  // As | Bs ; reused as C-staging after main loop
  u16* As = sh;
  u16* Bs = sh + 8192;
  f32x4 acc[4][4] = {};
  const int srow = t >> 3, scs = t & 7;
  for (int k0 = 0; k0 < K; k0 += 64) {
    __syncthreads();
#pragma unroll
    for (int i = 0; i < 4; ++i) {
      int row = srow + (i << 5), cs = scs;
      GLL(A + (long)(m0 + row) * K + k0 + ((cs ^ (row & 7)) << 3),
          &As[(i << 11) + (w << 9)]);
      GLL(Bm + (long)(n0 + row) * K + k0 + ((cs ^ (row & 7)) << 3),
          &Bs[(i << 11) + (w << 9)]);
    }
    __syncthreads();
#pragma unroll
    for (int ks = 0; ks < 2; ++ks) {
      bf16x8s af[4], bf[4];
#pragma unroll
      for (int fi = 0; fi < 4; ++fi) {
        int row = wm + fi * 16 + fr;
        af[fi] = *(const bf16x8s*)((const char*)As + row * 128 +
                                   (((ks * 4 + g) ^ (row & 7)) << 4));
      }
#pragma unroll
      for (int fj = 0; fj < 4; ++fj) {
        int row = wn + fj * 16 + fr;
        bf[fj] = *(const bf16x8s*)((const char*)Bs + row * 128 +
                                   (((ks * 4 + g) ^ (row & 7)) << 4));
      }
#pragma unroll
      for (int fi = 0; fi < 4; ++fi)
#pragma unroll
        for (int fj = 0; fj < 4; ++fj)
          acc[fi][fj] = MFMA(af[fi], bf[fj], acc[fi][fj], 0, 0, 0);
    }
  }
  const int crow = g << 2;
  if (MODE == 2) {
#pragma unroll
    for (int fi = 0; fi < 4; ++fi)
#pragma unroll
      for (int fj = 0; fj < 4; ++fj)
#pragma unroll
        for (int r = 0; r < 4; ++r) {
          int row = m0 + wm + fi * 16 + crow + r;
          int col = n0 + wn + fj * 16 + fr;
          long idx = ((long)row << 9) + col;
          ((float*)C0)[idx] = acc[fi][fj][r] + xres[idx] + bias[col];
        }
  } else {
    // stage C tile (bf16) in LDS, then coalesced bf16x8 stores
    __syncthreads();  // all tile readers done; reuse sh as [128 rows][256B]
    char* Cs = (char*)sh;
    const float scale = (MODE == 0) ? 0.125f : 1.f;
#pragma unroll
    for (int fi = 0; fi < 4; ++fi)
#pragma unroll
      for (int fj = 0; fj < 4; ++fj)
#pragma unroll
        for (int r = 0; r < 4; ++r) {
          int row = wm + fi * 16 + crow + r;
          int colb = (wn + fj * 16 + fr) << 1;
          *(u16*)(Cs + ((row * 256 + colb) ^ ((row & 7) << 4))) =
              f2b(acc[fi][fj][r] * scale);
        }
    __syncthreads();
    const bool vt = (MODE == 1) && (n0 >= 512);
    if (!vt) {
      // dh-contiguous layouts: 2048 segs of 16B, fully coalesced
#pragma unroll
      for (int i = 0; i < 8; ++i) {
        int seg = (i << 8) + t;
        int row = seg >> 4, cs = seg & 15;
        bf16x8s v = *(const bf16x8s*)(Cs +
                        ((row * 256 + (cs << 4)) ^ ((row & 7) << 4)));
        int m = m0 + row;
        int colg = n0 + (cs << 3);
        int h = colg >> 6, dh0 = colg & 63;
        if (MODE == 0) {
          int b = m >> 13, n = m & 8191;
          *(bf16x8s*)((u16*)C0 + ((((long)(b * 8 + h)) << 13) + n) * 64 + dh0) = v;
        } else {
          int b = m >> 12, nz = m & 4095;
          *(bf16x8s*)((u16*)C0 + ((((long)(b * 8 + h)) << 12) + nz) * 64 + dh0) = v;
        }
      }
    } else {
      // v^T half: gather 8 rows (nz) per dh -> one 16B store
#pragma unroll
      for (int i = 0; i < 8; ++i) {
        int seg = (i << 8) + t;
        int col = seg & 127;     // lane-fast col: conflict-free LDS reads
        int r0 = (seg >> 7) << 3;
        bf16x8s v;
#pragma unroll
        for (int j = 0; j < 8; ++j) {
          int rr = r0 + j;
          v[j] = *(const short*)(Cs + ((rr * 256 + (col << 1)) ^ ((rr & 7) << 4)));
        }
        int m = m0 + r0;
        int b = m >> 12, nz0 = m & 4095;
        int c2 = n0 + col - 512;
        int h = c2 >> 6, dh = c2 & 63;
        *(bf16x8s*)((u16*)C1 + ((((long)(b * 8 + h) * 64 + dh)) << 12) + nz0) = v;
      }
    }
  }
}

// ---------------- fused landmarks (q then k): mean -> split hi/lo bf16 ------
__global__ __launch_bounds__(256) void k_land2(const u16* __restrict__ qb,
                                               const u16* __restrict__ kb,
                                               u16* __restrict__ qlh,
                                               u16* __restrict__ qll,
                                               u16* __restrict__ klh,
                                               u16* __restrict__ kll) {
  int pidx = blockIdx.x * 4 + (threadIdx.x >> 6);  // < 16384
  const u16* src;
  u16 *hi, *lo;
  int ntok, l;
  float inv;
  if (pidx < 8192) { src = qb; hi = qlh; lo = qll; ntok = 8192; l = 32; inv = 1.f / 32.f; }
  else { src = kb; hi = klh; lo = kll; ntok = 4096; l = 16; inv = 1.f / 16.f; pidx -= 8192; }
  int d = threadIdx.x & 63;
  int bh = pidx >> 8, m = pidx & 255;
  const u16* s = src + ((long)bh * ntok + (long)m * l) * 64 + d;
  float sum = 0.f;
  for (int j = 0; j < l; ++j) sum += b2f(s[j * 64]);
  sum *= inv;
  long o = ((long)bh * 256 + m) * 64 + d;
  u16 h = f2b(sum);
  hi[o] = h;
  lo[o] = f2b(sum - b2f(h));
}

// ---------------- sim2 + softmax via split-bf16 MFMA ------------------------
__global__ __launch_bounds__(256, 2) void k_sim2(
    const u16* __restrict__ qlh, const u16* __restrict__ qll,
    const u16* __restrict__ klh, const u16* __restrict__ kll,
    float* __restrict__ attn2, u16* __restrict__ aNhi, u16* __restrict__ aNlo) {
  const int rb = blockIdx.x, bh = blockIdx.y;
  const int t = threadIdx.x, lane = t & 63, w = t >> 6;
  const int fr = lane & 15, g = lane >> 4;
  __shared__ char lds[65536];
  {
    const u16* kh = klh + (long)bh * 16384;
    const u16* kl = kll + (long)bh * 16384;
    int srow8 = lane >> 3, cs7 = lane & 7;
#pragma unroll
    for (int i = 0; i < 8; ++i) {
      int slab = w * 8 + i;
      int krow = slab * 8 + srow8;
      GLL(kh + krow * 64 + ((cs7 ^ (krow & 7)) << 3), lds + slab * 1024);
      GLL(kl + krow * 64 + ((cs7 ^ (krow & 7)) << 3), lds + 32768 + slab * 1024);
    }
  }
  long qoff = ((long)bh * 256 + rb * 64 + w * 16 + fr) * 64;
  bf16x8s qh0 = *(const bf16x8s*)(qlh + qoff + g * 8);
  bf16x8s qh1 = *(const bf16x8s*)(qlh + qoff + 32 + g * 8);
  bf16x8s ql0 = *(const bf16x8s*)(qll + qoff + g * 8);
  bf16x8s ql1 = *(const bf16x8s*)(qll + qoff + 32 + g * 8);
  __syncthreads();
  f32x4 s[16];
#pragma unroll
  for (int c = 0; c < 16; ++c) {
    int j = (c << 4) + fr;
    int o0 = j * 128 + ((g ^ (j & 7)) << 4);
    int o1 = j * 128 + (((4 + g) ^ (j & 7)) << 4);
    bf16x8s kh0 = *(const bf16x8s*)(lds + o0);
    bf16x8s kh1 = *(const bf16x8s*)(lds + o1);
    bf16x8s kl0 = *(const bf16x8s*)(lds + 32768 + o0);
    bf16x8s kl1 = *(const bf16x8s*)(lds + 32768 + o1);
    f32x4 zz = {};
    zz = MFMA(qh0, kh0, zz, 0, 0, 0);
    zz = MFMA(qh1, kh1, zz, 0, 0, 0);
    zz = MFMA(qh0, kl0, zz, 0, 0, 0);
    zz = MFMA(qh1, kl1, zz, 0, 0, 0);
    zz = MFMA(ql0, kh0, zz, 0, 0, 0);
    zz = MFMA(ql1, kh1, zz, 0, 0, 0);
    s[c] = zz;
  }
  float li[4];
#pragma unroll
  for (int r = 0; r < 4; ++r) {
    float m = s[0][r];
#pragma unroll
    for (int c = 1; c < 16; ++c) m = fmaxf(m, s[c][r]);
    m = fmaxf(m, __shfl_xor(m, 1, 64));
    m = fmaxf(m, __shfl_xor(m, 2, 64));
    m = fmaxf(m, __shfl_xor(m, 4, 64));
    m = fmaxf(m, __shfl_xor(m, 8, 64));
    float l = 0.f;
#pragma unroll
    for (int c = 0; c < 16; ++c) {
      float e = __expf(s[c][r] - m);
      s[c][r] = e;
      l += e;
    }
    l += __shfl_xor(l, 1, 64);
    l += __shfl_xor(l, 2, 64);
    l += __shfl_xor(l, 4, 64);
    l += __shfl_xor(l, 8, 64);
    li[r] = 1.f / l;
  }
#pragma unroll
  for (int c = 0; c < 16; ++c)
#pragma unroll
    for (int r = 0; r < 4; ++r) {
      int row = rb * 64 + w * 16 + (g << 2) + r;
      int col = (c << 4) + fr;
      long idx = ((long)bh << 16) + ((long)row << 8) + col;
      float p = s[c][r] * li[r];
      attn2[idx] = p;
      u16 h = f2b(p);
      aNhi[idx] = h;
      aNlo[idx] = f2b(p - b2f(h));
    }
}

__global__ __launch_bounds__(256) void k_colmax(const float* __restrict__ attn2,
                                                unsigned* __restrict__ cmax) {
  int bh = blockIdx.x, j = threadIdx.x, lane = j & 63, w = j >> 6;
  const float* p = attn2 + ((long)bh << 16) + j;
  float s = 0.f;
  for (int m = 0; m < 256; ++m) s += p[m * 256];
  float mx = s;
  for (int o = 1; o < 64; o <<= 1) mx = fmaxf(mx, __shfl_xor(mx, o, 64));
  __shared__ float r1[4];
  if (lane == 0) r1[w] = mx;
  __syncthreads();
  if (j == 0) {
    mx = fmaxf(fmaxf(r1[0], r1[1]), fmaxf(r1[2], r1[3]));
    atomicMax(cmax, __float_as_uint(mx));
  }
}

// ---------------- T1 split-KV partial: (bh, rb, kc of 1024 keys) ------------
__global__ __launch_bounds__(256, 2) void k_t1part(
    const u16* __restrict__ qlb, const u16* __restrict__ kb,
    const u16* __restrict__ vtb, float* __restrict__ opart,
    float* __restrict__ pm_, float* __restrict__ pl_) {
  int orig = blockIdx.x;  // 512 = 32 bh * 4 kc * 4 rb
  int xcd = orig & 7, idx = orig >> 3;
  int p = xcd * 16 + (idx >> 2);
  int rb = idx & 3;
  int bh = p >> 2, kc = p & 3;
  const int t = threadIdx.x, lane = t & 63, w = t >> 6;
  const int fr = lane & 15, g = lane >> 4;
  __shared__ char lds[65536];
  const u16* qrow = qlb + ((long)bh * 256 + rb * 64 + w * 16 + fr) * 64;
  bf16x8s qa0 = *(const bf16x8s*)(qrow + g * 8);
  bf16x8s qa1 = *(const bf16x8s*)(qrow + 32 + g * 8);
  f32x4 o[4] = {};
  float m[4] = {-3e38f, -3e38f, -3e38f, -3e38f};
  float l[4] = {};
  const long kbase = (long)bh * 262144;
  for (int cc = 0; cc < 4; ++cc) {
    int c0 = kc * 1024 + cc * 256;
    __syncthreads();
#pragma unroll
    for (int i = 0; i < 8; ++i) {
      int seg = (i << 8) + t, row = seg >> 3, cs = seg & 7;
      GLL(kb + kbase + (long)(c0 + row) * 64 + ((cs ^ (row & 7)) << 3),
          lds + (i << 12) + (w << 10));
    }
#pragma unroll
    for (int i = 0; i < 8; ++i) {
      int seg = (i << 8) + t, row = seg >> 5, cs = seg & 31;
      GLL(vtb + kbase + (long)row * 4096 + c0 + ((cs ^ (row & 7)) << 3),
          lds + 32768 + (i << 12) + (w << 10));
    }
    __syncthreads();
    f32x4 s[16];
#pragma unroll
    for (int c = 0; c < 16; ++c) {
      int j = c * 16 + fr;
      bf16x8s b0 = *(const bf16x8s*)(lds + j * 128 + ((g ^ (j & 7)) << 4));
      bf16x8s b1 = *(const bf16x8s*)(lds + j * 128 + (((4 + g) ^ (j & 7)) << 4));
      f32x4 zz = {};
      zz = MFMA(qa0, b0, zz, 0, 0, 0);
      zz = MFMA(qa1, b1, zz, 0, 0, 0);
      s[c] = zz;
    }
    float sc[4];
#pragma unroll
    for (int r = 0; r < 4; ++r) {
      float pm = s[0][r];
#pragma unroll
      for (int c = 1; c < 16; ++c) pm = fmaxf(pm, s[c][r]);
      pm = fmaxf(pm, __shfl_xor(pm, 1, 64));
      pm = fmaxf(pm, __shfl_xor(pm, 2, 64));
      pm = fmaxf(pm, __shfl_xor(pm, 4, 64));
      pm = fmaxf(pm, __shfl_xor(pm, 8, 64));
      float mn = fmaxf(m[r], pm);
      sc[r] = __expf(m[r] - mn);
      m[r] = mn;
    }
#pragma unroll
    for (int r = 0; r < 4; ++r) {
      float su = 0.f;
#pragma unroll
      for (int c = 0; c < 16; ++c) {
        float e = __expf(s[c][r] - m[r]);
        s[c][r] = e;
        su += e;
      }
      su += __shfl_xor(su, 1, 64);
      su += __shfl_xor(su, 2, 64);
      su += __shfl_xor(su, 4, 64);
      su += __shfl_xor(su, 8, 64);
      l[r] = l[r] * sc[r] + su;
    }
#pragma unroll
    for (int d = 0; d < 4; ++d)
#pragma unroll
      for (int r = 0; r < 4; ++r) o[d][r] *= sc[r];
    __syncthreads();
#pragma unroll
    for (int c = 0; c < 16; ++c)
#pragma unroll
      for (int r = 0; r < 4; ++r) {
        int row = (w << 4) + (g << 2) + r;
        int byin = (c << 5) + (fr << 1);
        *(u16*)(lds + row * 512 + (byin ^ ((row & 7) << 4))) = f2b(s[c][r]);
      }
    asm volatile("s_waitcnt lgkmcnt(0)" ::: "memory");
    __builtin_amdgcn_sched_barrier(0);
#pragma unroll
    for (int ss = 0; ss < 8; ++ss) {
      int prow = (w << 4) + fr;
      bf16x8s ap = *(const bf16x8s*)(lds + prow * 512 +
                                     (((ss * 64) + (g << 4)) ^ ((prow & 7) << 4)));
#pragma unroll
      for (int d = 0; d < 4; ++d) {
        int dh = (d << 4) + fr;
        bf16x8s bv = *(const bf16x8s*)(lds + 32768 + dh * 512 +
                                       (((ss * 4 + g) ^ (dh & 7)) << 4));
        o[d] = MFMA(ap, bv, o[d], 0, 0, 0);
      }
    }
  }
  __syncthreads();
  float* lf = (float*)lds;
#pragma unroll
  for (int d = 0; d < 4; ++d)
#pragma unroll
    for (int r = 0; r < 4; ++r)
      lf[((w << 4) + (g << 2) + r) * 76 + (d << 4) + fr] = o[d][r];
  __syncthreads();
  const long pb = (long)(bh * 4 + kc) * 256 + rb * 64;
#pragma unroll
  for (int i = 0; i < 4; ++i) {
    int row = i * 16 + (t >> 4);
    int c4 = (t & 15) << 2;
    float4 v = *(const float4*)&lf[row * 76 + c4];
    *(float4*)&opart[(pb + row) * 64 + c4] = v;
  }
  if (fr == 0) {
#pragma unroll
    for (int r = 0; r < 4; ++r) {
      int lr = (w << 4) + (g << 2) + r;
      pm_[pb + lr] = m[r];
      pl_[pb + lr] = l[r];
    }
  }
}

// ---------------- merge 4 partials -> T1^T split bf16 -----------------------
__global__ __launch_bounds__(256) void k_t1merge(
    const float* __restrict__ opart, const float* __restrict__ pm_,
    const float* __restrict__ pl_, u16* __restrict__ T1thi,
    u16* __restrict__ T1tlo) {
  const int rb = blockIdx.x, bh = blockIdx.y;
  const int t = threadIdx.x;
#pragma unroll
  for (int rp = 0; rp < 4; ++rp) {
    int row = rb * 64 + rp * 16 + (t >> 4);
    int dh4 = (t & 15) << 2;
    float pmv[4], M = -3e38f;
#pragma unroll
    for (int i = 0; i < 4; ++i) {
      pmv[i] = pm_[(long)(bh * 4 + i) * 256 + row];
      M = fmaxf(M, pmv[i]);
    }
    float L = 0.f, wt[4];
#pragma unroll
    for (int i = 0; i < 4; ++i) {
      wt[i] = __expf(pmv[i] - M);
      L += pl_[(long)(bh * 4 + i) * 256 + row] * wt[i];
    }
    float4 acc = {0.f, 0.f, 0.f, 0.f};
#pragma unroll
    for (int i = 0; i < 4; ++i) {
      float4 v = *(const float4*)&opart[((long)(bh * 4 + i) * 256 + row) * 64 + dh4];
      acc.x += v.x * wt[i]; acc.y += v.y * wt[i];
      acc.z += v.z * wt[i]; acc.w += v.w * wt[i];
    }
    float invL = 1.f / L;
    float vv[4] = {acc.x * invL, acc.y * invL, acc.z * invL, acc.w * invL};
#pragma unroll
    for (int e = 0; e < 4; ++e) {
      int dh = dh4 + e;
      long idx = (long)bh * 16384 + (long)dh * 256 + row;
      u16 h = f2b(vv[e]);
      T1thi[idx] = h;
      T1tlo[idx] = f2b(vv[e] - b2f(h));
    }
  }
}

// ---------------- MFMA NN GEMM (pinv chain); NP=1 plain bf16, NP=3 split ----
template <int NP>
__global__ __launch_bounds__(256) void k_nn_mfma(
    const u16* __restrict__ Ahi, const u16* __restrict__ Alo,
    const u16* __restrict__ Bthi, const u16* __restrict__ Btlo,
    u16* __restrict__ CNhi, u16* __restrict__ CNlo,
    u16* __restrict__ CThi, u16* __restrict__ CTlo,
    int Nc, float sab, float sa, float cdiag) {
  const int bz = blockIdx.z;
  const long offA = (long)bz << 16;
  const long offB = (long)bz * ((long)Nc << 8);
  const int m0 = blockIdx.y << 6, n0 = blockIdx.x << 6;
  const int t = threadIdx.x, lane = t & 63, w = t >> 6;
  const int wm = (w >> 1) << 5, wn = (w & 1) << 5;
  const int fr = lane & 15, g = lane >> 4;
  __shared__ u16 lds[16384];
  u16* LAh = lds;
  u16* LAl = lds + 4096;
  u16* LBh = lds + 8192;
  u16* LBl = lds + 12288;
  f32x4 acc[2][2] = {};
  const int srow8 = lane >> 3, cs = lane & 7;
  for (int k0 = 0; k0 < 256; k0 += 64) {
    __syncthreads();
#pragma unroll
    for (int j = 0; j < 2; ++j) {
      int slab = w * 2 + j;
      int row = slab * 8 + srow8;
      long asrc = offA + (long)(m0 + row) * 256 + k0 + ((cs ^ (row & 7)) << 3);
      long bsrc = offB + (long)(n0 + row) * 256 + k0 + ((cs ^ (row & 7)) << 3);
      GLL(Ahi + asrc, LAh + slab * 512);
      GLL(Bthi + bsrc, LBh + slab * 512);
      if (NP == 3) {
        GLL(Alo + asrc, LAl + slab * 512);
        GLL(Btlo + bsrc, LBl + slab * 512);
      }
    }
    __syncthreads();
#pragma unroll
    for (int ks = 0; ks < 2; ++ks) {
      const int ra0 = wm + fr, ra1 = wm + 16 + fr;
      const int rb0 = wn + fr, rb1 = wn + 16 + fr;
#define RD(base, row) \
  (*(const bf16x8s*)((const char*)(base) + (row) * 128 + (((ks * 4 + g) ^ ((row) & 7)) << 4)))
      bf16x8s ah0 = RD(LAh, ra0), ah1 = RD(LAh, ra1);
      bf16x8s bh0 = RD(LBh, rb0), bh1 = RD(LBh, rb1);
      acc[0][0] = MFMA(ah0, bh0, acc[0][0], 0, 0, 0);
      acc[0][1] = MFMA(ah0, bh1, acc[0][1], 0, 0, 0);
      acc[1][0] = MFMA(ah1, bh0, acc[1][0], 0, 0, 0);
      acc[1][1] = MFMA(ah1, bh1, acc[1][1], 0, 0, 0);
      if (NP == 3) {
        bf16x8s al0 = RD(LAl, ra0), al1 = RD(LAl, ra1);
        bf16x8s bl0 = RD(LBl, rb0), bl1 = RD(LBl, rb1);
        acc[0][0] = MFMA(ah0, bl0, acc[0][0], 0, 0, 0);
        acc[0][0] = MFMA(al0, bh0, acc[0][0], 0, 0, 0);
        acc[0][1] = MFMA(ah0, bl1, acc[0][1], 0, 0, 0);
        acc[0][1] = MFMA(al0, bh1, acc[0][1], 0, 0, 0);
        acc[1][0] = MFMA(ah1, bl0, acc[1][0], 0, 0, 0);
        acc[1][0] = MFMA(al1, bh0, acc[1][0], 0, 0, 0);
        acc[1][1] = MFMA(ah1, bl1, acc[1][1], 0, 0, 0);
        acc[1][1] = MFMA(al1, bh1, acc[1][1], 0, 0, 0);
      }
#undef RD
    }
  }
  const int crow = g << 2;
  const long offC = (long)bz * ((long)Nc << 8);
#pragma unroll
  for (int i = 0; i < 2; ++i)
#pragma unroll
    for (int j = 0; j < 2; ++j)
#pragma unroll
      for (int r = 0; r < 4; ++r) {
        int row = m0 + wm + i * 16 + crow + r;
        int col = n0 + wn + j * 16 + fr;
        float v = sab * acc[i][j][r];
        if (sa != 0.f) {
          long ai = offA + ((long)row << 8) + col;
          v += sa * (b2f(Ahi[ai]) + b2f(Alo[ai]));
        }
        if (row == col) v += cdiag;
        if (CNhi) {
          long ci = offC + (long)row * Nc + col;
          u16 h = f2b(v);
          if (CNlo) { CNhi[ci] = h; CNlo[ci] = f2b(v - b2f(h)); }
          else CNhi[ci] = h;
        }
        if (CThi) {
          long ti = offC + ((long)col << 8) + row;
          u16 h = f2b(v);
          CThi[ti] = h;
          if (CTlo) CTlo[ti] = f2b(v - b2f(h));
        }
      }
}

// ---------------- pinv operand prep (z0 only; aN written by k_sim2) ---------
__global__ __launch_bounds__(256) void k_prep_pinv(
    const float* __restrict__ attn2, const unsigned* __restrict__ cmax,
    u16* __restrict__ zNhi, u16* __restrict__ zNlo,
    u16* __restrict__ zThi, u16* __restrict__ zTlo) {
  const int bz = blockIdx.z, i0 = blockIdx.y << 6, j0 = blockIdx.x << 6;
  const float s = 1.f / __uint_as_float(*cmax);
  const float* base = attn2 + ((long)bz << 16);
  __shared__ float mt[64][65];
  const int r = threadIdx.x >> 2, cb = (threadIdx.x & 3) << 4;
#pragma unroll
  for (int c4 = 0; c4 < 16; c4 += 4) {
    float4 v = *(const float4*)&base[(long)(j0 + r) * 256 + i0 + cb + c4];
    mt[r][cb + c4] = v.x; mt[r][cb + c4 + 1] = v.y;
    mt[r][cb + c4 + 2] = v.z; mt[r][cb + c4 + 3] = v.w;
  }
  __syncthreads();
  const int i = i0 + r;
#pragma unroll
  for (int c4 = 0; c4 < 16; c4 += 4) {
    float4 v = *(const float4*)&base[(long)i * 256 + j0 + cb + c4];
    float vv[4] = {v.x, v.y, v.z, v.w};
#pragma unroll
    for (int e = 0; e < 4; ++e) {
      int j = j0 + cb + c4 + e;
      long idx = ((long)bz << 16) + ((long)i << 8) + j;
      float zt = vv[e] * s;
      u16 zh = f2b(zt);
      zThi[idx] = zh; zTlo[idx] = f2b(zt - b2f(zh));
      float zn = mt[cb + c4 + e][r] * s;
      u16 nh = f2b(zn);
      zNhi[idx] = nh; zNlo[idx] = f2b(zn - b2f(nh));
    }
  }
}

// ---------------- fused sim1: O = softmax(q @ k_land^T) @ T2 ----------------
__global__ __launch_bounds__(512, 4) void k_fused_attn1(const u16* __restrict__ q,
                                                        const u16* __restrict__ klb,
                                                        const u16* __restrict__ t2t,
                                                        u16* __restrict__ O) {
  const int bh = blockIdx.y, n0 = blockIdx.x << 7;
  const int bb = bh >> 3, hh = bh & 7;
  const int t = threadIdx.x, lane = t & 63, w = t >> 6;  // 8 waves
  const int fr = lane & 15, g = lane >> 4;
  __shared__ char lds[65536];  // [0,32K) k_land (aliased by half-P); [32K,64K) T2^T
  {
    const u16* ks = klb + (long)bh * 16384;
    const u16* ts = t2t + (long)bh * 16384;
#pragma unroll
    for (int i = 0; i < 4; ++i) {
      int seg = (i << 9) + t, row = seg >> 3, cs = seg & 7;
      GLL(ks + row * 64 + ((cs ^ (row & 7)) << 3), lds + (i << 13) + (w << 10));
      int slab = w * 4 + i;
      int trow = slab * 2 + (lane >> 5), cs32 = lane & 31;
      GLL(ts + trow * 256 + ((cs32 ^ (trow & 7)) << 3),
          lds + 32768 + slab * 1024);
    }
  }
  __syncthreads();
  const u16* qrow = q + ((long)bh * 8192 + n0 + (w << 4) + fr) * 64;
  bf16x8s qa0 = *(const bf16x8s*)(qrow + g * 8);
  bf16x8s qa1 = *(const bf16x8s*)(qrow + 32 + g * 8);
  f32x4 s[16];
#pragma unroll
  for (int c = 0; c < 16; ++c) {
    int j = (c << 4) + fr;
    bf16x8s b0 = *(const bf16x8s*)(lds + j * 128 + ((g ^ (j & 7)) << 4));
    bf16x8s b1 = *(const bf16x8s*)(lds + j * 128 + (((4 + g) ^ (j & 7)) << 4));
    f32x4 zz = {};
    zz = MFMA(qa0, b0, zz, 0, 0, 0);
    zz = MFMA(qa1, b1, zz, 0, 0, 0);
    s[c] = zz;
  }
  float li[4];
#pragma unroll
  for (int r = 0; r < 4; ++r) {
    float m = s[0][r];
#pragma unroll
    for (int c = 1; c < 16; ++c) m = fmaxf(m, s[c][r]);
    m = fmaxf(m, __shfl_xor(m, 1, 64));
    m = fmaxf(m, __shfl_xor(m, 2, 64));
    m = fmaxf(m, __shfl_xor(m, 4, 64));
    m = fmaxf(m, __shfl_xor(m, 8, 64));
    float l = 0.f;
#pragma unroll
    for (int c = 0; c < 16; ++c) {
      float e = __expf(s[c][r] - m);
      s[c][r] = e;
      l += e;
    }
    l += __shfl_xor(l, 1, 64);
    l += __shfl_xor(l, 2, 64);
    l += __shfl_xor(l, 4, 64);
    l += __shfl_xor(l, 8, 64);
    li[r] = 1.f / l;
  }
  __syncthreads();  // ALL waves done reading K; region becomes half-P [128][256B]
  f32x4 o4[4] = {};
#pragma unroll
  for (int p = 0; p < 2; ++p) {
#pragma unroll
    for (int c8 = 0; c8 < 8; ++c8) {
      int c = p * 8 + c8;
#pragma unroll
      for (int r = 0; r < 4; ++r) {
        int row = (w << 4) + (g << 2) + r;
        int byin = (c8 << 5) + (fr << 1);
        *(u16*)(lds + row * 256 + (byin ^ ((row & 7) << 4))) = f2b(s[c][r]);
      }
    }
    asm volatile("s_waitcnt lgkmcnt(0)" ::: "memory");
    __builtin_amdgcn_sched_barrier(0);
#pragma unroll
    for (int ss8 = 0; ss8 < 4; ++ss8) {
      int ss = p * 4 + ss8;
      int prow = (w << 4) + fr;
      bf16x8s ap = *(const bf16x8s*)(lds + prow * 256 +
                                     (((ss8 * 64) + (g << 4)) ^ ((prow & 7) << 4)));
#pragma unroll
      for (int d = 0; d < 4; ++d) {
        int dh = (d << 4) + fr;
        bf16x8s bv = *(const bf16x8s*)(lds + 32768 + dh * 512 +
                                       (((ss * 4 + g) ^ (dh & 7)) << 4));
        o4[d] = MFMA(ap, bv, o4[d], 0, 0, 0);
      }
    }
    asm volatile("s_waitcnt lgkmcnt(0)" ::: "memory");
    __builtin_amdgcn_sched_barrier(0);
  }
  u16* ob = O + (((long)bb * 8192 + n0 + (w << 4)) << 9) + (hh << 6);
#pragma unroll
  for (int d = 0; d < 4; ++d)
#pragma unroll
    for (int r = 0; r < 4; ++r) {
      int row = (g << 2) + r;
      int col = (d << 4) + fr;
      ob[((long)row << 9) + col] = f2b(o4[d][r] * li[r]);
    }
}

// ---------------- host ----------------
extern "C" void kernel_launch(void* const* d_in, const int* in_sizes, int n_in,
                              void* d_out, int out_size, void* d_ws, size_t ws_size,
                              hipStream_t stream) {
  const float* x = (const float*)d_in[0];
  const float* z = (const float*)d_in[1];
  const float* Wq = (const float*)d_in[2];
  const float* Wkv = (const float*)d_in[3];
  const float* Wo = (const float*)d_in[4];
  const float* bo = (const float*)d_in[5];
  float* out = (float*)d_out;

  char* base = (char*)d_ws;
  size_t off = 0;
  auto alloc = [&](size_t bytes) -> void* {
    void* r = base + off;
    off = (off + bytes + 255) & ~(size_t)255;
    return r;
  };
  u16* qb = (u16*)alloc(33554432);
  u16* kb = (u16*)alloc(16777216);
  u16* vtb = (u16*)alloc(16777216);
  u16* PS = (u16*)alloc(67108864);
  float* attn2 = (float*)alloc(8388608);
  u16* xb = (u16*)alloc(33554432);
  u16* zb = (u16*)alloc(16777216);
  u16* wqt = (u16*)alloc(524288);
  u16* wkvt = (u16*)alloc(1048576);
  u16* wot = (u16*)alloc(524288);
  u16* qlh = (u16*)alloc(1048576);
  u16* qll = (u16*)alloc(1048576);
  u16* klh = (u16*)alloc(1048576);
  u16* kll = (u16*)alloc(1048576);
  u16* T1t = (u16*)alloc(2097152);
  u16* T2t = (u16*)alloc(1048576);
  unsigned* cmax = (unsigned*)alloc(256);
  const long MC = 2097152;
  u16* P = PS;
  u16 *ztA_Nhi = P,          *ztA_Nlo = P + MC,      *ztA_Thi = P + 2 * MC,  *ztA_Tlo = P + 3 * MC;
  u16 *ztB_Nhi = P + 4 * MC,  *ztB_Nlo = P + 5 * MC,  *ztB_Thi = P + 6 * MC,  *ztB_Tlo = P + 7 * MC;
  u16 *az_Nhi = P + 8 * MC,   *az_Nlo = P + 9 * MC,   *az_Thi = P + 10 * MC,  *az_Tlo = P + 11 * MC;
  u16 *taThi = P + 12 * MC,   *taTlo = P + 13 * MC;
  u16 *tcThi = P + 14 * MC,   *tcTlo = P + 15 * MC;
  u16 *aNhi = zb, *aNlo = zb + MC;
  float* opart = (float*)PS;
  float* pm_ = opart + 2097152;
  float* pl_ = pm_ + 32768;
  u16* T1thi = T1t;
  u16* T1tlo = T1t + 524288;
  u16* Ob = xb;

  hipMemsetAsync(cmax, 0, 4, stream);
  k_f2bxz<<<24576, 256, 0, stream>>>(x, z, xb, zb);
  k_wt3<<<4096, 256, 0, stream>>>(Wq, Wkv, Wo, wqt, wkvt, wot);

  k_gemm128<0><<<dim3(4, 256), 256, 0, stream>>>(xb, wqt, qb, nullptr, nullptr,
                                                 nullptr, 512);
  k_gemm128<1><<<dim3(8, 128), 256, 0, stream>>>(zb, wkvt, kb, vtb, nullptr,
                                                 nullptr, 512);
  k_land2<<<4096, 256, 0, stream>>>(qb, kb, qlh, qll, klh, kll);

  k_sim2<<<dim3(4, 32), 256, 0, stream>>>(qlh, qll, klh, kll, attn2, aNhi, aNlo);
  k_colmax<<<32, 256, 0, stream>>>(attn2, cmax);

  k_t1part<<<512, 256, 0, stream>>>(qlh, kb, vtb, opart, pm_, pl_);
  k_t1merge<<<dim3(4, 32), 256, 0, stream>>>(opart, pm_, pl_, T1thi, T1tlo);

  k_prep_pinv<<<dim3(4, 4, 32), 256, 0, stream>>>(attn2, cmax, ztA_Nhi, ztA_Nlo,
                                                  ztA_Thi, ztA_Tlo);

  dim3 g256(4, 4, 32);
  u16 *cN0 = ztA_Nhi, *cN1 = ztA_Nlo, *cT0 = ztA_Thi, *cT1 = ztA_Tlo;
  u16 *nN0 = ztB_Nhi, *nN1 = ztB_Nlo, *nT0 = ztB_Thi, *nT1 = ztB_Tlo;
  for (int it = 0; it < 6; ++it) {
    bool last = (it == 5);
    if (it < 5) {
      k_nn_mfma<1><<<g256, 256, 0, stream>>>(aNhi, aNlo, cT0, cT1, az_Nhi, az_Nlo,
                                             az_Thi, az_Tlo, 256, 1.f, 0.f, 0.f);
      k_nn_mfma<1><<<g256, 256, 0, stream>>>(az_Nhi, az_Nlo, az_Thi, az_Tlo, nullptr,
                                             nullptr, taThi, taTlo, 256, 1.f, -7.f, 15.f);
      k_nn_mfma<1><<<g256, 256, 0, stream>>>(az_Nhi, az_Nlo, taThi, taTlo, nullptr,
                                             nullptr, tcThi, tcTlo, 256, -1.f, 0.f, 13.f);
      k_nn_mfma<1><<<g256, 256, 0, stream>>>(cN0, cN1, tcThi, tcTlo, nN0, nN1,
                                             nT0, nT1, 256, 0.25f, 0.f, 0.f);
    } else {
      k_nn_mfma<3><<<g256, 256, 0, stream>>>(aNhi, aNlo, cT0, cT1, az_Nhi, az_Nlo,
                                             az_Thi, az_Tlo, 256, 1.f, 0.f, 0.f);
      k_nn_mfma<3><<<g256, 256, 0, stream>>>(az_Nhi, az_Nlo, az_Thi, az_Tlo, nullptr,
                                             nullptr, taThi, taTlo, 256, 1.f, -7.f, 15.f);
      k_nn_mfma<3><<<g256, 256, 0, stream>>>(az_Nhi, az_Nlo, taThi, taTlo, nullptr,
                                             nullptr, tcThi, tcTlo, 256, -1.f, 0.f, 13.f);
      k_nn_mfma<3><<<g256, 256, 0, stream>>>(cN0, cN1, tcThi, tcTlo, nN0, nN1,
                                             last ? nullptr : nT0, last ? nullptr : nT1,
                                             256, 0.25f, 0.f, 0.f);
    }
    u16* t0;
    t0 = cN0; cN0 = nN0; nN0 = t0;  t0 = cN1; cN1 = nN1; nN1 = t0;
    t0 = cT0; cT0 = nT0; nT0 = t0;  t0 = cT1; cT1 = nT1; nT1 = t0;
  }
  k_nn_mfma<3><<<dim3(1, 4, 32), 256, 0, stream>>>(cN0, cN1, T1thi, T1tlo, nullptr,
                                                   nullptr, T2t, nullptr, 64,
                                                   1.f, 0.f, 0.f);

  k_fused_attn1<<<dim3(64, 32), 512, 0, stream>>>(qb, klh, T2t, Ob);
  k_gemm128<2><<<dim3(4, 256), 256, 0, stream>>>(Ob, wot, out, nullptr, x, bo, 512);
}

// Round 14
// 593.252 us; speedup vs baseline: 4.1597x; 1.0030x over previous
//
#include <hip/hip_runtime.h>

typedef unsigned short u16;
typedef __attribute__((ext_vector_type(8))) short bf16x8s;
typedef __attribute__((ext_vector_type(4))) float f32x4;

#define DEV static __device__ __forceinline__

DEV float b2f(u16 v) { return __uint_as_float(((unsigned)v) << 16); }
// HW RNE f32->bf16 (1 VALU op)
DEV u16 f2b(float f) {
  unsigned r;
  asm("v_cvt_pk_bf16_f32 %0, %1, %1" : "=v"(r) : "v"(f));
  return (u16)r;
}
DEV unsigned f2b2(float a, float b) {
  unsigned r;
  asm("v_cvt_pk_bf16_f32 %0, %1, %2" : "=v"(r) : "v"(a), "v"(b));
  return r;
}

// async global->LDS, 16B per lane; lds base must be wave-uniform (HW adds lane*16)
#define GLL(gp, lp)                                                            \
  __builtin_amdgcn_global_load_lds(                                            \
      (const __attribute__((address_space(1))) unsigned int*)(gp),             \
      (__attribute__((address_space(3))) unsigned int*)(lp), 16, 0, 0)

#define MFMA __builtin_amdgcn_mfma_f32_16x16x32_bf16

// ---------------- fused preamble: f2b(x), f2b(z), W transposes --------------
__global__ __launch_bounds__(256) void k_pre(const float* __restrict__ x,
                                             const float* __restrict__ z,
                                             u16* __restrict__ xb,
                                             u16* __restrict__ zb,
                                             const float* __restrict__ Wq,
                                             const float* __restrict__ Wkv,
                                             const float* __restrict__ Wo,
                                             u16* __restrict__ wqt,
                                             u16* __restrict__ wkvt,
                                             u16* __restrict__ wot) {
  if (blockIdx.x < 24576) {
    long i = (long)blockIdx.x * 256 + threadIdx.x;  // < 6291456
    const float* src;
    u16* dst;
    long j;
    if (i < 4194304) { src = x; dst = xb; j = i; }
    else { src = z; dst = zb; j = i - 4194304; }
    float4 v = *(const float4*)(src + j * 4);
    unsigned* d = (unsigned*)(dst + j * 4);
    d[0] = f2b2(v.x, v.y);
    d[1] = f2b2(v.z, v.w);
  } else {
    int e = (blockIdx.x - 24576) * 256 + threadIdx.x;  // < 1048576
    const float* W;
    u16* Wt;
    int N, le;
    if (e < 262144) { W = Wq; Wt = wqt; N = 512; le = e; }
    else if (e < 786432) { W = Wkv; Wt = wkvt; N = 1024; le = e - 262144; }
    else { W = Wo; Wt = wot; N = 512; le = e - 786432; }
    int nn = le >> 9, kk = le & 511;
    Wt[le] = f2b(W[(long)kk * N + nn]);
  }
}

// ---------------- 128x128 bf16 NT GEMM (BK=64, global_load_lds, swizzled) ----
template <int MODE>
__global__ __launch_bounds__(256, 2) void k_gemm128(
    const u16* __restrict__ A, const u16* __restrict__ Bm, void* __restrict__ C0,
    void* __restrict__ C1, const float* __restrict__ xres,
    const float* __restrict__ bias, int K) {
  const int nwg = gridDim.x * gridDim.y;
  const int orig = blockIdx.y * gridDim.x + blockIdx.x;
  const int qq = nwg >> 3, rr = nwg & 7;
  const int xcd = orig & 7, loc = orig >> 3;
  const int swz = (xcd < rr ? xcd * (qq + 1) : rr * (qq + 1) + (xcd - rr) * qq) + loc;
  const int m0 = (swz / gridDim.x) << 7, n0 = (swz % gridDim.x) << 7;
  const int t = threadIdx.x, lane = t & 63, w = t >> 6;
  const int wm = (w >> 1) << 6, wn = (w & 1) << 6;
  const int fr = lane & 15, g = lane >> 4;
  __shared__ u16 sh[16384];  // As | Bs ; reused as C-staging after main loop
  u16* As = sh;
  u16* Bs = sh + 8192;
  f32x4 acc[4][4] = {};
  const int srow = t >> 3, scs = t & 7;
  for (int k0 = 0; k0 < K; k0 += 64) {
    __syncthreads();
#pragma unroll
    for (int i = 0; i < 4; ++i) {
      int row = srow + (i << 5), cs = scs;
      GLL(A + (long)(m0 + row) * K + k0 + ((cs ^ (row & 7)) << 3),
          &As[(i << 11) + (w << 9)]);
      GLL(Bm + (long)(n0 + row) * K + k0 + ((cs ^ (row & 7)) << 3),
          &Bs[(i << 11) + (w << 9)]);
    }
    __syncthreads();
#pragma unroll
    for (int ks = 0; ks < 2; ++ks) {
      bf16x8s af[4], bf[4];
#pragma unroll
      for (int fi = 0; fi < 4; ++fi) {
        int row = wm + fi * 16 + fr;
        af[fi] = *(const bf16x8s*)((const char*)As + row * 128 +
                                   (((ks * 4 + g) ^ (row & 7)) << 4));
      }
#pragma unroll
      for (int fj = 0; fj < 4; ++fj) {
        int row = wn + fj * 16 + fr;
        bf[fj] = *(const bf16x8s*)((const char*)Bs + row * 128 +
                                   (((ks * 4 + g) ^ (row & 7)) << 4));
      }
#pragma unroll
      for (int fi = 0; fi < 4; ++fi)
#pragma unroll
        for (int fj = 0; fj < 4; ++fj)
          acc[fi][fj] = MFMA(af[fi], bf[fj], acc[fi][fj], 0, 0, 0);
    }
  }
  const int crow = g << 2;
  if (MODE == 2) {
#pragma unroll
    for (int fi = 0; fi < 4; ++fi)
#pragma unroll
      for (int fj = 0; fj < 4; ++fj)
#pragma unroll
        for (int r = 0; r < 4; ++r) {
          int row = m0 + wm + fi * 16 + crow + r;
          int col = n0 + wn + fj * 16 + fr;
          long idx = ((long)row << 9) + col;
          ((float*)C0)[idx] = acc[fi][fj][r] + xres[idx] + bias[col];
        }
  } else {
    __syncthreads();
    char* Cs = (char*)sh;
    const float scale = (MODE == 0) ? 0.125f : 1.f;
#pragma unroll
    for (int fi = 0; fi < 4; ++fi)
#pragma unroll
      for (int fj = 0; fj < 4; ++fj)
#pragma unroll
        for (int r = 0; r < 4; ++r) {
          int row = wm + fi * 16 + crow + r;
          int colb = (wn + fj * 16 + fr) << 1;
          *(u16*)(Cs + ((row * 256 + colb) ^ ((row & 7) << 4))) =
              f2b(acc[fi][fj][r] * scale);
        }
    __syncthreads();
    const bool vt = (MODE == 1) && (n0 >= 512);
    if (!vt) {
#pragma unroll
      for (int i = 0; i < 8; ++i) {
        int seg = (i << 8) + t;
        int row = seg >> 4, cs = seg & 15;
        bf16x8s v = *(const bf16x8s*)(Cs +
                        ((row * 256 + (cs << 4)) ^ ((row & 7) << 4)));
        int m = m0 + row;
        int colg = n0 + (cs << 3);
        int h = colg >> 6, dh0 = colg & 63;
        if (MODE == 0) {
          int b = m >> 13, n = m & 8191;
          *(bf16x8s*)((u16*)C0 + ((((long)(b * 8 + h)) << 13) + n) * 64 + dh0) = v;
        } else {
          int b = m >> 12, nz = m & 4095;
          *(bf16x8s*)((u16*)C0 + ((((long)(b * 8 + h)) << 12) + nz) * 64 + dh0) = v;
        }
      }
    } else {
#pragma unroll
      for (int i = 0; i < 8; ++i) {
        int seg = (i << 8) + t;
        int col = seg & 127;
        int r0 = (seg >> 7) << 3;
        bf16x8s v;
#pragma unroll
        for (int j = 0; j < 8; ++j) {
          int rr = r0 + j;
          v[j] = *(const short*)(Cs + ((rr * 256 + (col << 1)) ^ ((rr & 7) << 4)));
        }
        int m = m0 + r0;
        int b = m >> 12, nz0 = m & 4095;
        int c2 = n0 + col - 512;
        int h = c2 >> 6, dh = c2 & 63;
        *(bf16x8s*)((u16*)C1 + ((((long)(b * 8 + h) * 64 + dh)) << 12) + nz0) = v;
      }
    }
  }
}

// ---------------- fused landmarks (q then k): mean -> split hi/lo bf16 ------
__global__ __launch_bounds__(256) void k_land2(const u16* __restrict__ qb,
                                               const u16* __restrict__ kb,
                                               u16* __restrict__ qlh,
                                               u16* __restrict__ qll,
                                               u16* __restrict__ klh,
                                               u16* __restrict__ kll) {
  int pidx = blockIdx.x * 4 + (threadIdx.x >> 6);  // < 16384
  const u16* src;
  u16 *hi, *lo;
  int ntok, l;
  float inv;
  if (pidx < 8192) { src = qb; hi = qlh; lo = qll; ntok = 8192; l = 32; inv = 1.f / 32.f; }
  else { src = kb; hi = klh; lo = kll; ntok = 4096; l = 16; inv = 1.f / 16.f; pidx -= 8192; }
  int d = threadIdx.x & 63;
  int bh = pidx >> 8, m = pidx & 255;
  const u16* s = src + ((long)bh * ntok + (long)m * l) * 64 + d;
  float sum = 0.f;
  for (int j = 0; j < l; ++j) sum += b2f(s[j * 64]);
  sum *= inv;
  long o = ((long)bh * 256 + m) * 64 + d;
  u16 h = f2b(sum);
  hi[o] = h;
  lo[o] = f2b(sum - b2f(h));
}

// ---------------- sim2 + softmax via split-bf16 MFMA ------------------------
__global__ __launch_bounds__(256, 2) void k_sim2(
    const u16* __restrict__ qlh, const u16* __restrict__ qll,
    const u16* __restrict__ klh, const u16* __restrict__ kll,
    float* __restrict__ attn2, u16* __restrict__ aNhi, u16* __restrict__ aNlo) {
  const int rb = blockIdx.x, bh = blockIdx.y;
  const int t = threadIdx.x, lane = t & 63, w = t >> 6;
  const int fr = lane & 15, g = lane >> 4;
  __shared__ char lds[65536];
  {
    const u16* kh = klh + (long)bh * 16384;
    const u16* kl = kll + (long)bh * 16384;
    int srow8 = lane >> 3, cs7 = lane & 7;
#pragma unroll
    for (int i = 0; i < 8; ++i) {
      int slab = w * 8 + i;
      int krow = slab * 8 + srow8;
      GLL(kh + krow * 64 + ((cs7 ^ (krow & 7)) << 3), lds + slab * 1024);
      GLL(kl + krow * 64 + ((cs7 ^ (krow & 7)) << 3), lds + 32768 + slab * 1024);
    }
  }
  long qoff = ((long)bh * 256 + rb * 64 + w * 16 + fr) * 64;
  bf16x8s qh0 = *(const bf16x8s*)(qlh + qoff + g * 8);
  bf16x8s qh1 = *(const bf16x8s*)(qlh + qoff + 32 + g * 8);
  bf16x8s ql0 = *(const bf16x8s*)(qll + qoff + g * 8);
  bf16x8s ql1 = *(const bf16x8s*)(qll + qoff + 32 + g * 8);
  __syncthreads();
  f32x4 s[16];
#pragma unroll
  for (int c = 0; c < 16; ++c) {
    int j = (c << 4) + fr;
    int o0 = j * 128 + ((g ^ (j & 7)) << 4);
    int o1 = j * 128 + (((4 + g) ^ (j & 7)) << 4);
    bf16x8s kh0 = *(const bf16x8s*)(lds + o0);
    bf16x8s kh1 = *(const bf16x8s*)(lds + o1);
    bf16x8s kl0 = *(const bf16x8s*)(lds + 32768 + o0);
    bf16x8s kl1 = *(const bf16x8s*)(lds + 32768 + o1);
    f32x4 zz = {};
    zz = MFMA(qh0, kh0, zz, 0, 0, 0);
    zz = MFMA(qh1, kh1, zz, 0, 0, 0);
    zz = MFMA(qh0, kl0, zz, 0, 0, 0);
    zz = MFMA(qh1, kl1, zz, 0, 0, 0);
    zz = MFMA(ql0, kh0, zz, 0, 0, 0);
    zz = MFMA(ql1, kh1, zz, 0, 0, 0);
    s[c] = zz;
  }
  float li[4];
#pragma unroll
  for (int r = 0; r < 4; ++r) {
    float m = s[0][r];
#pragma unroll
    for (int c = 1; c < 16; ++c) m = fmaxf(m, s[c][r]);
    m = fmaxf(m, __shfl_xor(m, 1, 64));
    m = fmaxf(m, __shfl_xor(m, 2, 64));
    m = fmaxf(m, __shfl_xor(m, 4, 64));
    m = fmaxf(m, __shfl_xor(m, 8, 64));
    float l = 0.f;
#pragma unroll
    for (int c = 0; c < 16; ++c) {
      float e = __expf(s[c][r] - m);
      s[c][r] = e;
      l += e;
    }
    l += __shfl_xor(l, 1, 64);
    l += __shfl_xor(l, 2, 64);
    l += __shfl_xor(l, 4, 64);
    l += __shfl_xor(l, 8, 64);
    li[r] = 1.f / l;
  }
#pragma unroll
  for (int c = 0; c < 16; ++c)
#pragma unroll
    for (int r = 0; r < 4; ++r) {
      int row = rb * 64 + w * 16 + (g << 2) + r;
      int col = (c << 4) + fr;
      long idx = ((long)bh << 16) + ((long)row << 8) + col;
      float p = s[c][r] * li[r];
      attn2[idx] = p;
      u16 h = f2b(p);
      aNhi[idx] = h;
      aNlo[idx] = f2b(p - b2f(h));
    }
}

// ---------------- fused: colmax (32 blocks) + T1 split-KV partial (512) -----
__global__ __launch_bounds__(256, 2) void k_cm_t1(
    const float* __restrict__ attn2, unsigned* __restrict__ cmax,
    const u16* __restrict__ qlb, const u16* __restrict__ kb,
    const u16* __restrict__ vtb, float* __restrict__ opart,
    float* __restrict__ pm_, float* __restrict__ pl_) {
  __shared__ char lds[65536];
  if (blockIdx.x < 32) {
    int bh = blockIdx.x, j = threadIdx.x, lane = j & 63, w = j >> 6;
    const float* p = attn2 + ((long)bh << 16) + j;
    float s = 0.f;
    for (int m = 0; m < 256; ++m) s += p[m * 256];
    float mx = s;
    for (int o = 1; o < 64; o <<= 1) mx = fmaxf(mx, __shfl_xor(mx, o, 64));
    float* r1 = (float*)lds;
    if (lane == 0) r1[w] = mx;
    __syncthreads();
    if (j == 0) {
      mx = fmaxf(fmaxf(r1[0], r1[1]), fmaxf(r1[2], r1[3]));
      atomicMax(cmax, __float_as_uint(mx));
    }
    return;
  }
  int orig = blockIdx.x - 32;  // 512 = 32 bh * 4 kc * 4 rb
  int xcd = orig & 7, idx = orig >> 3;
  int p = xcd * 16 + (idx >> 2);
  int rb = idx & 3;
  int bh = p >> 2, kc = p & 3;
  const int t = threadIdx.x, lane = t & 63, w = t >> 6;
  const int fr = lane & 15, g = lane >> 4;
  const u16* qrow = qlb + ((long)bh * 256 + rb * 64 + w * 16 + fr) * 64;
  bf16x8s qa0 = *(const bf16x8s*)(qrow + g * 8);
  bf16x8s qa1 = *(const bf16x8s*)(qrow + 32 + g * 8);
  f32x4 o[4] = {};
  float m[4] = {-3e38f, -3e38f, -3e38f, -3e38f};
  float l[4] = {};
  const long kbase = (long)bh * 262144;
  for (int cc = 0; cc < 4; ++cc) {
    int c0 = kc * 1024 + cc * 256;
    __syncthreads();
#pragma unroll
    for (int i = 0; i < 8; ++i) {
      int seg = (i << 8) + t, row = seg >> 3, cs = seg & 7;
      GLL(kb + kbase + (long)(c0 + row) * 64 + ((cs ^ (row & 7)) << 3),
          lds + (i << 12) + (w << 10));
    }
#pragma unroll
    for (int i = 0; i < 8; ++i) {
      int seg = (i << 8) + t, row = seg >> 5, cs = seg & 31;
      GLL(vtb + kbase + (long)row * 4096 + c0 + ((cs ^ (row & 7)) << 3),
          lds + 32768 + (i << 12) + (w << 10));
    }
    __syncthreads();
    f32x4 s[16];
#pragma unroll
    for (int c = 0; c < 16; ++c) {
      int j = c * 16 + fr;
      bf16x8s b0 = *(const bf16x8s*)(lds + j * 128 + ((g ^ (j & 7)) << 4));
      bf16x8s b1 = *(const bf16x8s*)(lds + j * 128 + (((4 + g) ^ (j & 7)) << 4));
      f32x4 zz = {};
      zz = MFMA(qa0, b0, zz, 0, 0, 0);
      zz = MFMA(qa1, b1, zz, 0, 0, 0);
      s[c] = zz;
    }
    float sc[4];
#pragma unroll
    for (int r = 0; r < 4; ++r) {
      float pm = s[0][r];
#pragma unroll
      for (int c = 1; c < 16; ++c) pm = fmaxf(pm, s[c][r]);
      pm = fmaxf(pm, __shfl_xor(pm, 1, 64));
      pm = fmaxf(pm, __shfl_xor(pm, 2, 64));
      pm = fmaxf(pm, __shfl_xor(pm, 4, 64));
      pm = fmaxf(pm, __shfl_xor(pm, 8, 64));
      float mn = fmaxf(m[r], pm);
      sc[r] = __expf(m[r] - mn);
      m[r] = mn;
    }
#pragma unroll
    for (int r = 0; r < 4; ++r) {
      float su = 0.f;
#pragma unroll
      for (int c = 0; c < 16; ++c) {
        float e = __expf(s[c][r] - m[r]);
        s[c][r] = e;
        su += e;
      }
      su += __shfl_xor(su, 1, 64);
      su += __shfl_xor(su, 2, 64);
      su += __shfl_xor(su, 4, 64);
      su += __shfl_xor(su, 8, 64);
      l[r] = l[r] * sc[r] + su;
    }
#pragma unroll
    for (int d = 0; d < 4; ++d)
#pragma unroll
      for (int r = 0; r < 4; ++r) o[d][r] *= sc[r];
    __syncthreads();
#pragma unroll
    for (int c = 0; c < 16; ++c)
#pragma unroll
      for (int r = 0; r < 4; ++r) {
        int row = (w << 4) + (g << 2) + r;
        int byin = (c << 5) + (fr << 1);
        *(u16*)(lds + row * 512 + (byin ^ ((row & 7) << 4))) = f2b(s[c][r]);
      }
    asm volatile("s_waitcnt lgkmcnt(0)" ::: "memory");
    __builtin_amdgcn_sched_barrier(0);
#pragma unroll
    for (int ss = 0; ss < 8; ++ss) {
      int prow = (w << 4) + fr;
      bf16x8s ap = *(const bf16x8s*)(lds + prow * 512 +
                                     (((ss * 64) + (g << 4)) ^ ((prow & 7) << 4)));
#pragma unroll
      for (int d = 0; d < 4; ++d) {
        int dh = (d << 4) + fr;
        bf16x8s bv = *(const bf16x8s*)(lds + 32768 + dh * 512 +
                                       (((ss * 4 + g) ^ (dh & 7)) << 4));
        o[d] = MFMA(ap, bv, o[d], 0, 0, 0);
      }
    }
  }
  __syncthreads();
  float* lf = (float*)lds;
#pragma unroll
  for (int d = 0; d < 4; ++d)
#pragma unroll
    for (int r = 0; r < 4; ++r)
      lf[((w << 4) + (g << 2) + r) * 76 + (d << 4) + fr] = o[d][r];
  __syncthreads();
  const long pb = (long)(bh * 4 + kc) * 256 + rb * 64;
#pragma unroll
  for (int i = 0; i < 4; ++i) {
    int row = i * 16 + (t >> 4);
    int c4 = (t & 15) << 2;
    float4 v = *(const float4*)&lf[row * 76 + c4];
    *(float4*)&opart[(pb + row) * 64 + c4] = v;
  }
  if (fr == 0) {
#pragma unroll
    for (int r = 0; r < 4; ++r) {
      int lr = (w << 4) + (g << 2) + r;
      pm_[pb + lr] = m[r];
      pl_[pb + lr] = l[r];
    }
  }
}

// ---------------- fused: t1merge (128 blocks) + pinv prep (512) -------------
__global__ __launch_bounds__(256) void k_mergeprep(
    const float* __restrict__ opart, const float* __restrict__ pm_,
    const float* __restrict__ pl_, u16* __restrict__ T1thi,
    u16* __restrict__ T1tlo, const float* __restrict__ attn2,
    const unsigned* __restrict__ cmax, u16* __restrict__ zNhi,
    u16* __restrict__ zNlo, u16* __restrict__ zThi, u16* __restrict__ zTlo) {
  __shared__ float mt[64][65];
  if (blockIdx.x < 128) {
    const int rb = blockIdx.x & 3, bh = blockIdx.x >> 2;
    const int t = threadIdx.x;
#pragma unroll
    for (int rp = 0; rp < 4; ++rp) {
      int row = rb * 64 + rp * 16 + (t >> 4);
      int dh4 = (t & 15) << 2;
      float pmv[4], M = -3e38f;
#pragma unroll
      for (int i = 0; i < 4; ++i) {
        pmv[i] = pm_[(long)(bh * 4 + i) * 256 + row];
        M = fmaxf(M, pmv[i]);
      }
      float L = 0.f, wt[4];
#pragma unroll
      for (int i = 0; i < 4; ++i) {
        wt[i] = __expf(pmv[i] - M);
        L += pl_[(long)(bh * 4 + i) * 256 + row] * wt[i];
      }
      float4 acc = {0.f, 0.f, 0.f, 0.f};
#pragma unroll
      for (int i = 0; i < 4; ++i) {
        float4 v = *(const float4*)&opart[((long)(bh * 4 + i) * 256 + row) * 64 + dh4];
        acc.x += v.x * wt[i]; acc.y += v.y * wt[i];
        acc.z += v.z * wt[i]; acc.w += v.w * wt[i];
      }
      float invL = 1.f / L;
      float vv[4] = {acc.x * invL, acc.y * invL, acc.z * invL, acc.w * invL};
#pragma unroll
      for (int e = 0; e < 4; ++e) {
        int dh = dh4 + e;
        long idx = (long)bh * 16384 + (long)dh * 256 + row;
        u16 h = f2b(vv[e]);
        T1thi[idx] = h;
        T1tlo[idx] = f2b(vv[e] - b2f(h));
      }
    }
    return;
  }
  const int p = blockIdx.x - 128;
  const int bz = p >> 4, i0 = ((p >> 2) & 3) << 6, j0 = (p & 3) << 6;
  const float s = 1.f / __uint_as_float(*cmax);
  const float* base = attn2 + ((long)bz << 16);
  const int r = threadIdx.x >> 2, cb = (threadIdx.x & 3) << 4;
#pragma unroll
  for (int c4 = 0; c4 < 16; c4 += 4) {
    float4 v = *(const float4*)&base[(long)(j0 + r) * 256 + i0 + cb + c4];
    mt[r][cb + c4] = v.x; mt[r][cb + c4 + 1] = v.y;
    mt[r][cb + c4 + 2] = v.z; mt[r][cb + c4 + 3] = v.w;
  }
  __syncthreads();
  const int i = i0 + r;
#pragma unroll
  for (int c4 = 0; c4 < 16; c4 += 4) {
    float4 v = *(const float4*)&base[(long)i * 256 + j0 + cb + c4];
    float vv[4] = {v.x, v.y, v.z, v.w};
#pragma unroll
    for (int e = 0; e < 4; ++e) {
      int j = j0 + cb + c4 + e;
      long idx = ((long)bz << 16) + ((long)i << 8) + j;
      float zt = vv[e] * s;
      u16 zh = f2b(zt);
      zThi[idx] = zh; zTlo[idx] = f2b(zt - b2f(zh));
      float zn = mt[cb + c4 + e][r] * s;
      u16 nh = f2b(zn);
      zNhi[idx] = nh; zNlo[idx] = f2b(zn - b2f(nh));
    }
  }
}

// ---------------- MFMA NN GEMM (pinv chain), BK=128; NP=1 plain, NP=3 split -
// k-slice order identical to BK=64 version -> bit-identical accumulation.
template <int NP>
__global__ __launch_bounds__(256) void k_nn_mfma(
    const u16* __restrict__ Ahi, const u16* __restrict__ Alo,
    const u16* __restrict__ Bthi, const u16* __restrict__ Btlo,
    u16* __restrict__ CNhi, u16* __restrict__ CNlo,
    u16* __restrict__ CThi, u16* __restrict__ CTlo,
    int Nc, float sab, float sa, float cdiag) {
  const int bz = blockIdx.z;
  const long offA = (long)bz << 16;
  const long offB = (long)bz * ((long)Nc << 8);
  const int m0 = blockIdx.y << 6, n0 = blockIdx.x << 6;
  const int t = threadIdx.x, lane = t & 63, w = t >> 6;
  const int wm = (w >> 1) << 5, wn = (w & 1) << 5;
  const int fr = lane & 15, g = lane >> 4;
  __shared__ u16 lds[(NP == 3) ? 32768 : 16384];  // planes of [64][128] u16 (16KB)
  u16* LAh = lds;
  u16* LBh = lds + 8192;
  u16* LAl = (NP == 3) ? lds + 16384 : nullptr;
  u16* LBl = (NP == 3) ? lds + 24576 : nullptr;
  f32x4 acc[2][2] = {};
  for (int k0 = 0; k0 < 256; k0 += 128) {
    __syncthreads();
#pragma unroll
    for (int i = 0; i < 4; ++i) {
      // linear LDS pos L = i*4096 + t*16 -> row = i*16 + t/16, slot sp = t&15
      int row = (i << 4) + (t >> 4);
      int sp = t & 15;
      int seg = (sp & 8) | ((sp & 7) ^ (row & 7));  // source 16B-segment
      long asrc = offA + (long)(m0 + row) * 256 + k0 + (seg << 3);
      long bsrc = offB + (long)(n0 + row) * 256 + k0 + (seg << 3);
      GLL(Ahi + asrc, (char*)LAh + (i << 12) + (w << 10));
      GLL(Bthi + bsrc, (char*)LBh + (i << 12) + (w << 10));
      if (NP == 3) {
        GLL(Alo + asrc, (char*)LAl + (i << 12) + (w << 10));
        GLL(Btlo + bsrc, (char*)LBl + (i << 12) + (w << 10));
      }
    }
    __syncthreads();
#pragma unroll
    for (int ks = 0; ks < 4; ++ks) {
      const int ra0 = wm + fr, ra1 = wm + 16 + fr;
      const int rb0 = wn + fr, rb1 = wn + 16 + fr;
#define RD(base, row)                                                          \
  (*(const bf16x8s*)((const char*)(base) + (row) * 256 +                       \
                     ((((ks * 4 + g) & 8) |                                    \
                       (((ks * 4 + g) & 7) ^ ((row) & 7))) << 4)))
      bf16x8s ah0 = RD(LAh, ra0), ah1 = RD(LAh, ra1);
      bf16x8s bh0 = RD(LBh, rb0), bh1 = RD(LBh, rb1);
      acc[0][0] = MFMA(ah0, bh0, acc[0][0], 0, 0, 0);
      acc[0][1] = MFMA(ah0, bh1, acc[0][1], 0, 0, 0);
      acc[1][0] = MFMA(ah1, bh0, acc[1][0], 0, 0, 0);
      acc[1][1] = MFMA(ah1, bh1, acc[1][1], 0, 0, 0);
      if (NP == 3) {
        bf16x8s al0 = RD(LAl, ra0), al1 = RD(LAl, ra1);
        bf16x8s bl0 = RD(LBl, rb0), bl1 = RD(LBl, rb1);
        acc[0][0] = MFMA(ah0, bl0, acc[0][0], 0, 0, 0);
        acc[0][0] = MFMA(al0, bh0, acc[0][0], 0, 0, 0);
        acc[0][1] = MFMA(ah0, bl1, acc[0][1], 0, 0, 0);
        acc[0][1] = MFMA(al0, bh1, acc[0][1], 0, 0, 0);
        acc[1][0] = MFMA(ah1, bl0, acc[1][0], 0, 0, 0);
        acc[1][0] = MFMA(al1, bh0, acc[1][0], 0, 0, 0);
        acc[1][1] = MFMA(ah1, bl1, acc[1][1], 0, 0, 0);
        acc[1][1] = MFMA(al1, bh1, acc[1][1], 0, 0, 0);
      }
#undef RD
    }
  }
  const int crow = g << 2;
  const long offC = (long)bz * ((long)Nc << 8);
#pragma unroll
  for (int i = 0; i < 2; ++i)
#pragma unroll
    for (int j = 0; j < 2; ++j)
#pragma unroll
      for (int r = 0; r < 4; ++r) {
        int row = m0 + wm + i * 16 + crow + r;
        int col = n0 + wn + j * 16 + fr;
        float v = sab * acc[i][j][r];
        if (sa != 0.f) {
          long ai = offA + ((long)row << 8) + col;
          v += sa * (b2f(Ahi[ai]) + b2f(Alo[ai]));
        }
        if (row == col) v += cdiag;
        if (CNhi) {
          long ci = offC + (long)row * Nc + col;
          u16 h = f2b(v);
          if (CNlo) { CNhi[ci] = h; CNlo[ci] = f2b(v - b2f(h)); }
          else CNhi[ci] = h;
        }
        if (CThi) {
          long ti = offC + ((long)col << 8) + row;
          u16 h = f2b(v);
          CThi[ti] = h;
          if (CTlo) CTlo[ti] = f2b(v - b2f(h));
        }
      }
}

// ---------------- fused sim1: O = softmax(q @ k_land^T) @ T2 ----------------
__global__ __launch_bounds__(512, 4) void k_fused_attn1(const u16* __restrict__ q,
                                                        const u16* __restrict__ klb,
                                                        const u16* __restrict__ t2t,
                                                        u16* __restrict__ O) {
  const int bh = blockIdx.y, n0 = blockIdx.x << 7;
  const int bb = bh >> 3, hh = bh & 7;
  const int t = threadIdx.x, lane = t & 63, w = t >> 6;  // 8 waves
  const int fr = lane & 15, g = lane >> 4;
  __shared__ char lds[65536];  // [0,32K) k_land (aliased by half-P); [32K,64K) T2^T
  {
    const u16* ks = klb + (long)bh * 16384;
    const u16* ts = t2t + (long)bh * 16384;
#pragma unroll
    for (int i = 0; i < 4; ++i) {
      int seg = (i << 9) + t, row = seg >> 3, cs = seg & 7;
      GLL(ks + row * 64 + ((cs ^ (row & 7)) << 3), lds + (i << 13) + (w << 10));
      int slab = w * 4 + i;
      int trow = slab * 2 + (lane >> 5), cs32 = lane & 31;
      GLL(ts + trow * 256 + ((cs32 ^ (trow & 7)) << 3),
          lds + 32768 + slab * 1024);
    }
  }
  __syncthreads();
  const u16* qrow = q + ((long)bh * 8192 + n0 + (w << 4) + fr) * 64;
  bf16x8s qa0 = *(const bf16x8s*)(qrow + g * 8);
  bf16x8s qa1 = *(const bf16x8s*)(qrow + 32 + g * 8);
  f32x4 s[16];
#pragma unroll
  for (int c = 0; c < 16; ++c) {
    int j = (c << 4) + fr;
    bf16x8s b0 = *(const bf16x8s*)(lds + j * 128 + ((g ^ (j & 7)) << 4));
    bf16x8s b1 = *(const bf16x8s*)(lds + j * 128 + (((4 + g) ^ (j & 7)) << 4));
    f32x4 zz = {};
    zz = MFMA(qa0, b0, zz, 0, 0, 0);
    zz = MFMA(qa1, b1, zz, 0, 0, 0);
    s[c] = zz;
  }
  float li[4];
#pragma unroll
  for (int r = 0; r < 4; ++r) {
    float m = s[0][r];
#pragma unroll
    for (int c = 1; c < 16; ++c) m = fmaxf(m, s[c][r]);
    m = fmaxf(m, __shfl_xor(m, 1, 64));
    m = fmaxf(m, __shfl_xor(m, 2, 64));
    m = fmaxf(m, __shfl_xor(m, 4, 64));
    m = fmaxf(m, __shfl_xor(m, 8, 64));
    float l = 0.f;
#pragma unroll
    for (int c = 0; c < 16; ++c) {
      float e = __expf(s[c][r] - m);
      s[c][r] = e;
      l += e;
    }
    l += __shfl_xor(l, 1, 64);
    l += __shfl_xor(l, 2, 64);
    l += __shfl_xor(l, 4, 64);
    l += __shfl_xor(l, 8, 64);
    li[r] = 1.f / l;
  }
  __syncthreads();  // ALL waves done reading K; region becomes half-P [128][256B]
  f32x4 o4[4] = {};
#pragma unroll
  for (int p = 0; p < 2; ++p) {
#pragma unroll
    for (int c8 = 0; c8 < 8; ++c8) {
      int c = p * 8 + c8;
#pragma unroll
      for (int r = 0; r < 4; ++r) {
        int row = (w << 4) + (g << 2) + r;
        int byin = (c8 << 5) + (fr << 1);
        *(u16*)(lds + row * 256 + (byin ^ ((row & 7) << 4))) = f2b(s[c][r]);
      }
    }
    asm volatile("s_waitcnt lgkmcnt(0)" ::: "memory");
    __builtin_amdgcn_sched_barrier(0);
#pragma unroll
    for (int ss8 = 0; ss8 < 4; ++ss8) {
      int ss = p * 4 + ss8;
      int prow = (w << 4) + fr;
      bf16x8s ap = *(const bf16x8s*)(lds + prow * 256 +
                                     (((ss8 * 64) + (g << 4)) ^ ((prow & 7) << 4)));
#pragma unroll
      for (int d = 0; d < 4; ++d) {
        int dh = (d << 4) + fr;
        bf16x8s bv = *(const bf16x8s*)(lds + 32768 + dh * 512 +
                                       (((ss * 4 + g) ^ (dh & 7)) << 4));
        o4[d] = MFMA(ap, bv, o4[d], 0, 0, 0);
      }
    }
    asm volatile("s_waitcnt lgkmcnt(0)" ::: "memory");
    __builtin_amdgcn_sched_barrier(0);
  }
  u16* ob = O + (((long)bb * 8192 + n0 + (w << 4)) << 9) + (hh << 6);
#pragma unroll
  for (int d = 0; d < 4; ++d)
#pragma unroll
    for (int r = 0; r < 4; ++r) {
      int row = (g << 2) + r;
      int col = (d << 4) + fr;
      ob[((long)row << 9) + col] = f2b(o4[d][r] * li[r]);
    }
}

// ---------------- host ----------------
extern "C" void kernel_launch(void* const* d_in, const int* in_sizes, int n_in,
                              void* d_out, int out_size, void* d_ws, size_t ws_size,
                              hipStream_t stream) {
  const float* x = (const float*)d_in[0];
  const float* z = (const float*)d_in[1];
  const float* Wq = (const float*)d_in[2];
  const float* Wkv = (const float*)d_in[3];
  const float* Wo = (const float*)d_in[4];
  const float* bo = (const float*)d_in[5];
  float* out = (float*)d_out;

  char* base = (char*)d_ws;
  size_t off = 0;
  auto alloc = [&](size_t bytes) -> void* {
    void* r = base + off;
    off = (off + bytes + 255) & ~(size_t)255;
    return r;
  };
  u16* qb = (u16*)alloc(33554432);
  u16* kb = (u16*)alloc(16777216);
  u16* vtb = (u16*)alloc(16777216);
  u16* PS = (u16*)alloc(67108864);    // pinv state (16 x 4MB)
  float* attn2 = (float*)alloc(8388608);
  u16* xb = (u16*)alloc(33554432);    // dead after qproj -> opart, then Ob
  u16* zb = (u16*)alloc(16777216);    // dead after kvproj -> attn2 split aN
  u16* wqt = (u16*)alloc(524288);
  u16* wkvt = (u16*)alloc(1048576);
  u16* wot = (u16*)alloc(524288);
  u16* qlh = (u16*)alloc(1048576);
  u16* qll = (u16*)alloc(1048576);
  u16* klh = (u16*)alloc(1048576);
  u16* kll = (u16*)alloc(1048576);
  u16* T1t = (u16*)alloc(2097152);
  u16* T2t = (u16*)alloc(1048576);
  unsigned* cmax = (unsigned*)alloc(256);
  const long MC = 2097152;
  u16* P = PS;
  u16 *ztA_Nhi = P,          *ztA_Nlo = P + MC,      *ztA_Thi = P + 2 * MC,  *ztA_Tlo = P + 3 * MC;
  u16 *ztB_Nhi = P + 4 * MC,  *ztB_Nlo = P + 5 * MC,  *ztB_Thi = P + 6 * MC,  *ztB_Tlo = P + 7 * MC;
  u16 *az_Nhi = P + 8 * MC,   *az_Nlo = P + 9 * MC,   *az_Thi = P + 10 * MC,  *az_Tlo = P + 11 * MC;
  u16 *taThi = P + 12 * MC,   *taTlo = P + 13 * MC;
  u16 *tcThi = P + 14 * MC,   *tcTlo = P + 15 * MC;
  u16 *aNhi = zb, *aNlo = zb + MC;
  // T1 partials now alias xb (dead after qproj; Ob=xb written later by attn1)
  float* opart = (float*)xb;                 // 8.4MB + 256KB
  float* pm_ = opart + 2097152;
  float* pl_ = pm_ + 32768;
  u16* T1thi = T1t;
  u16* T1tlo = T1t + 524288;
  u16* Ob = xb;

  hipMemsetAsync(cmax, 0, 4, stream);
  k_pre<<<28672, 256, 0, stream>>>(x, z, xb, zb, Wq, Wkv, Wo, wqt, wkvt, wot);

  k_gemm128<0><<<dim3(4, 256), 256, 0, stream>>>(xb, wqt, qb, nullptr, nullptr,
                                                 nullptr, 512);
  k_gemm128<1><<<dim3(8, 128), 256, 0, stream>>>(zb, wkvt, kb, vtb, nullptr,
                                                 nullptr, 512);
  k_land2<<<4096, 256, 0, stream>>>(qb, kb, qlh, qll, klh, kll);

  k_sim2<<<dim3(4, 32), 256, 0, stream>>>(qlh, qll, klh, kll, attn2, aNhi, aNlo);

  // colmax + T1 partials in one dispatch (independent)
  k_cm_t1<<<544, 256, 0, stream>>>(attn2, cmax, qlh, kb, vtb, opart, pm_, pl_);
  // t1merge + pinv z0 prep in one dispatch (independent; opart in xb, prep in PS)
  k_mergeprep<<<640, 256, 0, stream>>>(opart, pm_, pl_, T1thi, T1tlo, attn2,
                                       cmax, ztA_Nhi, ztA_Nlo, ztA_Thi, ztA_Tlo);

  dim3 g256(4, 4, 32);
  u16 *cN0 = ztA_Nhi, *cN1 = ztA_Nlo, *cT0 = ztA_Thi, *cT1 = ztA_Tlo;
  u16 *nN0 = ztB_Nhi, *nN1 = ztB_Nlo, *nT0 = ztB_Thi, *nT1 = ztB_Tlo;
  for (int it = 0; it < 6; ++it) {
    bool last = (it == 5);
    if (it < 5) {
      k_nn_mfma<1><<<g256, 256, 0, stream>>>(aNhi, aNlo, cT0, cT1, az_Nhi, az_Nlo,
                                             az_Thi, az_Tlo, 256, 1.f, 0.f, 0.f);
      k_nn_mfma<1><<<g256, 256, 0, stream>>>(az_Nhi, az_Nlo, az_Thi, az_Tlo, nullptr,
                                             nullptr, taThi, taTlo, 256, 1.f, -7.f, 15.f);
      k_nn_mfma<1><<<g256, 256, 0, stream>>>(az_Nhi, az_Nlo, taThi, taTlo, nullptr,
                                             nullptr, tcThi, tcTlo, 256, -1.f, 0.f, 13.f);
      k_nn_mfma<1><<<g256, 256, 0, stream>>>(cN0, cN1, tcThi, tcTlo, nN0, nN1,
                                             nT0, nT1, 256, 0.25f, 0.f, 0.f);
    } else {
      k_nn_mfma<3><<<g256, 256, 0, stream>>>(aNhi, aNlo, cT0, cT1, az_Nhi, az_Nlo,
                                             az_Thi, az_Tlo, 256, 1.f, 0.f, 0.f);
      k_nn_mfma<3><<<g256, 256, 0, stream>>>(az_Nhi, az_Nlo, az_Thi, az_Tlo, nullptr,
                                             nullptr, taThi, taTlo, 256, 1.f, -7.f, 15.f);
      k_nn_mfma<3><<<g256, 256, 0, stream>>>(az_Nhi, az_Nlo, taThi, taTlo, nullptr,
                                             nullptr, tcThi, tcTlo, 256, -1.f, 0.f, 13.f);
      k_nn_mfma<3><<<g256, 256, 0, stream>>>(cN0, cN1, tcThi, tcTlo, nN0, nN1,
                                             last ? nullptr : nT0, last ? nullptr : nT1,
                                             256, 0.25f, 0.f, 0.f);
    }
    u16* t0;
    t0 = cN0; cN0 = nN0; nN0 = t0;  t0 = cN1; cN1 = nN1; nN1 = t0;
    t0 = cT0; cT0 = nT0; nT0 = t0;  t0 = cT1; cT1 = nT1; nT1 = t0;
  }
  k_nn_mfma<3><<<dim3(1, 4, 32), 256, 0, stream>>>(cN0, cN1, T1thi, T1tlo, nullptr,
                                                   nullptr, T2t, nullptr, 64,
                                                   1.f, 0.f, 0.f);

  k_fused_attn1<<<dim3(64, 32), 512, 0, stream>>>(qb, klh, T2t, Ob);
  k_gemm128<2><<<dim3(4, 256), 256, 0, stream>>>(Ob, wot, out, nullptr, x, bo, 512);
}

// Round 15
// 592.207 us; speedup vs baseline: 4.1671x; 1.0018x over previous
//
#include <hip/hip_runtime.h>

typedef unsigned short u16;
typedef __attribute__((ext_vector_type(8))) short bf16x8s;
typedef __attribute__((ext_vector_type(4))) float f32x4;

#define DEV static __device__ __forceinline__

DEV float b2f(u16 v) { return __uint_as_float(((unsigned)v) << 16); }
// HW RNE f32->bf16 (1 VALU op)
DEV u16 f2b(float f) {
  unsigned r;
  asm("v_cvt_pk_bf16_f32 %0, %1, %1" : "=v"(r) : "v"(f));
  return (u16)r;
}
DEV unsigned f2b2(float a, float b) {
  unsigned r;
  asm("v_cvt_pk_bf16_f32 %0, %1, %2" : "=v"(r) : "v"(a), "v"(b));
  return r;
}

// async global->LDS, 16B per lane; lds base must be wave-uniform (HW adds lane*16)
#define GLL(gp, lp)                                                            \
  __builtin_amdgcn_global_load_lds(                                            \
      (const __attribute__((address_space(1))) unsigned int*)(gp),             \
      (__attribute__((address_space(3))) unsigned int*)(lp), 16, 0, 0)

#define MFMA __builtin_amdgcn_mfma_f32_16x16x32_bf16

// ---------------- fused preamble: f2b(x), f2b(z), W transposes --------------
__global__ __launch_bounds__(256) void k_pre(const float* __restrict__ x,
                                             const float* __restrict__ z,
                                             u16* __restrict__ xb,
                                             u16* __restrict__ zb,
                                             const float* __restrict__ Wq,
                                             const float* __restrict__ Wkv,
                                             const float* __restrict__ Wo,
                                             u16* __restrict__ wqt,
                                             u16* __restrict__ wkvt,
                                             u16* __restrict__ wot) {
  if (blockIdx.x < 24576) {
    long i = (long)blockIdx.x * 256 + threadIdx.x;  // < 6291456
    const float* src;
    u16* dst;
    long j;
    if (i < 4194304) { src = x; dst = xb; j = i; }
    else { src = z; dst = zb; j = i - 4194304; }
    float4 v = *(const float4*)(src + j * 4);
    unsigned* d = (unsigned*)(dst + j * 4);
    d[0] = f2b2(v.x, v.y);
    d[1] = f2b2(v.z, v.w);
  } else {
    int e = (blockIdx.x - 24576) * 256 + threadIdx.x;  // < 1048576
    const float* W;
    u16* Wt;
    int N, le;
    if (e < 262144) { W = Wq; Wt = wqt; N = 512; le = e; }
    else if (e < 786432) { W = Wkv; Wt = wkvt; N = 1024; le = e - 262144; }
    else { W = Wo; Wt = wot; N = 512; le = e - 786432; }
    int nn = le >> 9, kk = le & 511;
    Wt[le] = f2b(W[(long)kk * N + nn]);
  }
}

// ---------------- 128x128 bf16 NT GEMM (BK=64, global_load_lds, swizzled) ----
// 4 blocks/CU (LDS 32KB, VGPR 64): latency hiding across co-resident blocks.
template <int MODE>
__global__ __launch_bounds__(256, 4) void k_gemm128(
    const u16* __restrict__ A, const u16* __restrict__ Bm, void* __restrict__ C0,
    void* __restrict__ C1, const float* __restrict__ xres,
    const float* __restrict__ bias, int K) {
  const int nwg = gridDim.x * gridDim.y;
  const int orig = blockIdx.y * gridDim.x + blockIdx.x;
  const int qq = nwg >> 3, rr = nwg & 7;
  const int xcd = orig & 7, loc = orig >> 3;
  const int swz = (xcd < rr ? xcd * (qq + 1) : rr * (qq + 1) + (xcd - rr) * qq) + loc;
  const int m0 = (swz / gridDim.x) << 7, n0 = (swz % gridDim.x) << 7;
  const int t = threadIdx.x, lane = t & 63, w = t >> 6;
  const int wm = (w >> 1) << 6, wn = (w & 1) << 6;
  const int fr = lane & 15, g = lane >> 4;
  __shared__ u16 sh[16384];  // As | Bs ; reused as C-staging after main loop
  u16* As = sh;
  u16* Bs = sh + 8192;
  f32x4 acc[4][4] = {};
  const int srow = t >> 3, scs = t & 7;
  for (int k0 = 0; k0 < K; k0 += 64) {
    __syncthreads();
#pragma unroll
    for (int i = 0; i < 4; ++i) {
      int row = srow + (i << 5), cs = scs;
      GLL(A + (long)(m0 + row) * K + k0 + ((cs ^ (row & 7)) << 3),
          &As[(i << 11) + (w << 9)]);
      GLL(Bm + (long)(n0 + row) * K + k0 + ((cs ^ (row & 7)) << 3),
          &Bs[(i << 11) + (w << 9)]);
    }
    __syncthreads();
#pragma unroll
    for (int ks = 0; ks < 2; ++ks) {
      bf16x8s af[4], bf[4];
#pragma unroll
      for (int fi = 0; fi < 4; ++fi) {
        int row = wm + fi * 16 + fr;
        af[fi] = *(const bf16x8s*)((const char*)As + row * 128 +
                                   (((ks * 4 + g) ^ (row & 7)) << 4));
      }
#pragma unroll
      for (int fj = 0; fj < 4; ++fj) {
        int row = wn + fj * 16 + fr;
        bf[fj] = *(const bf16x8s*)((const char*)Bs + row * 128 +
                                   (((ks * 4 + g) ^ (row & 7)) << 4));
      }
#pragma unroll
      for (int fi = 0; fi < 4; ++fi)
#pragma unroll
        for (int fj = 0; fj < 4; ++fj)
          acc[fi][fj] = MFMA(af[fi], bf[fj], acc[fi][fj], 0, 0, 0);
    }
  }
  const int crow = g << 2;
  if (MODE == 2) {
#pragma unroll
    for (int fi = 0; fi < 4; ++fi)
#pragma unroll
      for (int fj = 0; fj < 4; ++fj)
#pragma unroll
        for (int r = 0; r < 4; ++r) {
          int row = m0 + wm + fi * 16 + crow + r;
          int col = n0 + wn + fj * 16 + fr;
          long idx = ((long)row << 9) + col;
          ((float*)C0)[idx] = acc[fi][fj][r] + xres[idx] + bias[col];
        }
  } else {
    __syncthreads();
    char* Cs = (char*)sh;
    const float scale = (MODE == 0) ? 0.125f : 1.f;
#pragma unroll
    for (int fi = 0; fi < 4; ++fi)
#pragma unroll
      for (int fj = 0; fj < 4; ++fj)
#pragma unroll
        for (int r = 0; r < 4; ++r) {
          int row = wm + fi * 16 + crow + r;
          int colb = (wn + fj * 16 + fr) << 1;
          *(u16*)(Cs + ((row * 256 + colb) ^ ((row & 7) << 4))) =
              f2b(acc[fi][fj][r] * scale);
        }
    __syncthreads();
    const bool vt = (MODE == 1) && (n0 >= 512);
    if (!vt) {
#pragma unroll
      for (int i = 0; i < 8; ++i) {
        int seg = (i << 8) + t;
        int row = seg >> 4, cs = seg & 15;
        bf16x8s v = *(const bf16x8s*)(Cs +
                        ((row * 256 + (cs << 4)) ^ ((row & 7) << 4)));
        int m = m0 + row;
        int colg = n0 + (cs << 3);
        int h = colg >> 6, dh0 = colg & 63;
        if (MODE == 0) {
          int b = m >> 13, n = m & 8191;
          *(bf16x8s*)((u16*)C0 + ((((long)(b * 8 + h)) << 13) + n) * 64 + dh0) = v;
        } else {
          int b = m >> 12, nz = m & 4095;
          *(bf16x8s*)((u16*)C0 + ((((long)(b * 8 + h)) << 12) + nz) * 64 + dh0) = v;
        }
      }
    } else {
#pragma unroll
      for (int i = 0; i < 8; ++i) {
        int seg = (i << 8) + t;
        int col = seg & 127;
        int r0 = (seg >> 7) << 3;
        bf16x8s v;
#pragma unroll
        for (int j = 0; j < 8; ++j) {
          int rr = r0 + j;
          v[j] = *(const short*)(Cs + ((rr * 256 + (col << 1)) ^ ((rr & 7) << 4)));
        }
        int m = m0 + r0;
        int b = m >> 12, nz0 = m & 4095;
        int c2 = n0 + col - 512;
        int h = c2 >> 6, dh = c2 & 63;
        *(bf16x8s*)((u16*)C1 + ((((long)(b * 8 + h) * 64 + dh)) << 12) + nz0) = v;
      }
    }
  }
}

// ---------------- fused landmarks (q then k): mean -> split hi/lo bf16 ------
__global__ __launch_bounds__(256) void k_land2(const u16* __restrict__ qb,
                                               const u16* __restrict__ kb,
                                               u16* __restrict__ qlh,
                                               u16* __restrict__ qll,
                                               u16* __restrict__ klh,
                                               u16* __restrict__ kll) {
  int pidx = blockIdx.x * 4 + (threadIdx.x >> 6);  // < 16384
  const u16* src;
  u16 *hi, *lo;
  int ntok, l;
  float inv;
  if (pidx < 8192) { src = qb; hi = qlh; lo = qll; ntok = 8192; l = 32; inv = 1.f / 32.f; }
  else { src = kb; hi = klh; lo = kll; ntok = 4096; l = 16; inv = 1.f / 16.f; pidx -= 8192; }
  int d = threadIdx.x & 63;
  int bh = pidx >> 8, m = pidx & 255;
  const u16* s = src + ((long)bh * ntok + (long)m * l) * 64 + d;
  float sum = 0.f;
  for (int j = 0; j < l; ++j) sum += b2f(s[j * 64]);
  sum *= inv;
  long o = ((long)bh * 256 + m) * 64 + d;
  u16 h = f2b(sum);
  hi[o] = h;
  lo[o] = f2b(sum - b2f(h));
}

// ---------------- sim2 + softmax via split-bf16 MFMA ------------------------
__global__ __launch_bounds__(256, 2) void k_sim2(
    const u16* __restrict__ qlh, const u16* __restrict__ qll,
    const u16* __restrict__ klh, const u16* __restrict__ kll,
    float* __restrict__ attn2, u16* __restrict__ aNhi, u16* __restrict__ aNlo) {
  const int rb = blockIdx.x, bh = blockIdx.y;
  const int t = threadIdx.x, lane = t & 63, w = t >> 6;
  const int fr = lane & 15, g = lane >> 4;
  __shared__ char lds[65536];
  {
    const u16* kh = klh + (long)bh * 16384;
    const u16* kl = kll + (long)bh * 16384;
    int srow8 = lane >> 3, cs7 = lane & 7;
#pragma unroll
    for (int i = 0; i < 8; ++i) {
      int slab = w * 8 + i;
      int krow = slab * 8 + srow8;
      GLL(kh + krow * 64 + ((cs7 ^ (krow & 7)) << 3), lds + slab * 1024);
      GLL(kl + krow * 64 + ((cs7 ^ (krow & 7)) << 3), lds + 32768 + slab * 1024);
    }
  }
  long qoff = ((long)bh * 256 + rb * 64 + w * 16 + fr) * 64;
  bf16x8s qh0 = *(const bf16x8s*)(qlh + qoff + g * 8);
  bf16x8s qh1 = *(const bf16x8s*)(qlh + qoff + 32 + g * 8);
  bf16x8s ql0 = *(const bf16x8s*)(qll + qoff + g * 8);
  bf16x8s ql1 = *(const bf16x8s*)(qll + qoff + 32 + g * 8);
  __syncthreads();
  f32x4 s[16];
#pragma unroll
  for (int c = 0; c < 16; ++c) {
    int j = (c << 4) + fr;
    int o0 = j * 128 + ((g ^ (j & 7)) << 4);
    int o1 = j * 128 + (((4 + g) ^ (j & 7)) << 4);
    bf16x8s kh0 = *(const bf16x8s*)(lds + o0);
    bf16x8s kh1 = *(const bf16x8s*)(lds + o1);
    bf16x8s kl0 = *(const bf16x8s*)(lds + 32768 + o0);
    bf16x8s kl1 = *(const bf16x8s*)(lds + 32768 + o1);
    f32x4 zz = {};
    zz = MFMA(qh0, kh0, zz, 0, 0, 0);
    zz = MFMA(qh1, kh1, zz, 0, 0, 0);
    zz = MFMA(qh0, kl0, zz, 0, 0, 0);
    zz = MFMA(qh1, kl1, zz, 0, 0, 0);
    zz = MFMA(ql0, kh0, zz, 0, 0, 0);
    zz = MFMA(ql1, kh1, zz, 0, 0, 0);
    s[c] = zz;
  }
  float li[4];
#pragma unroll
  for (int r = 0; r < 4; ++r) {
    float m = s[0][r];
#pragma unroll
    for (int c = 1; c < 16; ++c) m = fmaxf(m, s[c][r]);
    m = fmaxf(m, __shfl_xor(m, 1, 64));
    m = fmaxf(m, __shfl_xor(m, 2, 64));
    m = fmaxf(m, __shfl_xor(m, 4, 64));
    m = fmaxf(m, __shfl_xor(m, 8, 64));
    float l = 0.f;
#pragma unroll
    for (int c = 0; c < 16; ++c) {
      float e = __expf(s[c][r] - m);
      s[c][r] = e;
      l += e;
    }
    l += __shfl_xor(l, 1, 64);
    l += __shfl_xor(l, 2, 64);
    l += __shfl_xor(l, 4, 64);
    l += __shfl_xor(l, 8, 64);
    li[r] = 1.f / l;
  }
#pragma unroll
  for (int c = 0; c < 16; ++c)
#pragma unroll
    for (int r = 0; r < 4; ++r) {
      int row = rb * 64 + w * 16 + (g << 2) + r;
      int col = (c << 4) + fr;
      long idx = ((long)bh << 16) + ((long)row << 8) + col;
      float p = s[c][r] * li[r];
      attn2[idx] = p;
      u16 h = f2b(p);
      aNhi[idx] = h;
      aNlo[idx] = f2b(p - b2f(h));
    }
}

// ---------------- fused: colmax (32 blocks) + T1 split-KV partial (512) -----
__global__ __launch_bounds__(256, 2) void k_cm_t1(
    const float* __restrict__ attn2, unsigned* __restrict__ cmax,
    const u16* __restrict__ qlb, const u16* __restrict__ kb,
    const u16* __restrict__ vtb, float* __restrict__ opart,
    float* __restrict__ pm_, float* __restrict__ pl_) {
  __shared__ char lds[65536];
  if (blockIdx.x < 32) {
    int bh = blockIdx.x, j = threadIdx.x, lane = j & 63, w = j >> 6;
    const float* p = attn2 + ((long)bh << 16) + j;
    float s = 0.f;
    for (int m = 0; m < 256; ++m) s += p[m * 256];
    float mx = s;
    for (int o = 1; o < 64; o <<= 1) mx = fmaxf(mx, __shfl_xor(mx, o, 64));
    float* r1 = (float*)lds;
    if (lane == 0) r1[w] = mx;
    __syncthreads();
    if (j == 0) {
      mx = fmaxf(fmaxf(r1[0], r1[1]), fmaxf(r1[2], r1[3]));
      atomicMax(cmax, __float_as_uint(mx));
    }
    return;
  }
  int orig = blockIdx.x - 32;  // 512 = 32 bh * 4 kc * 4 rb
  int xcd = orig & 7, idx = orig >> 3;
  int p = xcd * 16 + (idx >> 2);
  int rb = idx & 3;
  int bh = p >> 2, kc = p & 3;
  const int t = threadIdx.x, lane = t & 63, w = t >> 6;
  const int fr = lane & 15, g = lane >> 4;
  const u16* qrow = qlb + ((long)bh * 256 + rb * 64 + w * 16 + fr) * 64;
  bf16x8s qa0 = *(const bf16x8s*)(qrow + g * 8);
  bf16x8s qa1 = *(const bf16x8s*)(qrow + 32 + g * 8);
  f32x4 o[4] = {};
  float m[4] = {-3e38f, -3e38f, -3e38f, -3e38f};
  float l[4] = {};
  const long kbase = (long)bh * 262144;
  for (int cc = 0; cc < 4; ++cc) {
    int c0 = kc * 1024 + cc * 256;
    __syncthreads();
#pragma unroll
    for (int i = 0; i < 8; ++i) {
      int seg = (i << 8) + t, row = seg >> 3, cs = seg & 7;
      GLL(kb + kbase + (long)(c0 + row) * 64 + ((cs ^ (row & 7)) << 3),
          lds + (i << 12) + (w << 10));
    }
#pragma unroll
    for (int i = 0; i < 8; ++i) {
      int seg = (i << 8) + t, row = seg >> 5, cs = seg & 31;
      GLL(vtb + kbase + (long)row * 4096 + c0 + ((cs ^ (row & 7)) << 3),
          lds + 32768 + (i << 12) + (w << 10));
    }
    __syncthreads();
    f32x4 s[16];
#pragma unroll
    for (int c = 0; c < 16; ++c) {
      int j = c * 16 + fr;
      bf16x8s b0 = *(const bf16x8s*)(lds + j * 128 + ((g ^ (j & 7)) << 4));
      bf16x8s b1 = *(const bf16x8s*)(lds + j * 128 + (((4 + g) ^ (j & 7)) << 4));
      f32x4 zz = {};
      zz = MFMA(qa0, b0, zz, 0, 0, 0);
      zz = MFMA(qa1, b1, zz, 0, 0, 0);
      s[c] = zz;
    }
    float sc[4];
#pragma unroll
    for (int r = 0; r < 4; ++r) {
      float pm = s[0][r];
#pragma unroll
      for (int c = 1; c < 16; ++c) pm = fmaxf(pm, s[c][r]);
      pm = fmaxf(pm, __shfl_xor(pm, 1, 64));
      pm = fmaxf(pm, __shfl_xor(pm, 2, 64));
      pm = fmaxf(pm, __shfl_xor(pm, 4, 64));
      pm = fmaxf(pm, __shfl_xor(pm, 8, 64));
      float mn = fmaxf(m[r], pm);
      sc[r] = __expf(m[r] - mn);
      m[r] = mn;
    }
#pragma unroll
    for (int r = 0; r < 4; ++r) {
      float su = 0.f;
#pragma unroll
      for (int c = 0; c < 16; ++c) {
        float e = __expf(s[c][r] - m[r]);
        s[c][r] = e;
        su += e;
      }
      su += __shfl_xor(su, 1, 64);
      su += __shfl_xor(su, 2, 64);
      su += __shfl_xor(su, 4, 64);
      su += __shfl_xor(su, 8, 64);
      l[r] = l[r] * sc[r] + su;
    }
#pragma unroll
    for (int d = 0; d < 4; ++d)
#pragma unroll
      for (int r = 0; r < 4; ++r) o[d][r] *= sc[r];
    __syncthreads();
#pragma unroll
    for (int c = 0; c < 16; ++c)
#pragma unroll
      for (int r = 0; r < 4; ++r) {
        int row = (w << 4) + (g << 2) + r;
        int byin = (c << 5) + (fr << 1);
        *(u16*)(lds + row * 512 + (byin ^ ((row & 7) << 4))) = f2b(s[c][r]);
      }
    asm volatile("s_waitcnt lgkmcnt(0)" ::: "memory");
    __builtin_amdgcn_sched_barrier(0);
#pragma unroll
    for (int ss = 0; ss < 8; ++ss) {
      int prow = (w << 4) + fr;
      bf16x8s ap = *(const bf16x8s*)(lds + prow * 512 +
                                     (((ss * 64) + (g << 4)) ^ ((prow & 7) << 4)));
#pragma unroll
      for (int d = 0; d < 4; ++d) {
        int dh = (d << 4) + fr;
        bf16x8s bv = *(const bf16x8s*)(lds + 32768 + dh * 512 +
                                       (((ss * 4 + g) ^ (dh & 7)) << 4));
        o[d] = MFMA(ap, bv, o[d], 0, 0, 0);
      }
    }
  }
  __syncthreads();
  float* lf = (float*)lds;
#pragma unroll
  for (int d = 0; d < 4; ++d)
#pragma unroll
    for (int r = 0; r < 4; ++r)
      lf[((w << 4) + (g << 2) + r) * 76 + (d << 4) + fr] = o[d][r];
  __syncthreads();
  const long pb = (long)(bh * 4 + kc) * 256 + rb * 64;
#pragma unroll
  for (int i = 0; i < 4; ++i) {
    int row = i * 16 + (t >> 4);
    int c4 = (t & 15) << 2;
    float4 v = *(const float4*)&lf[row * 76 + c4];
    *(float4*)&opart[(pb + row) * 64 + c4] = v;
  }
  if (fr == 0) {
#pragma unroll
    for (int r = 0; r < 4; ++r) {
      int lr = (w << 4) + (g << 2) + r;
      pm_[pb + lr] = m[r];
      pl_[pb + lr] = l[r];
    }
  }
}

// ---------------- fused: t1merge (128 blocks) + pinv prep (512) -------------
__global__ __launch_bounds__(256) void k_mergeprep(
    const float* __restrict__ opart, const float* __restrict__ pm_,
    const float* __restrict__ pl_, u16* __restrict__ T1thi,
    u16* __restrict__ T1tlo, const float* __restrict__ attn2,
    const unsigned* __restrict__ cmax, u16* __restrict__ zNhi,
    u16* __restrict__ zNlo, u16* __restrict__ zThi, u16* __restrict__ zTlo) {
  __shared__ float mt[64][65];
  if (blockIdx.x < 128) {
    const int rb = blockIdx.x & 3, bh = blockIdx.x >> 2;
    const int t = threadIdx.x;
#pragma unroll
    for (int rp = 0; rp < 4; ++rp) {
      int row = rb * 64 + rp * 16 + (t >> 4);
      int dh4 = (t & 15) << 2;
      float pmv[4], M = -3e38f;
#pragma unroll
      for (int i = 0; i < 4; ++i) {
        pmv[i] = pm_[(long)(bh * 4 + i) * 256 + row];
        M = fmaxf(M, pmv[i]);
      }
      float L = 0.f, wt[4];
#pragma unroll
      for (int i = 0; i < 4; ++i) {
        wt[i] = __expf(pmv[i] - M);
        L += pl_[(long)(bh * 4 + i) * 256 + row] * wt[i];
      }
      float4 acc = {0.f, 0.f, 0.f, 0.f};
#pragma unroll
      for (int i = 0; i < 4; ++i) {
        float4 v = *(const float4*)&opart[((long)(bh * 4 + i) * 256 + row) * 64 + dh4];
        acc.x += v.x * wt[i]; acc.y += v.y * wt[i];
        acc.z += v.z * wt[i]; acc.w += v.w * wt[i];
      }
      float invL = 1.f / L;
      float vv[4] = {acc.x * invL, acc.y * invL, acc.z * invL, acc.w * invL};
#pragma unroll
      for (int e = 0; e < 4; ++e) {
        int dh = dh4 + e;
        long idx = (long)bh * 16384 + (long)dh * 256 + row;
        u16 h = f2b(vv[e]);
        T1thi[idx] = h;
        T1tlo[idx] = f2b(vv[e] - b2f(h));
      }
    }
    return;
  }
  const int p = blockIdx.x - 128;
  const int bz = p >> 4, i0 = ((p >> 2) & 3) << 6, j0 = (p & 3) << 6;
  const float s = 1.f / __uint_as_float(*cmax);
  const float* base = attn2 + ((long)bz << 16);
  const int r = threadIdx.x >> 2, cb = (threadIdx.x & 3) << 4;
#pragma unroll
  for (int c4 = 0; c4 < 16; c4 += 4) {
    float4 v = *(const float4*)&base[(long)(j0 + r) * 256 + i0 + cb + c4];
    mt[r][cb + c4] = v.x; mt[r][cb + c4 + 1] = v.y;
    mt[r][cb + c4 + 2] = v.z; mt[r][cb + c4 + 3] = v.w;
  }
  __syncthreads();
  const int i = i0 + r;
#pragma unroll
  for (int c4 = 0; c4 < 16; c4 += 4) {
    float4 v = *(const float4*)&base[(long)i * 256 + j0 + cb + c4];
    float vv[4] = {v.x, v.y, v.z, v.w};
#pragma unroll
    for (int e = 0; e < 4; ++e) {
      int j = j0 + cb + c4 + e;
      long idx = ((long)bz << 16) + ((long)i << 8) + j;
      float zt = vv[e] * s;
      u16 zh = f2b(zt);
      zThi[idx] = zh; zTlo[idx] = f2b(zt - b2f(zh));
      float zn = mt[cb + c4 + e][r] * s;
      u16 nh = f2b(zn);
      zNhi[idx] = nh; zNlo[idx] = f2b(zn - b2f(nh));
    }
  }
}

// ---------------- MFMA NN GEMM (pinv chain), BK=128; NP=1 plain, NP=3 split -
template <int NP>
__global__ __launch_bounds__(256) void k_nn_mfma(
    const u16* __restrict__ Ahi, const u16* __restrict__ Alo,
    const u16* __restrict__ Bthi, const u16* __restrict__ Btlo,
    u16* __restrict__ CNhi, u16* __restrict__ CNlo,
    u16* __restrict__ CThi, u16* __restrict__ CTlo,
    int Nc, float sab, float sa, float cdiag) {
  const int bz = blockIdx.z;
  const long offA = (long)bz << 16;
  const long offB = (long)bz * ((long)Nc << 8);
  const int m0 = blockIdx.y << 6, n0 = blockIdx.x << 6;
  const int t = threadIdx.x, lane = t & 63, w = t >> 6;
  const int wm = (w >> 1) << 5, wn = (w & 1) << 5;
  const int fr = lane & 15, g = lane >> 4;
  __shared__ u16 lds[(NP == 3) ? 32768 : 16384];  // planes of [64][128] u16 (16KB)
  u16* LAh = lds;
  u16* LBh = lds + 8192;
  u16* LAl = (NP == 3) ? lds + 16384 : nullptr;
  u16* LBl = (NP == 3) ? lds + 24576 : nullptr;
  f32x4 acc[2][2] = {};
  for (int k0 = 0; k0 < 256; k0 += 128) {
    __syncthreads();
#pragma unroll
    for (int i = 0; i < 4; ++i) {
      int row = (i << 4) + (t >> 4);
      int sp = t & 15;
      int seg = (sp & 8) | ((sp & 7) ^ (row & 7));  // source 16B-segment
      long asrc = offA + (long)(m0 + row) * 256 + k0 + (seg << 3);
      long bsrc = offB + (long)(n0 + row) * 256 + k0 + (seg << 3);
      GLL(Ahi + asrc, (char*)LAh + (i << 12) + (w << 10));
      GLL(Bthi + bsrc, (char*)LBh + (i << 12) + (w << 10));
      if (NP == 3) {
        GLL(Alo + asrc, (char*)LAl + (i << 12) + (w << 10));
        GLL(Btlo + bsrc, (char*)LBl + (i << 12) + (w << 10));
      }
    }
    __syncthreads();
#pragma unroll
    for (int ks = 0; ks < 4; ++ks) {
      const int ra0 = wm + fr, ra1 = wm + 16 + fr;
      const int rb0 = wn + fr, rb1 = wn + 16 + fr;
#define RD(base, row)                                                          \
  (*(const bf16x8s*)((const char*)(base) + (row) * 256 +                       \
                     ((((ks * 4 + g) & 8) |                                    \
                       (((ks * 4 + g) & 7) ^ ((row) & 7))) << 4)))
      bf16x8s ah0 = RD(LAh, ra0), ah1 = RD(LAh, ra1);
      bf16x8s bh0 = RD(LBh, rb0), bh1 = RD(LBh, rb1);
      acc[0][0] = MFMA(ah0, bh0, acc[0][0], 0, 0, 0);
      acc[0][1] = MFMA(ah0, bh1, acc[0][1], 0, 0, 0);
      acc[1][0] = MFMA(ah1, bh0, acc[1][0], 0, 0, 0);
      acc[1][1] = MFMA(ah1, bh1, acc[1][1], 0, 0, 0);
      if (NP == 3) {
        bf16x8s al0 = RD(LAl, ra0), al1 = RD(LAl, ra1);
        bf16x8s bl0 = RD(LBl, rb0), bl1 = RD(LBl, rb1);
        acc[0][0] = MFMA(ah0, bl0, acc[0][0], 0, 0, 0);
        acc[0][0] = MFMA(al0, bh0, acc[0][0], 0, 0, 0);
        acc[0][1] = MFMA(ah0, bl1, acc[0][1], 0, 0, 0);
        acc[0][1] = MFMA(al0, bh1, acc[0][1], 0, 0, 0);
        acc[1][0] = MFMA(ah1, bl0, acc[1][0], 0, 0, 0);
        acc[1][0] = MFMA(al1, bh0, acc[1][0], 0, 0, 0);
        acc[1][1] = MFMA(ah1, bl1, acc[1][1], 0, 0, 0);
        acc[1][1] = MFMA(al1, bh1, acc[1][1], 0, 0, 0);
      }
#undef RD
    }
  }
  const int crow = g << 2;
  const long offC = (long)bz * ((long)Nc << 8);
#pragma unroll
  for (int i = 0; i < 2; ++i)
#pragma unroll
    for (int j = 0; j < 2; ++j)
#pragma unroll
      for (int r = 0; r < 4; ++r) {
        int row = m0 + wm + i * 16 + crow + r;
        int col = n0 + wn + j * 16 + fr;
        float v = sab * acc[i][j][r];
        if (sa != 0.f) {
          long ai = offA + ((long)row << 8) + col;
          v += sa * (b2f(Ahi[ai]) + b2f(Alo[ai]));
        }
        if (row == col) v += cdiag;
        if (CNhi) {
          long ci = offC + (long)row * Nc + col;
          u16 h = f2b(v);
          if (CNlo) { CNhi[ci] = h; CNlo[ci] = f2b(v - b2f(h)); }
          else CNhi[ci] = h;
        }
        if (CThi) {
          long ti = offC + ((long)col << 8) + row;
          u16 h = f2b(v);
          CThi[ti] = h;
          if (CTlo) CTlo[ti] = f2b(v - b2f(h));
        }
      }
}

// ---------------- fused sim1: O = softmax(q @ k_land^T) @ T2 ----------------
__global__ __launch_bounds__(512, 4) void k_fused_attn1(const u16* __restrict__ q,
                                                        const u16* __restrict__ klb,
                                                        const u16* __restrict__ t2t,
                                                        u16* __restrict__ O) {
  const int bh = blockIdx.y, n0 = blockIdx.x << 7;
  const int bb = bh >> 3, hh = bh & 7;
  const int t = threadIdx.x, lane = t & 63, w = t >> 6;  // 8 waves
  const int fr = lane & 15, g = lane >> 4;
  __shared__ char lds[65536];  // [0,32K) k_land (aliased by half-P); [32K,64K) T2^T
  {
    const u16* ks = klb + (long)bh * 16384;
    const u16* ts = t2t + (long)bh * 16384;
#pragma unroll
    for (int i = 0; i < 4; ++i) {
      int seg = (i << 9) + t, row = seg >> 3, cs = seg & 7;
      GLL(ks + row * 64 + ((cs ^ (row & 7)) << 3), lds + (i << 13) + (w << 10));
      int slab = w * 4 + i;
      int trow = slab * 2 + (lane >> 5), cs32 = lane & 31;
      GLL(ts + trow * 256 + ((cs32 ^ (trow & 7)) << 3),
          lds + 32768 + slab * 1024);
    }
  }
  __syncthreads();
  const u16* qrow = q + ((long)bh * 8192 + n0 + (w << 4) + fr) * 64;
  bf16x8s qa0 = *(const bf16x8s*)(qrow + g * 8);
  bf16x8s qa1 = *(const bf16x8s*)(qrow + 32 + g * 8);
  f32x4 s[16];
#pragma unroll
  for (int c = 0; c < 16; ++c) {
    int j = (c << 4) + fr;
    bf16x8s b0 = *(const bf16x8s*)(lds + j * 128 + ((g ^ (j & 7)) << 4));
    bf16x8s b1 = *(const bf16x8s*)(lds + j * 128 + (((4 + g) ^ (j & 7)) << 4));
    f32x4 zz = {};
    zz = MFMA(qa0, b0, zz, 0, 0, 0);
    zz = MFMA(qa1, b1, zz, 0, 0, 0);
    s[c] = zz;
  }
  float li[4];
#pragma unroll
  for (int r = 0; r < 4; ++r) {
    float m = s[0][r];
#pragma unroll
    for (int c = 1; c < 16; ++c) m = fmaxf(m, s[c][r]);
    m = fmaxf(m, __shfl_xor(m, 1, 64));
    m = fmaxf(m, __shfl_xor(m, 2, 64));
    m = fmaxf(m, __shfl_xor(m, 4, 64));
    m = fmaxf(m, __shfl_xor(m, 8, 64));
    float l = 0.f;
#pragma unroll
    for (int c = 0; c < 16; ++c) {
      float e = __expf(s[c][r] - m);
      s[c][r] = e;
      l += e;
    }
    l += __shfl_xor(l, 1, 64);
    l += __shfl_xor(l, 2, 64);
    l += __shfl_xor(l, 4, 64);
    l += __shfl_xor(l, 8, 64);
    li[r] = 1.f / l;
  }
  __syncthreads();  // ALL waves done reading K; region becomes half-P [128][256B]
  f32x4 o4[4] = {};
#pragma unroll
  for (int p = 0; p < 2; ++p) {
#pragma unroll
    for (int c8 = 0; c8 < 8; ++c8) {
      int c = p * 8 + c8;
#pragma unroll
      for (int r = 0; r < 4; ++r) {
        int row = (w << 4) + (g << 2) + r;
        int byin = (c8 << 5) + (fr << 1);
        *(u16*)(lds + row * 256 + (byin ^ ((row & 7) << 4))) = f2b(s[c][r]);
      }
    }
    asm volatile("s_waitcnt lgkmcnt(0)" ::: "memory");
    __builtin_amdgcn_sched_barrier(0);
#pragma unroll
    for (int ss8 = 0; ss8 < 4; ++ss8) {
      int ss = p * 4 + ss8;
      int prow = (w << 4) + fr;
      bf16x8s ap = *(const bf16x8s*)(lds + prow * 256 +
                                     (((ss8 * 64) + (g << 4)) ^ ((prow & 7) << 4)));
#pragma unroll
      for (int d = 0; d < 4; ++d) {
        int dh = (d << 4) + fr;
        bf16x8s bv = *(const bf16x8s*)(lds + 32768 + dh * 512 +
                                       (((ss * 4 + g) ^ (dh & 7)) << 4));
        o4[d] = MFMA(ap, bv, o4[d], 0, 0, 0);
      }
    }
    asm volatile("s_waitcnt lgkmcnt(0)" ::: "memory");
    __builtin_amdgcn_sched_barrier(0);
  }
  u16* ob = O + (((long)bb * 8192 + n0 + (w << 4)) << 9) + (hh << 6);
#pragma unroll
  for (int d = 0; d < 4; ++d)
#pragma unroll
    for (int r = 0; r < 4; ++r) {
      int row = (g << 2) + r;
      int col = (d << 4) + fr;
      ob[((long)row << 9) + col] = f2b(o4[d][r] * li[r]);
    }
}

// ---------------- host ----------------
extern "C" void kernel_launch(void* const* d_in, const int* in_sizes, int n_in,
                              void* d_out, int out_size, void* d_ws, size_t ws_size,
                              hipStream_t stream) {
  const float* x = (const float*)d_in[0];
  const float* z = (const float*)d_in[1];
  const float* Wq = (const float*)d_in[2];
  const float* Wkv = (const float*)d_in[3];
  const float* Wo = (const float*)d_in[4];
  const float* bo = (const float*)d_in[5];
  float* out = (float*)d_out;

  char* base = (char*)d_ws;
  size_t off = 0;
  auto alloc = [&](size_t bytes) -> void* {
    void* r = base + off;
    off = (off + bytes + 255) & ~(size_t)255;
    return r;
  };
  u16* qb = (u16*)alloc(33554432);
  u16* kb = (u16*)alloc(16777216);
  u16* vtb = (u16*)alloc(16777216);
  u16* PS = (u16*)alloc(67108864);    // pinv state (16 x 4MB)
  float* attn2 = (float*)alloc(8388608);
  u16* xb = (u16*)alloc(33554432);    // dead after qproj -> opart, then Ob
  u16* zb = (u16*)alloc(16777216);    // dead after kvproj -> attn2 split aN
  u16* wqt = (u16*)alloc(524288);
  u16* wkvt = (u16*)alloc(1048576);
  u16* wot = (u16*)alloc(524288);
  u16* qlh = (u16*)alloc(1048576);
  u16* qll = (u16*)alloc(1048576);
  u16* klh = (u16*)alloc(1048576);
  u16* kll = (u16*)alloc(1048576);
  u16* T1t = (u16*)alloc(2097152);
  u16* T2t = (u16*)alloc(1048576);
  unsigned* cmax = (unsigned*)alloc(256);
  const long MC = 2097152;
  u16* P = PS;
  u16 *ztA_Nhi = P,          *ztA_Nlo = P + MC,      *ztA_Thi = P + 2 * MC,  *ztA_Tlo = P + 3 * MC;
  u16 *ztB_Nhi = P + 4 * MC,  *ztB_Nlo = P + 5 * MC,  *ztB_Thi = P + 6 * MC,  *ztB_Tlo = P + 7 * MC;
  u16 *az_Nhi = P + 8 * MC,   *az_Nlo = P + 9 * MC,   *az_Thi = P + 10 * MC,  *az_Tlo = P + 11 * MC;
  u16 *taThi = P + 12 * MC,   *taTlo = P + 13 * MC;
  u16 *tcThi = P + 14 * MC,   *tcTlo = P + 15 * MC;
  u16 *aNhi = zb, *aNlo = zb + MC;
  float* opart = (float*)xb;                 // 8.4MB + 256KB (xb dead after qproj)
  float* pm_ = opart + 2097152;
  float* pl_ = pm_ + 32768;
  u16* T1thi = T1t;
  u16* T1tlo = T1t + 524288;
  u16* Ob = xb;

  hipMemsetAsync(cmax, 0, 4, stream);
  k_pre<<<28672, 256, 0, stream>>>(x, z, xb, zb, Wq, Wkv, Wo, wqt, wkvt, wot);

  k_gemm128<0><<<dim3(4, 256), 256, 0, stream>>>(xb, wqt, qb, nullptr, nullptr,
                                                 nullptr, 512);
  k_gemm128<1><<<dim3(8, 128), 256, 0, stream>>>(zb, wkvt, kb, vtb, nullptr,
                                                 nullptr, 512);
  k_land2<<<4096, 256, 0, stream>>>(qb, kb, qlh, qll, klh, kll);

  k_sim2<<<dim3(4, 32), 256, 0, stream>>>(qlh, qll, klh, kll, attn2, aNhi, aNlo);

  k_cm_t1<<<544, 256, 0, stream>>>(attn2, cmax, qlh, kb, vtb, opart, pm_, pl_);
  k_mergeprep<<<640, 256, 0, stream>>>(opart, pm_, pl_, T1thi, T1tlo, attn2,
                                       cmax, ztA_Nhi, ztA_Nlo, ztA_Thi, ztA_Tlo);

  dim3 g256(4, 4, 32);
  u16 *cN0 = ztA_Nhi, *cN1 = ztA_Nlo, *cT0 = ztA_Thi, *cT1 = ztA_Tlo;
  u16 *nN0 = ztB_Nhi, *nN1 = ztB_Nlo, *nT0 = ztB_Thi, *nT1 = ztB_Tlo;
  for (int it = 0; it < 6; ++it) {
    bool last = (it == 5);
    if (it < 5) {
      k_nn_mfma<1><<<g256, 256, 0, stream>>>(aNhi, aNlo, cT0, cT1, az_Nhi, az_Nlo,
                                             az_Thi, az_Tlo, 256, 1.f, 0.f, 0.f);
      k_nn_mfma<1><<<g256, 256, 0, stream>>>(az_Nhi, az_Nlo, az_Thi, az_Tlo, nullptr,
                                             nullptr, taThi, taTlo, 256, 1.f, -7.f, 15.f);
      k_nn_mfma<1><<<g256, 256, 0, stream>>>(az_Nhi, az_Nlo, taThi, taTlo, nullptr,
                                             nullptr, tcThi, tcTlo, 256, -1.f, 0.f, 13.f);
      k_nn_mfma<1><<<g256, 256, 0, stream>>>(cN0, cN1, tcThi, tcTlo, nN0, nN1,
                                             nT0, nT1, 256, 0.25f, 0.f, 0.f);
    } else {
      k_nn_mfma<3><<<g256, 256, 0, stream>>>(aNhi, aNlo, cT0, cT1, az_Nhi, az_Nlo,
                                             az_Thi, az_Tlo, 256, 1.f, 0.f, 0.f);
      k_nn_mfma<3><<<g256, 256, 0, stream>>>(az_Nhi, az_Nlo, az_Thi, az_Tlo, nullptr,
                                             nullptr, taThi, taTlo, 256, 1.f, -7.f, 15.f);
      k_nn_mfma<3><<<g256, 256, 0, stream>>>(az_Nhi, az_Nlo, taThi, taTlo, nullptr,
                                             nullptr, tcThi, tcTlo, 256, -1.f, 0.f, 13.f);
      k_nn_mfma<3><<<g256, 256, 0, stream>>>(cN0, cN1, tcThi, tcTlo, nN0, nN1,
                                             last ? nullptr : nT0, last ? nullptr : nT1,
                                             256, 0.25f, 0.f, 0.f);
    }
    u16* t0;
    t0 = cN0; cN0 = nN0; nN0 = t0;  t0 = cN1; cN1 = nN1; nN1 = t0;
    t0 = cT0; cT0 = nT0; nT0 = t0;  t0 = cT1; cT1 = nT1; nT1 = t0;
  }
  k_nn_mfma<3><<<dim3(1, 4, 32), 256, 0, stream>>>(cN0, cN1, T1thi, T1tlo, nullptr,
                                                   nullptr, T2t, nullptr, 64,
                                                   1.f, 0.f, 0.f);

  k_fused_attn1<<<dim3(64, 32), 512, 0, stream>>>(qb, klh, T2t, Ob);
  k_gemm128<2><<<dim3(4, 256), 256, 0, stream>>>(Ob, wot, out, nullptr, x, bo, 512);
}